// Round 4
// baseline (768.673 us; speedup 1.0000x reference)
//
#include <hip/hip_runtime.h>
#include <hip/hip_bf16.h>
#include <math.h>

// ---------------- problem constants ----------------
constexpr int NA  = 3200;     // atoms
constexpr int NE  = 51200;    // edges
constexpr int C   = 128;      // channels
constexpr int NK  = 123;      // k-points with |k| <= 0.6
constexpr int NKP = 128;      // padded stride for cosd/sind
constexpr int BG  = 8;        // graphs
constexpr float SKIPF = 0.57735026918962576f;  // 3^-0.5
constexpr float AVGN  = 16.0f;

__device__ __forceinline__ float dsilu(float x) { return x / (1.0f + expf(-x)); }

__device__ __forceinline__ unsigned short f2bf(float f) {
    unsigned int u = __float_as_uint(f);
    unsigned int r = (u + 0x7fffu + ((u >> 16) & 1u)) >> 16;
    return (unsigned short)r;
}
__device__ __forceinline__ float bf2f(unsigned short s) {
    return __uint_as_float(((unsigned int)s) << 16);
}

typedef __attribute__((ext_vector_type(8))) short short8;
typedef __attribute__((ext_vector_type(4))) float f32x4;

// ---------------- generic tiled f32 GEMM (atom GEMMs, K=128) ----------------
template <int K, int ACT, int OBF16>
__global__ __launch_bounds__(256, 4) void gemm_kernel(
    const float* __restrict__ X, const float* __restrict__ W,
    const float* __restrict__ bias, const float* __restrict__ res1,
    const float* __restrict__ res2, void* __restrict__ outv,
    int M, int N, float scale)
{
    constexpr int K4 = K / 4;
    constexpr int BK  = (K < 64) ? K : 64;
    constexpr int BK4 = BK / 4;
    constexpr int BK4P = BK4 + 1;
    __shared__ float As[64 * BK4P * 4];
    __shared__ float Bs[BK * 64];
    const int tid = threadIdx.x;
    const int m0 = blockIdx.x * 64;
    const int n0 = blockIdx.y * 64;

    const float4* X4 = (const float4*)X;
    const float4* W4 = (const float4*)W;
    float4* As4 = (float4*)As;
    float4* Bs4 = (float4*)Bs;
    const int N4 = N >> 2;

    const int tx = tid & 15;
    const int ty = tid >> 4;
    float acc[4][4];
#pragma unroll
    for (int i = 0; i < 4; i++)
#pragma unroll
        for (int j = 0; j < 4; j++) acc[i][j] = 0.0f;

    for (int k0 = 0; k0 < K4; k0 += BK4) {
        if (k0) __syncthreads();
        for (int idx = tid; idx < 64 * BK4; idx += 256) {
            int r = idx / BK4, k4 = idx - r * BK4;
            As4[r * BK4P + k4] = X4[(size_t)(m0 + r) * K4 + k0 + k4];
        }
        for (int idx = tid; idx < BK * 16; idx += 256) {
            int kr = idx >> 4, c4 = idx & 15;
            Bs4[idx] = W4[(size_t)(k0 * 4 + kr) * N4 + (n0 >> 2) + c4];
        }
        __syncthreads();

#pragma unroll 4
        for (int k4 = 0; k4 < BK4; k4++) {
            float a[4][4];
#pragma unroll
            for (int i = 0; i < 4; i++) {
                float4 av = As4[(ty * 4 + i) * BK4P + k4];
                a[i][0] = av.x; a[i][1] = av.y; a[i][2] = av.z; a[i][3] = av.w;
            }
#pragma unroll
            for (int kk = 0; kk < 4; kk++) {
                float4 bv = Bs4[(k4 * 4 + kk) * 16 + tx];
#pragma unroll
                for (int i = 0; i < 4; i++) {
                    acc[i][0] += a[i][kk] * bv.x;
                    acc[i][1] += a[i][kk] * bv.y;
                    acc[i][2] += a[i][kk] * bv.z;
                    acc[i][3] += a[i][kk] * bv.w;
                }
            }
        }
    }

    float4 bv = make_float4(0.f, 0.f, 0.f, 0.f);
    if (bias) bv = ((const float4*)bias)[(n0 >> 2) + tx];
#pragma unroll
    for (int i = 0; i < 4; i++) {
        int row = m0 + ty * 4 + i;
        size_t o = (size_t)row * N + n0 + tx * 4;
        float4 v;
        v.x = acc[i][0] + bv.x; v.y = acc[i][1] + bv.y;
        v.z = acc[i][2] + bv.z; v.w = acc[i][3] + bv.w;
        if (ACT) { v.x = dsilu(v.x); v.y = dsilu(v.y); v.z = dsilu(v.z); v.w = dsilu(v.w); }
        if (res1) { float4 r = *(const float4*)(res1 + o); v.x += r.x; v.y += r.y; v.z += r.z; v.w += r.w; }
        if (res2) { float4 r = *(const float4*)(res2 + o); v.x += r.x; v.y += r.y; v.z += r.z; v.w += r.w; }
        v.x *= scale; v.y *= scale; v.z *= scale; v.w *= scale;
        if (OBF16) {
            ushort4 pk;
            pk.x = f2bf(v.x); pk.y = f2bf(v.y); pk.z = f2bf(v.z); pk.w = f2bf(v.w);
            *(ushort4*)((unsigned short*)outv + o) = pk;
        } else {
            *(float4*)((float*)outv + o) = v;
        }
    }
}

// ---------------- dual GEMM: t1 = silu(h@Wa + bias), hu = h@Wb ----------------
// K=N=128. grid (M/64, 4): blockIdx.y 0,1 -> Wa/outa(silu+bias); 2,3 -> Wb/outb.
__global__ __launch_bounds__(256, 4) void gemm_dual(
    const float* __restrict__ X, const float* __restrict__ Wa,
    const float* __restrict__ Wb, const float* __restrict__ bias,
    float* __restrict__ outa, float* __restrict__ outb)
{
    constexpr int K4 = 32, BK4 = 16, BK4P = 17;
    __shared__ float As[64 * BK4P * 4];
    __shared__ float Bs[64 * 64];
    const int tid = threadIdx.x;
    const int m0 = blockIdx.x * 64;
    const int sel = blockIdx.y >> 1;
    const int n0 = (blockIdx.y & 1) * 64;
    const float* W = sel ? Wb : Wa;
    float* out = sel ? outb : outa;

    const float4* X4 = (const float4*)X;
    const float4* W4 = (const float4*)W;
    float4* As4 = (float4*)As;
    float4* Bs4 = (float4*)Bs;

    const int tx = tid & 15;
    const int ty = tid >> 4;
    float acc[4][4];
#pragma unroll
    for (int i = 0; i < 4; i++)
#pragma unroll
        for (int j = 0; j < 4; j++) acc[i][j] = 0.0f;

    for (int k0 = 0; k0 < K4; k0 += BK4) {
        if (k0) __syncthreads();
        for (int idx = tid; idx < 64 * BK4; idx += 256) {
            int r = idx / BK4, k4 = idx - r * BK4;
            As4[r * BK4P + k4] = X4[(size_t)(m0 + r) * K4 + k0 + k4];
        }
        for (int idx = tid; idx < 64 * 16; idx += 256) {
            int kr = idx >> 4, c4 = idx & 15;
            Bs4[idx] = W4[(size_t)(k0 * 4 + kr) * 32 + (n0 >> 2) + c4];
        }
        __syncthreads();

#pragma unroll 4
        for (int k4 = 0; k4 < BK4; k4++) {
            float a[4][4];
#pragma unroll
            for (int i = 0; i < 4; i++) {
                float4 av = As4[(ty * 4 + i) * BK4P + k4];
                a[i][0] = av.x; a[i][1] = av.y; a[i][2] = av.z; a[i][3] = av.w;
            }
#pragma unroll
            for (int kk = 0; kk < 4; kk++) {
                float4 bv = Bs4[(k4 * 4 + kk) * 16 + tx];
#pragma unroll
                for (int i = 0; i < 4; i++) {
                    acc[i][0] += a[i][kk] * bv.x;
                    acc[i][1] += a[i][kk] * bv.y;
                    acc[i][2] += a[i][kk] * bv.z;
                    acc[i][3] += a[i][kk] * bv.w;
                }
            }
        }
    }

    float4 bv = make_float4(0.f, 0.f, 0.f, 0.f);
    if (!sel) bv = ((const float4*)bias)[(n0 >> 2) + tx];
#pragma unroll
    for (int i = 0; i < 4; i++) {
        int row = m0 + ty * 4 + i;
        size_t o = (size_t)row * 128 + n0 + tx * 4;
        float4 v;
        v.x = acc[i][0] + bv.x; v.y = acc[i][1] + bv.y;
        v.z = acc[i][2] + bv.z; v.w = acc[i][3] + bv.w;
        if (!sel) { v.x = dsilu(v.x); v.y = dsilu(v.y); v.z = dsilu(v.z); v.w = dsilu(v.w); }
        *(float4*)(out + o) = v;
    }
}

// ---------------- fused radial MLP: ef(8) -> 64 -> 64 -> 64, bf16 out ----------------
__device__ __forceinline__ float4 silu4(float4 a) {
    return make_float4(dsilu(a.x), dsilu(a.y), dsilu(a.z), dsilu(a.w));
}

__global__ __launch_bounds__(256) void k_rmlp(
    const float* __restrict__ efb,
    const float* __restrict__ rW1, const float* __restrict__ rb1,
    const float* __restrict__ rW2, const float* __restrict__ rb2,
    const float* __restrict__ rW3, const float* __restrict__ rb3,
    unsigned short* __restrict__ tA)
{
    __shared__ float sW1[8 * 64];
    __shared__ float sB1[64];
    __shared__ float sW2[64 * 64];
    __shared__ float sB2[64];
    __shared__ float sW3[64 * 64];
    __shared__ float sB3[64];
    const int tid = threadIdx.x;
    for (int i = tid; i < 8 * 64; i += 256) sW1[i] = rW1[i];
    for (int i = tid; i < 64 * 64; i += 256) { sW2[i] = rW2[i]; sW3[i] = rW3[i]; }
    if (tid < 64) { sB1[tid] = rb1[tid]; sB2[tid] = rb2[tid]; sB3[tid] = rb3[tid]; }
    __syncthreads();

    const int e = blockIdx.x * 256 + tid;
    const float4* ef4 = (const float4*)(efb + (size_t)e * 8);
    float4 e0 = ef4[0], e1 = ef4[1];
    float ef[8] = { e0.x, e0.y, e0.z, e0.w, e1.x, e1.y, e1.z, e1.w };

    const float4* W1v = (const float4*)sW1;
    const float4* W2v = (const float4*)sW2;
    const float4* W3v = (const float4*)sW3;
    const float4* B1v = (const float4*)sB1;
    const float4* B2v = (const float4*)sB2;
    const float4* B3v = (const float4*)sB3;

    float4 h1[16];
#pragma unroll
    for (int j = 0; j < 16; j++) {
        float4 a = B1v[j];
#pragma unroll
        for (int i = 0; i < 8; i++) {
            float4 w = W1v[i * 16 + j];
            a.x += ef[i] * w.x; a.y += ef[i] * w.y; a.z += ef[i] * w.z; a.w += ef[i] * w.w;
        }
        h1[j] = silu4(a);
    }

    float4 h2[16];
#pragma unroll
    for (int j = 0; j < 16; j++) h2[j] = B2v[j];
#pragma unroll
    for (int k4 = 0; k4 < 16; k4++) {
        float4 hv = h1[k4];
#pragma unroll
        for (int j = 0; j < 16; j++) {
            float4 w0 = W2v[(k4 * 4 + 0) * 16 + j];
            float4 w1 = W2v[(k4 * 4 + 1) * 16 + j];
            float4 w2_ = W2v[(k4 * 4 + 2) * 16 + j];
            float4 w3_ = W2v[(k4 * 4 + 3) * 16 + j];
            h2[j].x += hv.x * w0.x + hv.y * w1.x + hv.z * w2_.x + hv.w * w3_.x;
            h2[j].y += hv.x * w0.y + hv.y * w1.y + hv.z * w2_.y + hv.w * w3_.y;
            h2[j].z += hv.x * w0.z + hv.y * w1.z + hv.z * w2_.z + hv.w * w3_.z;
            h2[j].w += hv.x * w0.w + hv.y * w1.w + hv.z * w2_.w + hv.w * w3_.w;
        }
    }
#pragma unroll
    for (int j = 0; j < 16; j++) h2[j] = silu4(h2[j]);

    float4 h3[16];
#pragma unroll
    for (int j = 0; j < 16; j++) h3[j] = B3v[j];
#pragma unroll
    for (int k4 = 0; k4 < 16; k4++) {
        float4 hv = h2[k4];
#pragma unroll
        for (int j = 0; j < 16; j++) {
            float4 w0 = W3v[(k4 * 4 + 0) * 16 + j];
            float4 w1 = W3v[(k4 * 4 + 1) * 16 + j];
            float4 w2_ = W3v[(k4 * 4 + 2) * 16 + j];
            float4 w3_ = W3v[(k4 * 4 + 3) * 16 + j];
            h3[j].x += hv.x * w0.x + hv.y * w1.x + hv.z * w2_.x + hv.w * w3_.x;
            h3[j].y += hv.x * w0.y + hv.y * w1.y + hv.z * w2_.y + hv.w * w3_.y;
            h3[j].z += hv.x * w0.z + hv.y * w1.z + hv.z * w2_.z + hv.w * w3_.z;
            h3[j].w += hv.x * w0.w + hv.y * w1.w + hv.z * w2_.w + hv.w * w3_.w;
        }
    }

    unsigned short* outp = tA + (size_t)e * 64;
#pragma unroll
    for (int j = 0; j < 16; j++) {
        float4 v = silu4(h3[j]);
        ushort4 pk;
        pk.x = f2bf(v.x); pk.y = f2bf(v.y); pk.z = f2bf(v.z); pk.w = f2bf(v.w);
        *(ushort4*)(outp + j * 4) = pk;
    }
}

// ---------------- rW4 convert: f32 [L][64][512] -> bf16 transposed [L][512][64] ----------------
__global__ __launch_bounds__(64) void k_convW4(
    const float* __restrict__ rW4, unsigned short* __restrict__ W4bt)
{
    int b = blockIdx.x;           // 0..1023 : layer = b>>9, n = b&511
    int layer = b >> 9, n = b & 511;
    int k = threadIdx.x;
    W4bt[((size_t)layer * 512 + n) * 64 + k] = f2bf(rW4[((size_t)layer * 64 + k) * 512 + n]);
}

// ---------------- MFMA GEMM: wbuf[e][n] = tA[e][0:64] @ W4t[n][0:64], bf16 ----------------
__global__ __launch_bounds__(256, 2) void k_wbuf_mfma(
    const unsigned short* __restrict__ tA, const unsigned short* __restrict__ W4t,
    unsigned short* __restrict__ wbuf)
{
    constexpr int MT = 256, NT = 64, AS = 72;   // AS: padded LDS row stride (shorts)
    __shared__ unsigned short Als[MT * AS];     // 36 KB
    __shared__ unsigned short Bls[NT * AS];     // 9 KB
    const int tid = threadIdx.x;
    const int m0 = blockIdx.x * MT;
    const int n0 = blockIdx.y * NT;

    // stage A: 256 rows x 64 shorts (8 x short8 per row)
    for (int idx = tid; idx < MT * 8; idx += 256) {
        int r = idx >> 3, s = idx & 7;
        *(short8*)(Als + r * AS + s * 8) = ((const short8*)tA)[(size_t)(m0 + r) * 8 + s];
    }
    // stage B (already [n][k]): 64 rows x 64 shorts
    for (int idx = tid; idx < NT * 8; idx += 256) {
        int r = idx >> 3, s = idx & 7;
        *(short8*)(Bls + r * AS + s * 8) = ((const short8*)W4t)[(size_t)(n0 + r) * 8 + s];
    }
    __syncthreads();

    const int wave = tid >> 6;
    const int lane = tid & 63;
    const int q = lane >> 4;
    const int l16 = lane & 15;
    const int mw = wave * 64;

    f32x4 acc[4][4];
#pragma unroll
    for (int mi = 0; mi < 4; mi++)
#pragma unroll
        for (int ni = 0; ni < 4; ni++) acc[mi][ni] = (f32x4){0.f, 0.f, 0.f, 0.f};

#pragma unroll
    for (int kc = 0; kc < 2; kc++) {
        short8 a[4], b[4];
#pragma unroll
        for (int mi = 0; mi < 4; mi++)
            a[mi] = *(const short8*)(Als + (mw + mi * 16 + l16) * AS + kc * 32 + q * 8);
#pragma unroll
        for (int ni = 0; ni < 4; ni++)
            b[ni] = *(const short8*)(Bls + (ni * 16 + l16) * AS + kc * 32 + q * 8);
#pragma unroll
        for (int mi = 0; mi < 4; mi++)
#pragma unroll
            for (int ni = 0; ni < 4; ni++)
                acc[mi][ni] = __builtin_amdgcn_mfma_f32_16x16x32_bf16(a[mi], b[ni], acc[mi][ni], 0, 0, 0);
    }

    // epilogue: D[row=q*4+reg][col=l16] per 16x16 tile
#pragma unroll
    for (int mi = 0; mi < 4; mi++) {
#pragma unroll
        for (int ni = 0; ni < 4; ni++) {
#pragma unroll
            for (int r = 0; r < 4; r++) {
                int e = m0 + mw + mi * 16 + q * 4 + r;
                int n = n0 + ni * 16 + l16;
                wbuf[(size_t)e * 512 + n] = f2bf(acc[mi][ni][r]);
            }
        }
    }
}

// ---------------- setup kernels ----------------
__global__ __launch_bounds__(128) void k_node_init(
    const float* __restrict__ na, const float* __restrict__ Wemb,
    const float* __restrict__ aE, const int* __restrict__ batch,
    float* __restrict__ h, float* __restrict__ Eout)
{
    int n = blockIdx.x, c = threadIdx.x;
    float s = 0.f;
#pragma unroll
    for (int k = 0; k < 10; k++) s += na[n * 10 + k] * Wemb[k * C + c];
    h[(size_t)n * C + c] = s;
    if (c == 0) {
        float e = 0.f;
#pragma unroll
        for (int k = 0; k < 10; k++) e += na[n * 10 + k] * aE[k];
        atomicAdd(&Eout[batch[n]], e);
    }
}

__global__ __launch_bounds__(256) void k_ranges(const int* __restrict__ batch, int* __restrict__ gs)
{
    __shared__ int cnt[BG];
    if (threadIdx.x < BG) cnt[threadIdx.x] = 0;
    __syncthreads();
    for (int n = threadIdx.x; n < NA; n += 256) atomicAdd(&cnt[batch[n]], 1);
    __syncthreads();
    if (threadIdx.x == 0) {
        int s = 0;
        for (int b = 0; b < BG; b++) { gs[b] = s; s += cnt[b]; }
        gs[BG] = s;
    }
}

__device__ __forceinline__ float sincn(float x) {
    float px = 3.14159265358979323846f * x;
    return (fabsf(px) < 1e-8f) ? 1.0f : (sinf(px) / px);
}

__global__ __launch_bounds__(128) void k_kspace(
    const float* __restrict__ pos, const float* __restrict__ kgrid,
    float* __restrict__ cosd, float* __restrict__ sind)
{
    int n = blockIdx.x, k = threadIdx.x;
    float p0 = pos[n * 3 + 0], p1 = pos[n * 3 + 1], p2 = pos[n * 3 + 2];
    float sd = sincn(0.1f * p0) * sincn(0.1f * p1) * sincn(0.1f * p2);
    if (k < NK) {
        float d = p0 * kgrid[k * 3 + 0] + p1 * kgrid[k * 3 + 1] + p2 * kgrid[k * 3 + 2];
        float sn, cs;
        sincosf(d, &sn, &cs);
        cosd[(size_t)n * NKP + k] = sd * cs;
        sind[(size_t)n * NKP + k] = sd * sn;
    } else {
        cosd[(size_t)n * NKP + k] = 0.f;
        sind[(size_t)n * NKP + k] = 0.f;
    }
}

__global__ __launch_bounds__(1024) void k_kdown(
    const float* __restrict__ krbf, const float* __restrict__ Wdown, float* __restrict__ kdown)
{
    int t = threadIdx.x;
    if (t < NK * 8) {
        int k = t >> 3, j = t & 7;
        float s = 0.f;
        for (int r = 0; r < 128; r++) s += krbf[k * 128 + r] * Wdown[r * 8 + j];
        kdown[t] = s;
    }
}

__global__ __launch_bounds__(256) void k_edge_geom(
    const float* __restrict__ pos, const float* __restrict__ shifts,
    const int* __restrict__ eidx, float* __restrict__ Y, float* __restrict__ ef)
{
    int e = blockIdx.x * 256 + threadIdx.x;
    if (e >= NE) return;
    int s = eidx[e], d = eidx[NE + e];
    float vx = pos[d * 3 + 0] - pos[s * 3 + 0] + shifts[e * 3 + 0];
    float vy = pos[d * 3 + 1] - pos[s * 3 + 1] + shifts[e * 3 + 1];
    float vz = pos[d * 3 + 2] - pos[s * 3 + 2] + shifts[e * 3 + 2];
    float r = sqrtf(vx * vx + vy * vy + vz * vz);
    float rinv = 1.0f / fmaxf(r, 1e-9f);
    float x = vx * rinv, y = vy * rinv, z = vz * rinv;

    const float s3 = 1.7320508075688772f, s5 = 2.2360679774997896f, s15 = 3.8729833462074170f;
    const float c70 = 2.0916500663351889f;
    const float c105 = 10.246950765959598f;
    const float c42 = 1.6201851746019651f;
    const float c7 = 1.3228756555322954f;
    float o[16];
    o[0] = 1.0f;
    o[1] = s3 * x; o[2] = s3 * y; o[3] = s3 * z;
    o[4] = s15 * x * y; o[5] = s15 * y * z; o[6] = 0.5f * s5 * (3.f * z * z - 1.f);
    o[7] = s15 * x * z; o[8] = 0.5f * s15 * (x * x - y * y);
    o[9]  = c70 * y * (3.f * x * x - y * y);
    o[10] = c105 * x * y * z;
    o[11] = c42 * y * (5.f * z * z - 1.f);
    o[12] = c7 * z * (5.f * z * z - 3.f);
    o[13] = c42 * x * (5.f * z * z - 1.f);
    o[14] = 0.5f * c105 * z * (x * x - y * y);
    o[15] = c70 * x * (x * x - 3.f * y * y);
    float4* Y4 = (float4*)(Y + (size_t)e * 16);
    Y4[0] = make_float4(o[0], o[1], o[2], o[3]);
    Y4[1] = make_float4(o[4], o[5], o[6], o[7]);
    Y4[2] = make_float4(o[8], o[9], o[10], o[11]);
    Y4[3] = make_float4(o[12], o[13], o[14], o[15]);

    float uu = fminf(fmaxf(r * 0.2f, 0.f), 1.f);
    float u2 = uu * uu, u4 = u2 * u2, u5 = u4 * uu, u6 = u5 * uu, u7 = u6 * uu;
    float env = 1.f - 21.f * u5 + 35.f * u6 - 15.f * u7;
    env = (r < 5.0f) ? env : 0.0f;
    float pref = 0.63245553203367587f * rinv * env;
    const float pio5 = 0.62831853071795865f;
    float efv[8];
#pragma unroll
    for (int n1 = 1; n1 <= 8; n1++) efv[n1 - 1] = pref * sinf(n1 * pio5 * r);
    float4* E4 = (float4*)(ef + (size_t)e * 8);
    E4[0] = make_float4(efv[0], efv[1], efv[2], efv[3]);
    E4[1] = make_float4(efv[4], efv[5], efv[6], efv[7]);
}

// ---------------- CSR by dst ----------------
__global__ __launch_bounds__(256) void k_count(const int* __restrict__ eidx, int* __restrict__ deg)
{
    int e = blockIdx.x * 256 + threadIdx.x;
    if (e < NE) atomicAdd(&deg[eidx[NE + e]], 1);
}

__global__ __launch_bounds__(1024) void k_scan(
    const int* __restrict__ deg, int* __restrict__ offs, int* __restrict__ cursor)
{
    __shared__ int sc[1024];
    int tid = threadIdx.x;
    int base = tid * 4;
    int v[4]; int s = 0;
#pragma unroll
    for (int i = 0; i < 4; i++) {
        int idx = base + i;
        int d = (idx < NA) ? deg[idx] : 0;
        v[i] = s; s += d;
    }
    sc[tid] = s;
    __syncthreads();
    for (int ofs = 1; ofs < 1024; ofs <<= 1) {
        int t = (tid >= ofs) ? sc[tid - ofs] : 0;
        __syncthreads();
        sc[tid] += t;
        __syncthreads();
    }
    int excl = (tid > 0) ? sc[tid - 1] : 0;
#pragma unroll
    for (int i = 0; i < 4; i++) {
        int idx = base + i;
        if (idx < NA) { int o = excl + v[i]; offs[idx] = o; cursor[idx] = o; }
    }
    if (tid == 1023) offs[NA] = sc[1023];
}

__global__ __launch_bounds__(256) void k_fill(
    const int* __restrict__ eidx, int* __restrict__ cursor, int* __restrict__ perm)
{
    int e = blockIdx.x * 256 + threadIdx.x;
    if (e < NE) {
        int d = eidx[NE + e];
        int p = atomicAdd(&cursor[d], 1);
        perm[p] = e;
    }
}

// ---------------- Ewald kernels ----------------
__global__ __launch_bounds__(128) void k_kfilter(
    const float* __restrict__ kdown, const float* __restrict__ WupE, float* __restrict__ kf)
{
    int k = blockIdx.x, c = threadIdx.x;
    float s = 0.f;
#pragma unroll
    for (int j = 0; j < 8; j++) s += kdown[k * 8 + j] * WupE[j * C + c];
    kf[(size_t)k * C + c] = s;
}

__global__ __launch_bounds__(256, 4) void k_sf(
    const float* __restrict__ hres, const float* __restrict__ cosd, const float* __restrict__ sind,
    const int* __restrict__ gs, const float* __restrict__ kf,
    float* __restrict__ sfr, float* __restrict__ sfi)
{
    constexpr int SPLIT = 8;
    const int b = blockIdx.x, kt = blockIdx.y, sp = blockIdx.z;
    const int n0 = gs[b], n1 = gs[b + 1];
    const int cnt = n1 - n0;
    const int per = (cnt + SPLIT - 1) / SPLIT;
    const int cs = n0 + sp * per;
    const int ce = min(cs + per, n1);

    __shared__ float Hs[32 * 128];
    __shared__ float Cs[32 * 32];
    __shared__ float Ss[32 * 32];

    const int tid = threadIdx.x;
    const int tx = tid & 31;
    const int ty = tid >> 5;

    float accR[4][4], accI[4][4];
#pragma unroll
    for (int i = 0; i < 4; i++)
#pragma unroll
        for (int j = 0; j < 4; j++) { accR[i][j] = 0.f; accI[i][j] = 0.f; }

    float4* H4 = (float4*)Hs;
    float4* C4 = (float4*)Cs;
    float4* S4 = (float4*)Ss;

    for (int nb = cs; nb < ce; nb += 32) {
        __syncthreads();
        for (int idx = tid; idx < 32 * 32; idx += 256) {
            int r = idx >> 5, c4 = idx & 31;
            int n = nb + r;
            H4[idx] = (n < ce) ? ((const float4*)hres)[(size_t)n * 32 + c4]
                               : make_float4(0.f, 0.f, 0.f, 0.f);
        }
        for (int idx = tid; idx < 32 * 8; idx += 256) {
            int r = idx >> 3, k4 = idx & 7;
            int n = nb + r;
            float4 cv = make_float4(0.f, 0.f, 0.f, 0.f), sv = cv;
            if (n < ce) {
                cv = ((const float4*)cosd)[(size_t)n * 32 + kt * 8 + k4];
                sv = ((const float4*)sind)[(size_t)n * 32 + kt * 8 + k4];
            }
            C4[idx] = cv;
            S4[idx] = sv;
        }
        __syncthreads();
        const int lim = min(32, ce - nb);
        for (int n = 0; n < lim; n++) {
            float4 hv = H4[n * 32 + tx];
            float4 cv = C4[n * 8 + ty];
            float4 sv = S4[n * 8 + ty];
            float h[4] = { hv.x, hv.y, hv.z, hv.w };
            float ck[4] = { cv.x, cv.y, cv.z, cv.w };
            float sk[4] = { sv.x, sv.y, sv.z, sv.w };
#pragma unroll
            for (int i = 0; i < 4; i++)
#pragma unroll
                for (int j = 0; j < 4; j++) {
                    accR[i][j] += ck[i] * h[j];
                    accI[i][j] += sk[i] * h[j];
                }
        }
    }

    const int kbase = kt * 32 + ty * 4;
#pragma unroll
    for (int i = 0; i < 4; i++) {
        int k = kbase + i;
        if (k < NK) {
            float4 kfv = ((const float4*)kf)[(size_t)k * 32 + tx];
            float vx = kfv.x * 0.01f, vy = kfv.y * 0.01f, vz = kfv.z * 0.01f, vw = kfv.w * 0.01f;
            float* pR = sfr + ((size_t)(b * NK + k)) * C + tx * 4;
            float* pI = sfi + ((size_t)(b * NK + k)) * C + tx * 4;
            atomicAdd(pR + 0, accR[i][0] * vx);
            atomicAdd(pR + 1, accR[i][1] * vy);
            atomicAdd(pR + 2, accR[i][2] * vz);
            atomicAdd(pR + 3, accR[i][3] * vw);
            atomicAdd(pI + 0, accI[i][0] * vx);
            atomicAdd(pI + 1, accI[i][1] * vy);
            atomicAdd(pI + 2, accI[i][2] * vz);
            atomicAdd(pI + 3, accI[i][3] * vw);
        }
    }
}

__global__ __launch_bounds__(128) void k_he(
    const float* __restrict__ cosd, const float* __restrict__ sind,
    const float* __restrict__ sfr, const float* __restrict__ sfi,
    const int* __restrict__ batch, float* __restrict__ out)
{
    int n = blockIdx.x, c = threadIdx.x;
    int b = batch[n];
    const float* pr = sfr + (size_t)b * NK * C;
    const float* pi = sfi + (size_t)b * NK * C;
    const float* cdp = cosd + (size_t)n * NKP;
    const float* sdp = sind + (size_t)n * NKP;
    float acc = 0.f;
    for (int k = 0; k < NK; k++) {
        acc += cdp[k] * pr[(size_t)k * C + c] + sdp[k] * pi[(size_t)k * C + c];
    }
    out[(size_t)n * C + c] = acc;
}

// ---------------- message gather + symmetric contraction ----------------
__global__ __launch_bounds__(128) void k_gather(
    const unsigned short* __restrict__ wbuf, const float* __restrict__ hu,
    const float* __restrict__ Y, const int* __restrict__ srcArr,
    const int* __restrict__ offs, const int* __restrict__ perm,
    const float* __restrict__ w2, const float* __restrict__ w3,
    float* __restrict__ feats)
{
    int n = blockIdx.x, c = threadIdx.x;
    int j0 = offs[n], j1 = offs[n + 1];
    float A[16];
#pragma unroll
    for (int s = 0; s < 16; s++) A[s] = 0.f;
    for (int j = j0; j < j1; j++) {
        int e = perm[j];
        int s = srcArr[e];
        float huc = hu[(size_t)s * C + c];
        ushort4 wv = *(const ushort4*)(wbuf + (size_t)e * 512 + c * 4);
        const float4* Yp = (const float4*)(Y + (size_t)e * 16);
        float4 y0 = Yp[0], y1 = Yp[1], y2 = Yp[2], y3 = Yp[3];
        float m0 = bf2f(wv.x) * huc, m1 = bf2f(wv.y) * huc;
        float m2 = bf2f(wv.z) * huc, m3 = bf2f(wv.w) * huc;
        A[0] += m0 * y0.x;
        A[1] += m1 * y0.y;  A[2]  += m1 * y0.z;  A[3]  += m1 * y0.w;
        A[4] += m2 * y1.x;  A[5]  += m2 * y1.y;  A[6]  += m2 * y1.z;  A[7] += m2 * y1.w;
        A[8] += m2 * y2.x;
        A[9] += m3 * y2.y;  A[10] += m3 * y2.z;  A[11] += m3 * y2.w;
        A[12] += m3 * y3.x; A[13] += m3 * y3.y;  A[14] += m3 * y3.z;  A[15] += m3 * y3.w;
    }
    const float inv = 1.0f / AVGN;
#pragma unroll
    for (int s = 0; s < 16; s++) A[s] *= inv;
    float scal = A[0];
    float i0 = A[0] * A[0];
    float i1 = A[1] * A[1] + A[2] * A[2] + A[3] * A[3];
    float i2 = A[4] * A[4] + A[5] * A[5] + A[6] * A[6] + A[7] * A[7] + A[8] * A[8];
    float i3 = A[9] * A[9] + A[10] * A[10] + A[11] * A[11] + A[12] * A[12] +
               A[13] * A[13] + A[14] * A[14] + A[15] * A[15];
    float t2 = i0 * w2[c] + i1 * w2[C + c] + i2 * w2[2 * C + c] + i3 * w2[3 * C + c];
    float t3 = i0 * w3[c] + i1 * w3[C + c] + i2 * w3[2 * C + c] + i3 * w3[3 * C + c];
    feats[(size_t)n * C + c] = scal + t2 + scal * t3;
}

// ---------------- readout energy ----------------
__global__ __launch_bounds__(128) void k_node_energy(
    const float* __restrict__ h, const int* __restrict__ batch,
    const float* __restrict__ Wr0, const float* __restrict__ Wr1a,
    const float* __restrict__ Wr1b, int mode, float* __restrict__ Eout)
{
    int n = blockIdx.x, t = threadIdx.x;
    __shared__ float hs[128];
    __shared__ float red[16];
    float hv = h[(size_t)n * C + t];
    if (mode == 0) {
        float v = hv * Wr0[t];
#pragma unroll
        for (int o = 32; o; o >>= 1) v += __shfl_down(v, o, 64);
        if ((t & 63) == 0) red[t >> 6] = v;
        __syncthreads();
        if (t == 0) atomicAdd(&Eout[batch[n]], red[0] + red[1]);
    } else {
        hs[t] = hv;
        __syncthreads();
        if (t < 16) {
            float s = 0.f;
#pragma unroll 8
            for (int cc = 0; cc < 128; cc++) s += hs[cc] * Wr1a[cc * 16 + t];
            red[t] = dsilu(s) * Wr1b[t];
        }
        __syncthreads();
        if (t == 0) {
            float s = 0.f;
#pragma unroll
            for (int j = 0; j < 16; j++) s += red[j];
            atomicAdd(&Eout[batch[n]], s);
        }
    }
}

// ---------------- workspace layout (floats) ----------------
constexpr size_t NAC   = (size_t)NA * C;
constexpr size_t F_COSD = 0;
constexpr size_t F_SIND = F_COSD + (size_t)NA * NKP;
constexpr size_t F_Y    = F_SIND + (size_t)NA * NKP;
constexpr size_t F_EF   = F_Y + (size_t)NE * 16;
constexpr size_t F_H    = F_EF + (size_t)NE * 8;
constexpr size_t F_HN   = F_H + NAC;
constexpr size_t F_HRES = F_HN + NAC;
constexpr size_t F_T1   = F_HRES + NAC;
constexpr size_t F_T2   = F_T1 + NAC;
constexpr size_t F_HE2  = F_T2 + NAC;
constexpr size_t F_HU   = F_HE2 + NAC;
constexpr size_t F_FE   = F_HU + NAC;
constexpr size_t F_TA   = F_FE + NAC;                // bf16 tA: NE*64 shorts (fits NE*64 f32)
constexpr size_t F_TB   = F_TA + (size_t)NE * 64;    // reused: W4bt bf16 2*512*64 shorts
constexpr size_t F_W    = F_TB + (size_t)NE * 64;    // bf16 wbuf: NE*512 shorts
constexpr size_t F_SFR  = F_W + (size_t)NE * 512;
constexpr size_t F_SFI  = F_SFR + (size_t)BG * NK * C;
constexpr size_t F_KD   = F_SFI + (size_t)BG * NK * C;
constexpr size_t F_KF   = F_KD + 1024;
constexpr size_t F_END  = F_KF + (size_t)NK * C;
constexpr size_t I_BASE = ((F_END * 4 + 255) / 256) * 256;

extern "C" void kernel_launch(void* const* d_in, const int* in_sizes, int n_in,
                              void* d_out, int out_size, void* d_ws, size_t ws_size,
                              hipStream_t stream) {
    const float* pos    = (const float*)d_in[0];
    const float* na     = (const float*)d_in[1];
    const float* shifts = (const float*)d_in[2];
    const int*   eidx   = (const int*)d_in[3];
    const int*   batch  = (const int*)d_in[4];
    const float* kgrid  = (const float*)d_in[5];
    const float* krbf   = (const float*)d_in[6];
    const float* Wemb   = (const float*)d_in[7];
    const float* aE     = (const float*)d_in[8];
    const float* rW1    = (const float*)d_in[9];
    const float* rb1    = (const float*)d_in[10];
    const float* rW2    = (const float*)d_in[11];
    const float* rb2    = (const float*)d_in[12];
    const float* rW3    = (const float*)d_in[13];
    const float* rb3    = (const float*)d_in[14];
    const float* rW4    = (const float*)d_in[15];
    const float* Wup    = (const float*)d_in[16];
    const float* w2     = (const float*)d_in[17];
    const float* w3     = (const float*)d_in[18];
    const float* Wmix   = (const float*)d_in[19];
    const float* Wr0    = (const float*)d_in[20];
    const float* Wr1a   = (const float*)d_in[21];
    const float* Wr1b   = (const float*)d_in[22];
    const float* Wdown  = (const float*)d_in[23];
    const float* WupE   = (const float*)d_in[24];
    const float* Wpre1  = (const float*)d_in[25];
    const float* bpre1  = (const float*)d_in[26];
    const float* Wpre2  = (const float*)d_in[27];
    const float* bpre2  = (const float*)d_in[28];
    const float* Wm1    = (const float*)d_in[29];
    const float* bm1    = (const float*)d_in[30];
    const float* Wm2    = (const float*)d_in[31];
    const float* bm2    = (const float*)d_in[32];

    float* fw = (float*)d_ws;
    float* cosd = fw + F_COSD;
    float* sind = fw + F_SIND;
    float* Ybuf = fw + F_Y;
    float* efb  = fw + F_EF;
    float* h    = fw + F_H;
    float* hn   = fw + F_HN;
    float* hres = fw + F_HRES;
    float* t1   = fw + F_T1;
    float* t2   = fw + F_T2;
    float* he2  = fw + F_HE2;
    float* hu   = fw + F_HU;
    float* fe   = fw + F_FE;
    unsigned short* tA   = (unsigned short*)(fw + F_TA);
    unsigned short* W4bt = (unsigned short*)(fw + F_TB);
    unsigned short* wbuf = (unsigned short*)(fw + F_W);
    float* sfr  = fw + F_SFR;
    float* sfi  = fw + F_SFI;
    float* kdwn = fw + F_KD;
    float* kfil = fw + F_KF;

    int* ip     = (int*)((char*)d_ws + I_BASE);
    int* deg    = ip;
    int* offs   = ip + NA;
    int* cursor = ip + 2 * NA + 1;
    int* perm   = ip + 3 * NA + 1;
    int* gs     = perm + NE;

    float* Eout = (float*)d_out;

    hipMemsetAsync(Eout, 0, BG * sizeof(float), stream);
    hipMemsetAsync(deg, 0, NA * sizeof(int), stream);

    k_node_init<<<NA, 128, 0, stream>>>(na, Wemb, aE, batch, h, Eout);
    k_ranges<<<1, 256, 0, stream>>>(batch, gs);
    k_kspace<<<NA, 128, 0, stream>>>(pos, kgrid, cosd, sind);
    k_kdown<<<1, 1024, 0, stream>>>(krbf, Wdown, kdwn);
    k_edge_geom<<<NE / 256, 256, 0, stream>>>(pos, shifts, eidx, Ybuf, efb);
    k_count<<<NE / 256, 256, 0, stream>>>(eidx, deg);
    k_scan<<<1, 1024, 0, stream>>>(deg, offs, cursor);
    k_fill<<<NE / 256, 256, 0, stream>>>(eidx, cursor, perm);
    k_convW4<<<1024, 64, 0, stream>>>(rW4, W4bt);

    const dim3 gA(NA / 64, C / 64);
    const dim3 gDual(NA / 64, 4);
    const dim3 gSF(BG, 4, 8);
    const dim3 gWB(NE / 256, 512 / 64);

    for (int i = 0; i < 2; i++) {
        const float* Wpre1_i = Wpre1 + (size_t)i * C * C;
        const float* bpre1_i = bpre1 + (size_t)i * C;
        const float* Wpre2_i = Wpre2 + (size_t)i * C * C;
        const float* bpre2_i = bpre2 + (size_t)i * C;
        const float* WupE_i  = WupE + (size_t)i * 8 * C;
        const float* Wm1_i   = Wm1 + (size_t)i * C * C;
        const float* bm1_i   = bm1 + (size_t)i * C;
        const float* Wm2_i   = Wm2 + (size_t)i * C * C;
        const float* bm2_i   = bm2 + (size_t)i * C;
        const float* Wup_i   = Wup + (size_t)i * C * C;
        const float* rW1_i   = rW1 + (size_t)i * 8 * 64;
        const float* rb1_i   = rb1 + (size_t)i * 64;
        const float* rW2_i   = rW2 + (size_t)i * 64 * 64;
        const float* rb2_i   = rb2 + (size_t)i * 64;
        const float* rW3_i   = rW3 + (size_t)i * 64 * 64;
        const float* rb3_i   = rb3 + (size_t)i * 64;
        const float* w2_i    = w2 + (size_t)i * 4 * C;
        const float* w3_i    = w3 + (size_t)i * 4 * C;
        const float* Wmix_i  = Wmix + (size_t)i * C * C;
        const unsigned short* W4bt_i = W4bt + (size_t)i * 512 * 64;

        // dual: t1 = silu(h@Wpre1+b), hu = h@Wup
        gemm_dual<<<gDual, 256, 0, stream>>>(h, Wpre1_i, Wup_i, bpre1_i, t1, hu);
        gemm_kernel<128, 0, 0><<<gA, 256, 0, stream>>>(t1, Wpre2_i, bpre2_i, h, nullptr, hres, NA, C, 1.f);

        // edge branch
        k_rmlp<<<NE / 256, 256, 0, stream>>>(efb, rW1_i, rb1_i, rW2_i, rb2_i, rW3_i, rb3_i, tA);
        k_wbuf_mfma<<<gWB, 256, 0, stream>>>(tA, W4bt_i, wbuf);

        // Ewald branch
        k_kfilter<<<NK, 128, 0, stream>>>(kdwn, WupE_i, kfil);
        hipMemsetAsync(sfr, 0, 2 * (size_t)BG * NK * C * sizeof(float), stream);
        k_sf<<<gSF, 256, 0, stream>>>(hres, cosd, sind, gs, kfil, sfr, sfi);
        k_he<<<NA, 128, 0, stream>>>(cosd, sind, sfr, sfi, batch, t1);
        gemm_kernel<128, 1, 0><<<gA, 256, 0, stream>>>(t1, Wm1_i, bm1_i, nullptr, nullptr, t2, NA, C, 1.f);
        gemm_kernel<128, 1, 0><<<gA, 256, 0, stream>>>(t2, Wm2_i, bm2_i, nullptr, nullptr, he2, NA, C, 1.f);

        // gather + combine
        k_gather<<<NA, 128, 0, stream>>>(wbuf, hu, Ybuf, eidx, offs, perm, w2_i, w3_i, fe);
        gemm_kernel<128, 0, 0><<<gA, 256, 0, stream>>>(fe, Wmix_i, nullptr, h, he2, hn, NA, C, SKIPF);
        k_node_energy<<<NA, 128, 0, stream>>>(hn, batch, Wr0, Wr1a, Wr1b, (i == 0) ? 0 : 1, Eout);

        float* tmp = h; h = hn; hn = tmp;
    }
}

// Round 5
// 673.707 us; speedup vs baseline: 1.1410x; 1.1410x over previous
//
#include <hip/hip_runtime.h>
#include <hip/hip_bf16.h>
#include <math.h>

// ---------------- problem constants ----------------
constexpr int NA  = 3200;     // atoms
constexpr int NE  = 51200;    // edges
constexpr int C   = 128;      // channels
constexpr int NK  = 123;      // k-points with |k| <= 0.6
constexpr int NKP = 128;      // padded stride for cosd/sind
constexpr int BG  = 8;        // graphs
constexpr float SKIPF = 0.57735026918962576f;  // 3^-0.5
constexpr float AVGN  = 16.0f;

__device__ __forceinline__ float dsilu(float x) { return x / (1.0f + expf(-x)); }

__device__ __forceinline__ unsigned short f2bf(float f) {
    unsigned int u = __float_as_uint(f);
    unsigned int r = (u + 0x7fffu + ((u >> 16) & 1u)) >> 16;
    return (unsigned short)r;
}
__device__ __forceinline__ float bf2f(unsigned short s) {
    return __uint_as_float(((unsigned int)s) << 16);
}

typedef __attribute__((ext_vector_type(8))) short short8;
typedef __attribute__((ext_vector_type(4))) float f32x4;

// ---------------- generic tiled f32 GEMM ----------------
template <int K, int ACT, int OBF16>
__global__ __launch_bounds__(256, 4) void gemm_kernel(
    const float* __restrict__ X, const float* __restrict__ W,
    const float* __restrict__ bias, const float* __restrict__ res1,
    const float* __restrict__ res2, void* __restrict__ outv,
    int M, int N, float scale)
{
    constexpr int K4 = K / 4;
    constexpr int BK  = (K < 64) ? K : 64;
    constexpr int BK4 = BK / 4;
    constexpr int BK4P = BK4 + 1;
    __shared__ float As[64 * BK4P * 4];
    __shared__ float Bs[BK * 64];
    const int tid = threadIdx.x;
    const int m0 = blockIdx.x * 64;
    const int n0 = blockIdx.y * 64;

    const float4* X4 = (const float4*)X;
    const float4* W4 = (const float4*)W;
    float4* As4 = (float4*)As;
    float4* Bs4 = (float4*)Bs;
    const int N4 = N >> 2;

    const int tx = tid & 15;
    const int ty = tid >> 4;
    float acc[4][4];
#pragma unroll
    for (int i = 0; i < 4; i++)
#pragma unroll
        for (int j = 0; j < 4; j++) acc[i][j] = 0.0f;

    for (int k0 = 0; k0 < K4; k0 += BK4) {
        if (k0) __syncthreads();
        for (int idx = tid; idx < 64 * BK4; idx += 256) {
            int r = idx / BK4, k4 = idx - r * BK4;
            As4[r * BK4P + k4] = X4[(size_t)(m0 + r) * K4 + k0 + k4];
        }
        for (int idx = tid; idx < BK * 16; idx += 256) {
            int kr = idx >> 4, c4 = idx & 15;
            Bs4[idx] = W4[(size_t)(k0 * 4 + kr) * N4 + (n0 >> 2) + c4];
        }
        __syncthreads();

#pragma unroll 4
        for (int k4 = 0; k4 < BK4; k4++) {
            float a[4][4];
#pragma unroll
            for (int i = 0; i < 4; i++) {
                float4 av = As4[(ty * 4 + i) * BK4P + k4];
                a[i][0] = av.x; a[i][1] = av.y; a[i][2] = av.z; a[i][3] = av.w;
            }
#pragma unroll
            for (int kk = 0; kk < 4; kk++) {
                float4 bv = Bs4[(k4 * 4 + kk) * 16 + tx];
#pragma unroll
                for (int i = 0; i < 4; i++) {
                    acc[i][0] += a[i][kk] * bv.x;
                    acc[i][1] += a[i][kk] * bv.y;
                    acc[i][2] += a[i][kk] * bv.z;
                    acc[i][3] += a[i][kk] * bv.w;
                }
            }
        }
    }

    float4 bv = make_float4(0.f, 0.f, 0.f, 0.f);
    if (bias) bv = ((const float4*)bias)[(n0 >> 2) + tx];
#pragma unroll
    for (int i = 0; i < 4; i++) {
        int row = m0 + ty * 4 + i;
        size_t o = (size_t)row * N + n0 + tx * 4;
        float4 v;
        v.x = acc[i][0] + bv.x; v.y = acc[i][1] + bv.y;
        v.z = acc[i][2] + bv.z; v.w = acc[i][3] + bv.w;
        if (ACT) { v.x = dsilu(v.x); v.y = dsilu(v.y); v.z = dsilu(v.z); v.w = dsilu(v.w); }
        if (res1) { float4 r = *(const float4*)(res1 + o); v.x += r.x; v.y += r.y; v.z += r.z; v.w += r.w; }
        if (res2) { float4 r = *(const float4*)(res2 + o); v.x += r.x; v.y += r.y; v.z += r.z; v.w += r.w; }
        v.x *= scale; v.y *= scale; v.z *= scale; v.w *= scale;
        if (OBF16) {
            ushort4 pk;
            pk.x = f2bf(v.x); pk.y = f2bf(v.y); pk.z = f2bf(v.z); pk.w = f2bf(v.w);
            *(ushort4*)((unsigned short*)outv + o) = pk;
        } else {
            *(float4*)((float*)outv + o) = v;
        }
    }
}

// ---------------- dual GEMM: t1 = silu(h@Wa + bias), hu = h@Wb ----------------
__global__ __launch_bounds__(256, 4) void gemm_dual(
    const float* __restrict__ X, const float* __restrict__ Wa,
    const float* __restrict__ Wb, const float* __restrict__ bias,
    float* __restrict__ outa, float* __restrict__ outb)
{
    constexpr int K4 = 32, BK4 = 16, BK4P = 17;
    __shared__ float As[64 * BK4P * 4];
    __shared__ float Bs[64 * 64];
    const int tid = threadIdx.x;
    const int m0 = blockIdx.x * 64;
    const int sel = blockIdx.y >> 1;
    const int n0 = (blockIdx.y & 1) * 64;
    const float* W = sel ? Wb : Wa;
    float* out = sel ? outb : outa;

    const float4* X4 = (const float4*)X;
    const float4* W4 = (const float4*)W;
    float4* As4 = (float4*)As;
    float4* Bs4 = (float4*)Bs;

    const int tx = tid & 15;
    const int ty = tid >> 4;
    float acc[4][4];
#pragma unroll
    for (int i = 0; i < 4; i++)
#pragma unroll
        for (int j = 0; j < 4; j++) acc[i][j] = 0.0f;

    for (int k0 = 0; k0 < K4; k0 += BK4) {
        if (k0) __syncthreads();
        for (int idx = tid; idx < 64 * BK4; idx += 256) {
            int r = idx / BK4, k4 = idx - r * BK4;
            As4[r * BK4P + k4] = X4[(size_t)(m0 + r) * K4 + k0 + k4];
        }
        for (int idx = tid; idx < 64 * 16; idx += 256) {
            int kr = idx >> 4, c4 = idx & 15;
            Bs4[idx] = W4[(size_t)(k0 * 4 + kr) * 32 + (n0 >> 2) + c4];
        }
        __syncthreads();

#pragma unroll 4
        for (int k4 = 0; k4 < BK4; k4++) {
            float a[4][4];
#pragma unroll
            for (int i = 0; i < 4; i++) {
                float4 av = As4[(ty * 4 + i) * BK4P + k4];
                a[i][0] = av.x; a[i][1] = av.y; a[i][2] = av.z; a[i][3] = av.w;
            }
#pragma unroll
            for (int kk = 0; kk < 4; kk++) {
                float4 bv = Bs4[(k4 * 4 + kk) * 16 + tx];
#pragma unroll
                for (int i = 0; i < 4; i++) {
                    acc[i][0] += a[i][kk] * bv.x;
                    acc[i][1] += a[i][kk] * bv.y;
                    acc[i][2] += a[i][kk] * bv.z;
                    acc[i][3] += a[i][kk] * bv.w;
                }
            }
        }
    }

    float4 bv = make_float4(0.f, 0.f, 0.f, 0.f);
    if (!sel) bv = ((const float4*)bias)[(n0 >> 2) + tx];
#pragma unroll
    for (int i = 0; i < 4; i++) {
        int row = m0 + ty * 4 + i;
        size_t o = (size_t)row * 128 + n0 + tx * 4;
        float4 v;
        v.x = acc[i][0] + bv.x; v.y = acc[i][1] + bv.y;
        v.z = acc[i][2] + bv.z; v.w = acc[i][3] + bv.w;
        if (!sel) { v.x = dsilu(v.x); v.y = dsilu(v.y); v.z = dsilu(v.z); v.w = dsilu(v.w); }
        *(float4*)(out + o) = v;
    }
}

// ---------------- MFMA MLP layer: out = silu(X @ Wt^T + bias), all bf16 ----------------
// X: NE x 64 bf16.  Wt: 64 x 64 bf16 stored [n][k].  out: NE x 64 bf16.
// grid: NE/128 blocks of 128 threads (2 waves, 64 edges each).
__global__ __launch_bounds__(128, 2) void k_mlp_mfma(
    const unsigned short* __restrict__ X, const unsigned short* __restrict__ Wt,
    const float* __restrict__ bias, unsigned short* __restrict__ out)
{
    constexpr int MT = 128, AS = 72;
    __shared__ unsigned short Als[MT * AS];  // 18 KB
    __shared__ unsigned short Bls[64 * AS];  // 9 KB
    const int tid = threadIdx.x;
    const int m0 = blockIdx.x * MT;

    for (int idx = tid; idx < MT * 8; idx += 128) {
        int r = idx >> 3, s = idx & 7;
        *(short8*)(Als + r * AS + s * 8) = ((const short8*)X)[(size_t)(m0 + r) * 8 + s];
    }
    for (int idx = tid; idx < 64 * 8; idx += 128) {
        int r = idx >> 3, s = idx & 7;
        *(short8*)(Bls + r * AS + s * 8) = ((const short8*)Wt)[(size_t)r * 8 + s];
    }
    __syncthreads();

    const int wave = tid >> 6;
    const int lane = tid & 63;
    const int q = lane >> 4;
    const int l16 = lane & 15;
    const int mw = wave * 64;

    f32x4 acc[4][4];
#pragma unroll
    for (int mi = 0; mi < 4; mi++)
#pragma unroll
        for (int ni = 0; ni < 4; ni++) acc[mi][ni] = (f32x4){0.f, 0.f, 0.f, 0.f};

#pragma unroll
    for (int kc = 0; kc < 2; kc++) {
        short8 a[4], b[4];
#pragma unroll
        for (int mi = 0; mi < 4; mi++)
            a[mi] = *(const short8*)(Als + (mw + mi * 16 + l16) * AS + kc * 32 + q * 8);
#pragma unroll
        for (int ni = 0; ni < 4; ni++)
            b[ni] = *(const short8*)(Bls + (ni * 16 + l16) * AS + kc * 32 + q * 8);
#pragma unroll
        for (int mi = 0; mi < 4; mi++)
#pragma unroll
            for (int ni = 0; ni < 4; ni++)
                acc[mi][ni] = __builtin_amdgcn_mfma_f32_16x16x32_bf16(a[mi], b[ni], acc[mi][ni], 0, 0, 0);
    }

#pragma unroll
    for (int ni = 0; ni < 4; ni++) {
        float bv = bias[ni * 16 + l16];
#pragma unroll
        for (int mi = 0; mi < 4; mi++) {
#pragma unroll
            for (int r = 0; r < 4; r++) {
                int e = m0 + mw + mi * 16 + q * 4 + r;
                int n = ni * 16 + l16;
                out[(size_t)e * 64 + n] = f2bf(dsilu(acc[mi][ni][r] + bv));
            }
        }
    }
}

// ---------------- weight converts ----------------
// rW4 f32 [L][64][512] -> bf16 transposed [L][512][64]
__global__ __launch_bounds__(64) void k_convW4(
    const float* __restrict__ rW4, unsigned short* __restrict__ W4bt)
{
    int b = blockIdx.x;           // layer = b>>9, n = b&511
    int layer = b >> 9, n = b & 511;
    int k = threadIdx.x;
    W4bt[((size_t)layer * 512 + n) * 64 + k] = f2bf(rW4[((size_t)layer * 64 + k) * 512 + n]);
}

// rW f32 [L][64][64] -> bf16 transposed [L][64][64] ([n][k])
__global__ __launch_bounds__(64) void k_convW64(
    const float* __restrict__ rW, unsigned short* __restrict__ Wbt)
{
    int b = blockIdx.x;           // layer = b>>6, n = b&63
    int layer = b >> 6, n = b & 63;
    int k = threadIdx.x;
    Wbt[((size_t)layer * 64 + n) * 64 + k] = f2bf(rW[((size_t)layer * 64 + k) * 64 + n]);
}

// ---------------- MFMA GEMM: wbuf[e][n] = tA[e][0:64] @ W4t[n][0:64], bf16 ----------------
__global__ __launch_bounds__(256, 2) void k_wbuf_mfma(
    const unsigned short* __restrict__ tA, const unsigned short* __restrict__ W4t,
    unsigned short* __restrict__ wbuf)
{
    constexpr int MT = 256, NT = 64, AS = 72;
    __shared__ unsigned short Als[MT * AS];
    __shared__ unsigned short Bls[NT * AS];
    const int tid = threadIdx.x;
    const int m0 = blockIdx.x * MT;
    const int n0 = blockIdx.y * NT;

    for (int idx = tid; idx < MT * 8; idx += 256) {
        int r = idx >> 3, s = idx & 7;
        *(short8*)(Als + r * AS + s * 8) = ((const short8*)tA)[(size_t)(m0 + r) * 8 + s];
    }
    for (int idx = tid; idx < NT * 8; idx += 256) {
        int r = idx >> 3, s = idx & 7;
        *(short8*)(Bls + r * AS + s * 8) = ((const short8*)W4t)[(size_t)(n0 + r) * 8 + s];
    }
    __syncthreads();

    const int wave = tid >> 6;
    const int lane = tid & 63;
    const int q = lane >> 4;
    const int l16 = lane & 15;
    const int mw = wave * 64;

    f32x4 acc[4][4];
#pragma unroll
    for (int mi = 0; mi < 4; mi++)
#pragma unroll
        for (int ni = 0; ni < 4; ni++) acc[mi][ni] = (f32x4){0.f, 0.f, 0.f, 0.f};

#pragma unroll
    for (int kc = 0; kc < 2; kc++) {
        short8 a[4], b[4];
#pragma unroll
        for (int mi = 0; mi < 4; mi++)
            a[mi] = *(const short8*)(Als + (mw + mi * 16 + l16) * AS + kc * 32 + q * 8);
#pragma unroll
        for (int ni = 0; ni < 4; ni++)
            b[ni] = *(const short8*)(Bls + (ni * 16 + l16) * AS + kc * 32 + q * 8);
#pragma unroll
        for (int mi = 0; mi < 4; mi++)
#pragma unroll
            for (int ni = 0; ni < 4; ni++)
                acc[mi][ni] = __builtin_amdgcn_mfma_f32_16x16x32_bf16(a[mi], b[ni], acc[mi][ni], 0, 0, 0);
    }

#pragma unroll
    for (int mi = 0; mi < 4; mi++) {
#pragma unroll
        for (int ni = 0; ni < 4; ni++) {
#pragma unroll
            for (int r = 0; r < 4; r++) {
                int e = m0 + mw + mi * 16 + q * 4 + r;
                int n = n0 + ni * 16 + l16;
                wbuf[(size_t)e * 512 + n] = f2bf(acc[mi][ni][r]);
            }
        }
    }
}

// ---------------- setup kernels ----------------
__global__ __launch_bounds__(128) void k_node_init(
    const float* __restrict__ na, const float* __restrict__ Wemb,
    const float* __restrict__ aE, const int* __restrict__ batch,
    float* __restrict__ h, float* __restrict__ Eout)
{
    int n = blockIdx.x, c = threadIdx.x;
    float s = 0.f;
#pragma unroll
    for (int k = 0; k < 10; k++) s += na[n * 10 + k] * Wemb[k * C + c];
    h[(size_t)n * C + c] = s;
    if (c == 0) {
        float e = 0.f;
#pragma unroll
        for (int k = 0; k < 10; k++) e += na[n * 10 + k] * aE[k];
        atomicAdd(&Eout[batch[n]], e);
    }
}

__global__ __launch_bounds__(256) void k_ranges(const int* __restrict__ batch, int* __restrict__ gs)
{
    __shared__ int cnt[BG];
    if (threadIdx.x < BG) cnt[threadIdx.x] = 0;
    __syncthreads();
    for (int n = threadIdx.x; n < NA; n += 256) atomicAdd(&cnt[batch[n]], 1);
    __syncthreads();
    if (threadIdx.x == 0) {
        int s = 0;
        for (int b = 0; b < BG; b++) { gs[b] = s; s += cnt[b]; }
        gs[BG] = s;
    }
}

__device__ __forceinline__ float sincn(float x) {
    float px = 3.14159265358979323846f * x;
    return (fabsf(px) < 1e-8f) ? 1.0f : (sinf(px) / px);
}

__global__ __launch_bounds__(128) void k_kspace(
    const float* __restrict__ pos, const float* __restrict__ kgrid,
    float* __restrict__ cosd, float* __restrict__ sind)
{
    int n = blockIdx.x, k = threadIdx.x;
    float p0 = pos[n * 3 + 0], p1 = pos[n * 3 + 1], p2 = pos[n * 3 + 2];
    float sd = sincn(0.1f * p0) * sincn(0.1f * p1) * sincn(0.1f * p2);
    if (k < NK) {
        float d = p0 * kgrid[k * 3 + 0] + p1 * kgrid[k * 3 + 1] + p2 * kgrid[k * 3 + 2];
        float sn, cs;
        sincosf(d, &sn, &cs);
        cosd[(size_t)n * NKP + k] = sd * cs;
        sind[(size_t)n * NKP + k] = sd * sn;
    } else {
        cosd[(size_t)n * NKP + k] = 0.f;
        sind[(size_t)n * NKP + k] = 0.f;
    }
}

__global__ __launch_bounds__(1024) void k_kdown(
    const float* __restrict__ krbf, const float* __restrict__ Wdown, float* __restrict__ kdown)
{
    int t = threadIdx.x;
    if (t < NK * 8) {
        int k = t >> 3, j = t & 7;
        float s = 0.f;
        for (int r = 0; r < 128; r++) s += krbf[k * 128 + r] * Wdown[r * 8 + j];
        kdown[t] = s;
    }
}

__global__ __launch_bounds__(256) void k_edge_geom(
    const float* __restrict__ pos, const float* __restrict__ shifts,
    const int* __restrict__ eidx, float* __restrict__ Y, float* __restrict__ ef)
{
    int e = blockIdx.x * 256 + threadIdx.x;
    if (e >= NE) return;
    int s = eidx[e], d = eidx[NE + e];
    float vx = pos[d * 3 + 0] - pos[s * 3 + 0] + shifts[e * 3 + 0];
    float vy = pos[d * 3 + 1] - pos[s * 3 + 1] + shifts[e * 3 + 1];
    float vz = pos[d * 3 + 2] - pos[s * 3 + 2] + shifts[e * 3 + 2];
    float r = sqrtf(vx * vx + vy * vy + vz * vz);
    float rinv = 1.0f / fmaxf(r, 1e-9f);
    float x = vx * rinv, y = vy * rinv, z = vz * rinv;

    const float s3 = 1.7320508075688772f, s5 = 2.2360679774997896f, s15 = 3.8729833462074170f;
    const float c70 = 2.0916500663351889f;
    const float c105 = 10.246950765959598f;
    const float c42 = 1.6201851746019651f;
    const float c7 = 1.3228756555322954f;
    float o[16];
    o[0] = 1.0f;
    o[1] = s3 * x; o[2] = s3 * y; o[3] = s3 * z;
    o[4] = s15 * x * y; o[5] = s15 * y * z; o[6] = 0.5f * s5 * (3.f * z * z - 1.f);
    o[7] = s15 * x * z; o[8] = 0.5f * s15 * (x * x - y * y);
    o[9]  = c70 * y * (3.f * x * x - y * y);
    o[10] = c105 * x * y * z;
    o[11] = c42 * y * (5.f * z * z - 1.f);
    o[12] = c7 * z * (5.f * z * z - 3.f);
    o[13] = c42 * x * (5.f * z * z - 1.f);
    o[14] = 0.5f * c105 * z * (x * x - y * y);
    o[15] = c70 * x * (x * x - 3.f * y * y);
    float4* Y4 = (float4*)(Y + (size_t)e * 16);
    Y4[0] = make_float4(o[0], o[1], o[2], o[3]);
    Y4[1] = make_float4(o[4], o[5], o[6], o[7]);
    Y4[2] = make_float4(o[8], o[9], o[10], o[11]);
    Y4[3] = make_float4(o[12], o[13], o[14], o[15]);

    float uu = fminf(fmaxf(r * 0.2f, 0.f), 1.f);
    float u2 = uu * uu, u4 = u2 * u2, u5 = u4 * uu, u6 = u5 * uu, u7 = u6 * uu;
    float env = 1.f - 21.f * u5 + 35.f * u6 - 15.f * u7;
    env = (r < 5.0f) ? env : 0.0f;
    float pref = 0.63245553203367587f * rinv * env;
    const float pio5 = 0.62831853071795865f;
    float efv[8];
#pragma unroll
    for (int n1 = 1; n1 <= 8; n1++) efv[n1 - 1] = pref * sinf(n1 * pio5 * r);
    float4* E4 = (float4*)(ef + (size_t)e * 8);
    E4[0] = make_float4(efv[0], efv[1], efv[2], efv[3]);
    E4[1] = make_float4(efv[4], efv[5], efv[6], efv[7]);
}

// ---------------- CSR by dst ----------------
__global__ __launch_bounds__(256) void k_count(const int* __restrict__ eidx, int* __restrict__ deg)
{
    int e = blockIdx.x * 256 + threadIdx.x;
    if (e < NE) atomicAdd(&deg[eidx[NE + e]], 1);
}

__global__ __launch_bounds__(1024) void k_scan(
    const int* __restrict__ deg, int* __restrict__ offs, int* __restrict__ cursor)
{
    __shared__ int sc[1024];
    int tid = threadIdx.x;
    int base = tid * 4;
    int v[4]; int s = 0;
#pragma unroll
    for (int i = 0; i < 4; i++) {
        int idx = base + i;
        int d = (idx < NA) ? deg[idx] : 0;
        v[i] = s; s += d;
    }
    sc[tid] = s;
    __syncthreads();
    for (int ofs = 1; ofs < 1024; ofs <<= 1) {
        int t = (tid >= ofs) ? sc[tid - ofs] : 0;
        __syncthreads();
        sc[tid] += t;
        __syncthreads();
    }
    int excl = (tid > 0) ? sc[tid - 1] : 0;
#pragma unroll
    for (int i = 0; i < 4; i++) {
        int idx = base + i;
        if (idx < NA) { int o = excl + v[i]; offs[idx] = o; cursor[idx] = o; }
    }
    if (tid == 1023) offs[NA] = sc[1023];
}

__global__ __launch_bounds__(256) void k_fill(
    const int* __restrict__ eidx, int* __restrict__ cursor, int* __restrict__ perm)
{
    int e = blockIdx.x * 256 + threadIdx.x;
    if (e < NE) {
        int d = eidx[NE + e];
        int p = atomicAdd(&cursor[d], 1);
        perm[p] = e;
    }
}

// ---------------- Ewald kernels ----------------
__global__ __launch_bounds__(128) void k_kfilter(
    const float* __restrict__ kdown, const float* __restrict__ WupE, float* __restrict__ kf)
{
    int k = blockIdx.x, c = threadIdx.x;
    float s = 0.f;
#pragma unroll
    for (int j = 0; j < 8; j++) s += kdown[k * 8 + j] * WupE[j * C + c];
    kf[(size_t)k * C + c] = s;
}

__global__ __launch_bounds__(256, 4) void k_sf(
    const float* __restrict__ hres, const float* __restrict__ cosd, const float* __restrict__ sind,
    const int* __restrict__ gs, const float* __restrict__ kf,
    float* __restrict__ sfr, float* __restrict__ sfi)
{
    constexpr int SPLIT = 8;
    const int b = blockIdx.x, kt = blockIdx.y, sp = blockIdx.z;
    const int n0 = gs[b], n1 = gs[b + 1];
    const int cnt = n1 - n0;
    const int per = (cnt + SPLIT - 1) / SPLIT;
    const int cs = n0 + sp * per;
    const int ce = min(cs + per, n1);

    __shared__ float Hs[32 * 128];
    __shared__ float Cs[32 * 32];
    __shared__ float Ss[32 * 32];

    const int tid = threadIdx.x;
    const int tx = tid & 31;
    const int ty = tid >> 5;

    float accR[4][4], accI[4][4];
#pragma unroll
    for (int i = 0; i < 4; i++)
#pragma unroll
        for (int j = 0; j < 4; j++) { accR[i][j] = 0.f; accI[i][j] = 0.f; }

    float4* H4 = (float4*)Hs;
    float4* C4 = (float4*)Cs;
    float4* S4 = (float4*)Ss;

    for (int nb = cs; nb < ce; nb += 32) {
        __syncthreads();
        for (int idx = tid; idx < 32 * 32; idx += 256) {
            int r = idx >> 5, c4 = idx & 31;
            int n = nb + r;
            H4[idx] = (n < ce) ? ((const float4*)hres)[(size_t)n * 32 + c4]
                               : make_float4(0.f, 0.f, 0.f, 0.f);
        }
        for (int idx = tid; idx < 32 * 8; idx += 256) {
            int r = idx >> 3, k4 = idx & 7;
            int n = nb + r;
            float4 cv = make_float4(0.f, 0.f, 0.f, 0.f), sv = cv;
            if (n < ce) {
                cv = ((const float4*)cosd)[(size_t)n * 32 + kt * 8 + k4];
                sv = ((const float4*)sind)[(size_t)n * 32 + kt * 8 + k4];
            }
            C4[idx] = cv;
            S4[idx] = sv;
        }
        __syncthreads();
        const int lim = min(32, ce - nb);
        for (int n = 0; n < lim; n++) {
            float4 hv = H4[n * 32 + tx];
            float4 cv = C4[n * 8 + ty];
            float4 sv = S4[n * 8 + ty];
            float h[4] = { hv.x, hv.y, hv.z, hv.w };
            float ck[4] = { cv.x, cv.y, cv.z, cv.w };
            float sk[4] = { sv.x, sv.y, sv.z, sv.w };
#pragma unroll
            for (int i = 0; i < 4; i++)
#pragma unroll
                for (int j = 0; j < 4; j++) {
                    accR[i][j] += ck[i] * h[j];
                    accI[i][j] += sk[i] * h[j];
                }
        }
    }

    const int kbase = kt * 32 + ty * 4;
#pragma unroll
    for (int i = 0; i < 4; i++) {
        int k = kbase + i;
        if (k < NK) {
            float4 kfv = ((const float4*)kf)[(size_t)k * 32 + tx];
            float vx = kfv.x * 0.01f, vy = kfv.y * 0.01f, vz = kfv.z * 0.01f, vw = kfv.w * 0.01f;
            float* pR = sfr + ((size_t)(b * NK + k)) * C + tx * 4;
            float* pI = sfi + ((size_t)(b * NK + k)) * C + tx * 4;
            atomicAdd(pR + 0, accR[i][0] * vx);
            atomicAdd(pR + 1, accR[i][1] * vy);
            atomicAdd(pR + 2, accR[i][2] * vz);
            atomicAdd(pR + 3, accR[i][3] * vw);
            atomicAdd(pI + 0, accI[i][0] * vx);
            atomicAdd(pI + 1, accI[i][1] * vy);
            atomicAdd(pI + 2, accI[i][2] * vz);
            atomicAdd(pI + 3, accI[i][3] * vw);
        }
    }
}

__global__ __launch_bounds__(128) void k_he(
    const float* __restrict__ cosd, const float* __restrict__ sind,
    const float* __restrict__ sfr, const float* __restrict__ sfi,
    const int* __restrict__ batch, float* __restrict__ out)
{
    int n = blockIdx.x, c = threadIdx.x;
    int b = batch[n];
    const float* pr = sfr + (size_t)b * NK * C;
    const float* pi = sfi + (size_t)b * NK * C;
    const float* cdp = cosd + (size_t)n * NKP;
    const float* sdp = sind + (size_t)n * NKP;
    float acc = 0.f;
    for (int k = 0; k < NK; k++) {
        acc += cdp[k] * pr[(size_t)k * C + c] + sdp[k] * pi[(size_t)k * C + c];
    }
    out[(size_t)n * C + c] = acc;
}

// ---------------- message gather + symmetric contraction ----------------
__global__ __launch_bounds__(128) void k_gather(
    const unsigned short* __restrict__ wbuf, const float* __restrict__ hu,
    const float* __restrict__ Y, const int* __restrict__ srcArr,
    const int* __restrict__ offs, const int* __restrict__ perm,
    const float* __restrict__ w2, const float* __restrict__ w3,
    float* __restrict__ feats)
{
    int n = blockIdx.x, c = threadIdx.x;
    int j0 = offs[n], j1 = offs[n + 1];
    float A[16];
#pragma unroll
    for (int s = 0; s < 16; s++) A[s] = 0.f;
    for (int j = j0; j < j1; j++) {
        int e = perm[j];
        int s = srcArr[e];
        float huc = hu[(size_t)s * C + c];
        ushort4 wv = *(const ushort4*)(wbuf + (size_t)e * 512 + c * 4);
        const float4* Yp = (const float4*)(Y + (size_t)e * 16);
        float4 y0 = Yp[0], y1 = Yp[1], y2 = Yp[2], y3 = Yp[3];
        float m0 = bf2f(wv.x) * huc, m1 = bf2f(wv.y) * huc;
        float m2 = bf2f(wv.z) * huc, m3 = bf2f(wv.w) * huc;
        A[0] += m0 * y0.x;
        A[1] += m1 * y0.y;  A[2]  += m1 * y0.z;  A[3]  += m1 * y0.w;
        A[4] += m2 * y1.x;  A[5]  += m2 * y1.y;  A[6]  += m2 * y1.z;  A[7] += m2 * y1.w;
        A[8] += m2 * y2.x;
        A[9] += m3 * y2.y;  A[10] += m3 * y2.z;  A[11] += m3 * y2.w;
        A[12] += m3 * y3.x; A[13] += m3 * y3.y;  A[14] += m3 * y3.z;  A[15] += m3 * y3.w;
    }
    const float inv = 1.0f / AVGN;
#pragma unroll
    for (int s = 0; s < 16; s++) A[s] *= inv;
    float scal = A[0];
    float i0 = A[0] * A[0];
    float i1 = A[1] * A[1] + A[2] * A[2] + A[3] * A[3];
    float i2 = A[4] * A[4] + A[5] * A[5] + A[6] * A[6] + A[7] * A[7] + A[8] * A[8];
    float i3 = A[9] * A[9] + A[10] * A[10] + A[11] * A[11] + A[12] * A[12] +
               A[13] * A[13] + A[14] * A[14] + A[15] * A[15];
    float t2 = i0 * w2[c] + i1 * w2[C + c] + i2 * w2[2 * C + c] + i3 * w2[3 * C + c];
    float t3 = i0 * w3[c] + i1 * w3[C + c] + i2 * w3[2 * C + c] + i3 * w3[3 * C + c];
    feats[(size_t)n * C + c] = scal + t2 + scal * t3;
}

// ---------------- readout energy ----------------
__global__ __launch_bounds__(128) void k_node_energy(
    const float* __restrict__ h, const int* __restrict__ batch,
    const float* __restrict__ Wr0, const float* __restrict__ Wr1a,
    const float* __restrict__ Wr1b, int mode, float* __restrict__ Eout)
{
    int n = blockIdx.x, t = threadIdx.x;
    __shared__ float hs[128];
    __shared__ float red[16];
    float hv = h[(size_t)n * C + t];
    if (mode == 0) {
        float v = hv * Wr0[t];
#pragma unroll
        for (int o = 32; o; o >>= 1) v += __shfl_down(v, o, 64);
        if ((t & 63) == 0) red[t >> 6] = v;
        __syncthreads();
        if (t == 0) atomicAdd(&Eout[batch[n]], red[0] + red[1]);
    } else {
        hs[t] = hv;
        __syncthreads();
        if (t < 16) {
            float s = 0.f;
#pragma unroll 8
            for (int cc = 0; cc < 128; cc++) s += hs[cc] * Wr1a[cc * 16 + t];
            red[t] = dsilu(s) * Wr1b[t];
        }
        __syncthreads();
        if (t == 0) {
            float s = 0.f;
#pragma unroll
            for (int j = 0; j < 16; j++) s += red[j];
            atomicAdd(&Eout[batch[n]], s);
        }
    }
}

// ---------------- workspace layout (floats) ----------------
constexpr size_t NAC   = (size_t)NA * C;
constexpr size_t F_COSD = 0;
constexpr size_t F_SIND = F_COSD + (size_t)NA * NKP;
constexpr size_t F_Y    = F_SIND + (size_t)NA * NKP;
constexpr size_t F_EF   = F_Y + (size_t)NE * 16;
constexpr size_t F_H    = F_EF + (size_t)NE * 8;
constexpr size_t F_HN   = F_H + NAC;
constexpr size_t F_HRES = F_HN + NAC;
constexpr size_t F_T1   = F_HRES + NAC;
constexpr size_t F_T2   = F_T1 + NAC;
constexpr size_t F_HE2  = F_T2 + NAC;
constexpr size_t F_HU   = F_HE2 + NAC;
constexpr size_t F_FE   = F_HU + NAC;
constexpr size_t F_TA   = F_FE + NAC;                // bf16 tA (NE*64) + hbuf (NE*64) shorts
constexpr size_t F_TB   = F_TA + (size_t)NE * 64;    // bf16 W4bt + W2bt + W3bt
constexpr size_t F_W    = F_TB + (size_t)NE * 64;    // bf16 wbuf: NE*512 shorts
constexpr size_t F_SFR  = F_W + (size_t)NE * 512;
constexpr size_t F_SFI  = F_SFR + (size_t)BG * NK * C;
constexpr size_t F_KD   = F_SFI + (size_t)BG * NK * C;
constexpr size_t F_KF   = F_KD + 1024;
constexpr size_t F_END  = F_KF + (size_t)NK * C;
constexpr size_t I_BASE = ((F_END * 4 + 255) / 256) * 256;

extern "C" void kernel_launch(void* const* d_in, const int* in_sizes, int n_in,
                              void* d_out, int out_size, void* d_ws, size_t ws_size,
                              hipStream_t stream) {
    const float* pos    = (const float*)d_in[0];
    const float* na     = (const float*)d_in[1];
    const float* shifts = (const float*)d_in[2];
    const int*   eidx   = (const int*)d_in[3];
    const int*   batch  = (const int*)d_in[4];
    const float* kgrid  = (const float*)d_in[5];
    const float* krbf   = (const float*)d_in[6];
    const float* Wemb   = (const float*)d_in[7];
    const float* aE     = (const float*)d_in[8];
    const float* rW1    = (const float*)d_in[9];
    const float* rb1    = (const float*)d_in[10];
    const float* rW2    = (const float*)d_in[11];
    const float* rb2    = (const float*)d_in[12];
    const float* rW3    = (const float*)d_in[13];
    const float* rb3    = (const float*)d_in[14];
    const float* rW4    = (const float*)d_in[15];
    const float* Wup    = (const float*)d_in[16];
    const float* w2     = (const float*)d_in[17];
    const float* w3     = (const float*)d_in[18];
    const float* Wmix   = (const float*)d_in[19];
    const float* Wr0    = (const float*)d_in[20];
    const float* Wr1a   = (const float*)d_in[21];
    const float* Wr1b   = (const float*)d_in[22];
    const float* Wdown  = (const float*)d_in[23];
    const float* WupE   = (const float*)d_in[24];
    const float* Wpre1  = (const float*)d_in[25];
    const float* bpre1  = (const float*)d_in[26];
    const float* Wpre2  = (const float*)d_in[27];
    const float* bpre2  = (const float*)d_in[28];
    const float* Wm1    = (const float*)d_in[29];
    const float* bm1    = (const float*)d_in[30];
    const float* Wm2    = (const float*)d_in[31];
    const float* bm2    = (const float*)d_in[32];

    float* fw = (float*)d_ws;
    float* cosd = fw + F_COSD;
    float* sind = fw + F_SIND;
    float* Ybuf = fw + F_Y;
    float* efb  = fw + F_EF;
    float* h    = fw + F_H;
    float* hn   = fw + F_HN;
    float* hres = fw + F_HRES;
    float* t1   = fw + F_T1;
    float* t2   = fw + F_T2;
    float* he2  = fw + F_HE2;
    float* hu   = fw + F_HU;
    float* fe   = fw + F_FE;
    unsigned short* tA   = (unsigned short*)(fw + F_TA);
    unsigned short* hbuf = tA + (size_t)NE * 64;
    unsigned short* W4bt = (unsigned short*)(fw + F_TB);
    unsigned short* W2bt = W4bt + (size_t)2 * 512 * 64;
    unsigned short* W3bt = W2bt + (size_t)2 * 64 * 64;
    unsigned short* wbuf = (unsigned short*)(fw + F_W);
    float* sfr  = fw + F_SFR;
    float* sfi  = fw + F_SFI;
    float* kdwn = fw + F_KD;
    float* kfil = fw + F_KF;

    int* ip     = (int*)((char*)d_ws + I_BASE);
    int* deg    = ip;
    int* offs   = ip + NA;
    int* cursor = ip + 2 * NA + 1;
    int* perm   = ip + 3 * NA + 1;
    int* gs     = perm + NE;

    float* Eout = (float*)d_out;

    hipMemsetAsync(Eout, 0, BG * sizeof(float), stream);
    hipMemsetAsync(deg, 0, NA * sizeof(int), stream);

    k_node_init<<<NA, 128, 0, stream>>>(na, Wemb, aE, batch, h, Eout);
    k_ranges<<<1, 256, 0, stream>>>(batch, gs);
    k_kspace<<<NA, 128, 0, stream>>>(pos, kgrid, cosd, sind);
    k_kdown<<<1, 1024, 0, stream>>>(krbf, Wdown, kdwn);
    k_edge_geom<<<NE / 256, 256, 0, stream>>>(pos, shifts, eidx, Ybuf, efb);
    k_count<<<NE / 256, 256, 0, stream>>>(eidx, deg);
    k_scan<<<1, 1024, 0, stream>>>(deg, offs, cursor);
    k_fill<<<NE / 256, 256, 0, stream>>>(eidx, cursor, perm);
    k_convW4<<<1024, 64, 0, stream>>>(rW4, W4bt);
    k_convW64<<<128, 64, 0, stream>>>(rW2, W2bt);
    k_convW64<<<128, 64, 0, stream>>>(rW3, W3bt);

    const dim3 gA(NA / 64, C / 64);
    const dim3 gDual(NA / 64, 4);
    const dim3 gSF(BG, 4, 8);
    const dim3 gWB(NE / 256, 512 / 64);

    for (int i = 0; i < 2; i++) {
        const float* Wpre1_i = Wpre1 + (size_t)i * C * C;
        const float* bpre1_i = bpre1 + (size_t)i * C;
        const float* Wpre2_i = Wpre2 + (size_t)i * C * C;
        const float* bpre2_i = bpre2 + (size_t)i * C;
        const float* WupE_i  = WupE + (size_t)i * 8 * C;
        const float* Wm1_i   = Wm1 + (size_t)i * C * C;
        const float* bm1_i   = bm1 + (size_t)i * C;
        const float* Wm2_i   = Wm2 + (size_t)i * C * C;
        const float* bm2_i   = bm2 + (size_t)i * C;
        const float* Wup_i   = Wup + (size_t)i * C * C;
        const float* rW1_i   = rW1 + (size_t)i * 8 * 64;
        const float* rb1_i   = rb1 + (size_t)i * 64;
        const float* rb2_i   = rb2 + (size_t)i * 64;
        const float* rb3_i   = rb3 + (size_t)i * 64;
        const float* w2_i    = w2 + (size_t)i * 4 * C;
        const float* w3_i    = w3 + (size_t)i * 4 * C;
        const float* Wmix_i  = Wmix + (size_t)i * C * C;
        const unsigned short* W4bt_i = W4bt + (size_t)i * 512 * 64;
        const unsigned short* W2bt_i = W2bt + (size_t)i * 64 * 64;
        const unsigned short* W3bt_i = W3bt + (size_t)i * 64 * 64;

        // dual: t1 = silu(h@Wpre1+b), hu = h@Wup
        gemm_dual<<<gDual, 256, 0, stream>>>(h, Wpre1_i, Wup_i, bpre1_i, t1, hu);
        gemm_kernel<128, 0, 0><<<gA, 256, 0, stream>>>(t1, Wpre2_i, bpre2_i, h, nullptr, hres, NA, C, 1.f);

        // edge branch: L1 (f32 GEMM -> bf16), L2/L3 (MFMA), W4 expand (MFMA)
        gemm_kernel<8, 1, 1><<<dim3(NE / 64, 1), 256, 0, stream>>>(efb, rW1_i, rb1_i, nullptr, nullptr, hbuf, NE, 64, 1.f);
        k_mlp_mfma<<<NE / 128, 128, 0, stream>>>(hbuf, W2bt_i, rb2_i, tA);
        k_mlp_mfma<<<NE / 128, 128, 0, stream>>>(tA, W3bt_i, rb3_i, hbuf);
        k_wbuf_mfma<<<gWB, 256, 0, stream>>>(hbuf, W4bt_i, wbuf);

        // Ewald branch
        k_kfilter<<<NK, 128, 0, stream>>>(kdwn, WupE_i, kfil);
        hipMemsetAsync(sfr, 0, 2 * (size_t)BG * NK * C * sizeof(float), stream);
        k_sf<<<gSF, 256, 0, stream>>>(hres, cosd, sind, gs, kfil, sfr, sfi);
        k_he<<<NA, 128, 0, stream>>>(cosd, sind, sfr, sfi, batch, t1);
        gemm_kernel<128, 1, 0><<<gA, 256, 0, stream>>>(t1, Wm1_i, bm1_i, nullptr, nullptr, t2, NA, C, 1.f);
        gemm_kernel<128, 1, 0><<<gA, 256, 0, stream>>>(t2, Wm2_i, bm2_i, nullptr, nullptr, he2, NA, C, 1.f);

        // gather + combine
        k_gather<<<NA, 128, 0, stream>>>(wbuf, hu, Ybuf, eidx, offs, perm, w2_i, w3_i, fe);
        gemm_kernel<128, 0, 0><<<gA, 256, 0, stream>>>(fe, Wmix_i, nullptr, h, he2, hn, NA, C, SKIPF);
        k_node_energy<<<NA, 128, 0, stream>>>(hn, batch, Wr0, Wr1a, Wr1b, (i == 0) ? 0 : 1, Eout);

        float* tmp = h; h = hn; hn = tmp;
    }
}

// Round 6
// 556.533 us; speedup vs baseline: 1.3812x; 1.2105x over previous
//
#include <hip/hip_runtime.h>
#include <hip/hip_bf16.h>
#include <math.h>

// ---------------- problem constants ----------------
constexpr int NA  = 3200;     // atoms
constexpr int NE  = 51200;    // edges
constexpr int C   = 128;      // channels
constexpr int NK  = 123;      // k-points with |k| <= 0.6
constexpr int NKP = 128;      // padded stride for cosd/sind
constexpr int BG  = 8;        // graphs
constexpr float SKIPF = 0.57735026918962576f;  // 3^-0.5
constexpr float AVGN  = 16.0f;

__device__ __forceinline__ float dsilu(float x) { return x / (1.0f + expf(-x)); }

__device__ __forceinline__ unsigned short f2bf(float f) {
    unsigned int u = __float_as_uint(f);
    unsigned int r = (u + 0x7fffu + ((u >> 16) & 1u)) >> 16;
    return (unsigned short)r;
}
__device__ __forceinline__ float bf2f(unsigned short s) {
    return __uint_as_float(((unsigned int)s) << 16);
}

typedef __attribute__((ext_vector_type(8))) short short8;
typedef __attribute__((ext_vector_type(4))) float f32x4;

// ---------------- generic tiled f32 GEMM ----------------
template <int K, int ACT, int OBF16>
__global__ __launch_bounds__(256, 4) void gemm_kernel(
    const float* __restrict__ X, const float* __restrict__ W,
    const float* __restrict__ bias, const float* __restrict__ res1,
    const float* __restrict__ res2, void* __restrict__ outv,
    int M, int N, float scale)
{
    constexpr int K4 = K / 4;
    constexpr int BK  = (K < 64) ? K : 64;
    constexpr int BK4 = BK / 4;
    constexpr int BK4P = BK4 + 1;
    __shared__ float As[64 * BK4P * 4];
    __shared__ float Bs[BK * 64];
    const int tid = threadIdx.x;
    const int m0 = blockIdx.x * 64;
    const int n0 = blockIdx.y * 64;

    const float4* X4 = (const float4*)X;
    const float4* W4 = (const float4*)W;
    float4* As4 = (float4*)As;
    float4* Bs4 = (float4*)Bs;
    const int N4 = N >> 2;

    const int tx = tid & 15;
    const int ty = tid >> 4;
    float acc[4][4];
#pragma unroll
    for (int i = 0; i < 4; i++)
#pragma unroll
        for (int j = 0; j < 4; j++) acc[i][j] = 0.0f;

    for (int k0 = 0; k0 < K4; k0 += BK4) {
        if (k0) __syncthreads();
        for (int idx = tid; idx < 64 * BK4; idx += 256) {
            int r = idx / BK4, k4 = idx - r * BK4;
            As4[r * BK4P + k4] = X4[(size_t)(m0 + r) * K4 + k0 + k4];
        }
        for (int idx = tid; idx < BK * 16; idx += 256) {
            int kr = idx >> 4, c4 = idx & 15;
            Bs4[idx] = W4[(size_t)(k0 * 4 + kr) * N4 + (n0 >> 2) + c4];
        }
        __syncthreads();

#pragma unroll 4
        for (int k4 = 0; k4 < BK4; k4++) {
            float a[4][4];
#pragma unroll
            for (int i = 0; i < 4; i++) {
                float4 av = As4[(ty * 4 + i) * BK4P + k4];
                a[i][0] = av.x; a[i][1] = av.y; a[i][2] = av.z; a[i][3] = av.w;
            }
#pragma unroll
            for (int kk = 0; kk < 4; kk++) {
                float4 bv = Bs4[(k4 * 4 + kk) * 16 + tx];
#pragma unroll
                for (int i = 0; i < 4; i++) {
                    acc[i][0] += a[i][kk] * bv.x;
                    acc[i][1] += a[i][kk] * bv.y;
                    acc[i][2] += a[i][kk] * bv.z;
                    acc[i][3] += a[i][kk] * bv.w;
                }
            }
        }
    }

    float4 bv = make_float4(0.f, 0.f, 0.f, 0.f);
    if (bias) bv = ((const float4*)bias)[(n0 >> 2) + tx];
#pragma unroll
    for (int i = 0; i < 4; i++) {
        int row = m0 + ty * 4 + i;
        size_t o = (size_t)row * N + n0 + tx * 4;
        float4 v;
        v.x = acc[i][0] + bv.x; v.y = acc[i][1] + bv.y;
        v.z = acc[i][2] + bv.z; v.w = acc[i][3] + bv.w;
        if (ACT) { v.x = dsilu(v.x); v.y = dsilu(v.y); v.z = dsilu(v.z); v.w = dsilu(v.w); }
        if (res1) { float4 r = *(const float4*)(res1 + o); v.x += r.x; v.y += r.y; v.z += r.z; v.w += r.w; }
        if (res2) { float4 r = *(const float4*)(res2 + o); v.x += r.x; v.y += r.y; v.z += r.z; v.w += r.w; }
        v.x *= scale; v.y *= scale; v.z *= scale; v.w *= scale;
        if (OBF16) {
            ushort4 pk;
            pk.x = f2bf(v.x); pk.y = f2bf(v.y); pk.z = f2bf(v.z); pk.w = f2bf(v.w);
            *(ushort4*)((unsigned short*)outv + o) = pk;
        } else {
            *(float4*)((float*)outv + o) = v;
        }
    }
}

// ---------------- dual GEMM: t1 = silu(h@Wa + bias), hu = h@Wb ----------------
__global__ __launch_bounds__(256, 4) void gemm_dual(
    const float* __restrict__ X, const float* __restrict__ Wa,
    const float* __restrict__ Wb, const float* __restrict__ bias,
    float* __restrict__ outa, float* __restrict__ outb)
{
    constexpr int K4 = 32, BK4 = 16, BK4P = 17;
    __shared__ float As[64 * BK4P * 4];
    __shared__ float Bs[64 * 64];
    const int tid = threadIdx.x;
    const int m0 = blockIdx.x * 64;
    const int sel = blockIdx.y >> 1;
    const int n0 = (blockIdx.y & 1) * 64;
    const float* W = sel ? Wb : Wa;
    float* out = sel ? outb : outa;

    const float4* X4 = (const float4*)X;
    const float4* W4 = (const float4*)W;
    float4* As4 = (float4*)As;
    float4* Bs4 = (float4*)Bs;

    const int tx = tid & 15;
    const int ty = tid >> 4;
    float acc[4][4];
#pragma unroll
    for (int i = 0; i < 4; i++)
#pragma unroll
        for (int j = 0; j < 4; j++) acc[i][j] = 0.0f;

    for (int k0 = 0; k0 < K4; k0 += BK4) {
        if (k0) __syncthreads();
        for (int idx = tid; idx < 64 * BK4; idx += 256) {
            int r = idx / BK4, k4 = idx - r * BK4;
            As4[r * BK4P + k4] = X4[(size_t)(m0 + r) * K4 + k0 + k4];
        }
        for (int idx = tid; idx < 64 * 16; idx += 256) {
            int kr = idx >> 4, c4 = idx & 15;
            Bs4[idx] = W4[(size_t)(k0 * 4 + kr) * 32 + (n0 >> 2) + c4];
        }
        __syncthreads();

#pragma unroll 4
        for (int k4 = 0; k4 < BK4; k4++) {
            float a[4][4];
#pragma unroll
            for (int i = 0; i < 4; i++) {
                float4 av = As4[(ty * 4 + i) * BK4P + k4];
                a[i][0] = av.x; a[i][1] = av.y; a[i][2] = av.z; a[i][3] = av.w;
            }
#pragma unroll
            for (int kk = 0; kk < 4; kk++) {
                float4 bv = Bs4[(k4 * 4 + kk) * 16 + tx];
#pragma unroll
                for (int i = 0; i < 4; i++) {
                    acc[i][0] += a[i][kk] * bv.x;
                    acc[i][1] += a[i][kk] * bv.y;
                    acc[i][2] += a[i][kk] * bv.z;
                    acc[i][3] += a[i][kk] * bv.w;
                }
            }
        }
    }

    float4 bv = make_float4(0.f, 0.f, 0.f, 0.f);
    if (!sel) bv = ((const float4*)bias)[(n0 >> 2) + tx];
#pragma unroll
    for (int i = 0; i < 4; i++) {
        int row = m0 + ty * 4 + i;
        size_t o = (size_t)row * 128 + n0 + tx * 4;
        float4 v;
        v.x = acc[i][0] + bv.x; v.y = acc[i][1] + bv.y;
        v.z = acc[i][2] + bv.z; v.w = acc[i][3] + bv.w;
        if (!sel) { v.x = dsilu(v.x); v.y = dsilu(v.y); v.z = dsilu(v.z); v.w = dsilu(v.w); }
        *(float4*)(out + o) = v;
    }
}

// ---------------- MFMA MLP layer: out = silu(X @ Wt^T + bias), all bf16 ----------------
__global__ __launch_bounds__(128, 2) void k_mlp_mfma(
    const unsigned short* __restrict__ X, const unsigned short* __restrict__ Wt,
    const float* __restrict__ bias, unsigned short* __restrict__ out)
{
    constexpr int MT = 128, AS = 72;
    __shared__ unsigned short Als[MT * AS];
    __shared__ unsigned short Bls[64 * AS];
    const int tid = threadIdx.x;
    const int m0 = blockIdx.x * MT;

    for (int idx = tid; idx < MT * 8; idx += 128) {
        int r = idx >> 3, s = idx & 7;
        *(short8*)(Als + r * AS + s * 8) = ((const short8*)X)[(size_t)(m0 + r) * 8 + s];
    }
    for (int idx = tid; idx < 64 * 8; idx += 128) {
        int r = idx >> 3, s = idx & 7;
        *(short8*)(Bls + r * AS + s * 8) = ((const short8*)Wt)[(size_t)r * 8 + s];
    }
    __syncthreads();

    const int wave = tid >> 6;
    const int lane = tid & 63;
    const int q = lane >> 4;
    const int l16 = lane & 15;
    const int mw = wave * 64;

    f32x4 acc[4][4];
#pragma unroll
    for (int mi = 0; mi < 4; mi++)
#pragma unroll
        for (int ni = 0; ni < 4; ni++) acc[mi][ni] = (f32x4){0.f, 0.f, 0.f, 0.f};

#pragma unroll
    for (int kc = 0; kc < 2; kc++) {
        short8 a[4], b[4];
#pragma unroll
        for (int mi = 0; mi < 4; mi++)
            a[mi] = *(const short8*)(Als + (mw + mi * 16 + l16) * AS + kc * 32 + q * 8);
#pragma unroll
        for (int ni = 0; ni < 4; ni++)
            b[ni] = *(const short8*)(Bls + (ni * 16 + l16) * AS + kc * 32 + q * 8);
#pragma unroll
        for (int mi = 0; mi < 4; mi++)
#pragma unroll
            for (int ni = 0; ni < 4; ni++)
                acc[mi][ni] = __builtin_amdgcn_mfma_f32_16x16x32_bf16(a[mi], b[ni], acc[mi][ni], 0, 0, 0);
    }

#pragma unroll
    for (int ni = 0; ni < 4; ni++) {
        float bv = bias[ni * 16 + l16];
#pragma unroll
        for (int mi = 0; mi < 4; mi++) {
#pragma unroll
            for (int r = 0; r < 4; r++) {
                int e = m0 + mw + mi * 16 + q * 4 + r;
                int n = ni * 16 + l16;
                out[(size_t)e * 64 + n] = f2bf(dsilu(acc[mi][ni][r] + bv));
            }
        }
    }
}

// ---------------- weight converts ----------------
__global__ __launch_bounds__(64) void k_convW4(
    const float* __restrict__ rW4, unsigned short* __restrict__ W4bt)
{
    int b = blockIdx.x;
    int layer = b >> 9, n = b & 511;
    int k = threadIdx.x;
    W4bt[((size_t)layer * 512 + n) * 64 + k] = f2bf(rW4[((size_t)layer * 64 + k) * 512 + n]);
}

__global__ __launch_bounds__(64) void k_convW64(
    const float* __restrict__ rW, unsigned short* __restrict__ Wbt)
{
    int b = blockIdx.x;
    int layer = b >> 6, n = b & 63;
    int k = threadIdx.x;
    Wbt[((size_t)layer * 64 + n) * 64 + k] = f2bf(rW[((size_t)layer * 64 + k) * 64 + n]);
}

// ---------------- MFMA GEMM: wbuf[e][n] = tA[e][0:64] @ W4t[n][0:64], bf16 ----------------
__global__ __launch_bounds__(256, 2) void k_wbuf_mfma(
    const unsigned short* __restrict__ tA, const unsigned short* __restrict__ W4t,
    unsigned short* __restrict__ wbuf)
{
    constexpr int MT = 256, NT = 64, AS = 72;
    __shared__ unsigned short Als[MT * AS];
    __shared__ unsigned short Bls[NT * AS];
    const int tid = threadIdx.x;
    const int m0 = blockIdx.x * MT;
    const int n0 = blockIdx.y * NT;

    for (int idx = tid; idx < MT * 8; idx += 256) {
        int r = idx >> 3, s = idx & 7;
        *(short8*)(Als + r * AS + s * 8) = ((const short8*)tA)[(size_t)(m0 + r) * 8 + s];
    }
    for (int idx = tid; idx < NT * 8; idx += 256) {
        int r = idx >> 3, s = idx & 7;
        *(short8*)(Bls + r * AS + s * 8) = ((const short8*)W4t)[(size_t)(n0 + r) * 8 + s];
    }
    __syncthreads();

    const int wave = tid >> 6;
    const int lane = tid & 63;
    const int q = lane >> 4;
    const int l16 = lane & 15;
    const int mw = wave * 64;

    f32x4 acc[4][4];
#pragma unroll
    for (int mi = 0; mi < 4; mi++)
#pragma unroll
        for (int ni = 0; ni < 4; ni++) acc[mi][ni] = (f32x4){0.f, 0.f, 0.f, 0.f};

#pragma unroll
    for (int kc = 0; kc < 2; kc++) {
        short8 a[4], b[4];
#pragma unroll
        for (int mi = 0; mi < 4; mi++)
            a[mi] = *(const short8*)(Als + (mw + mi * 16 + l16) * AS + kc * 32 + q * 8);
#pragma unroll
        for (int ni = 0; ni < 4; ni++)
            b[ni] = *(const short8*)(Bls + (ni * 16 + l16) * AS + kc * 32 + q * 8);
#pragma unroll
        for (int mi = 0; mi < 4; mi++)
#pragma unroll
            for (int ni = 0; ni < 4; ni++)
                acc[mi][ni] = __builtin_amdgcn_mfma_f32_16x16x32_bf16(a[mi], b[ni], acc[mi][ni], 0, 0, 0);
    }

#pragma unroll
    for (int mi = 0; mi < 4; mi++) {
#pragma unroll
        for (int ni = 0; ni < 4; ni++) {
#pragma unroll
            for (int r = 0; r < 4; r++) {
                int e = m0 + mw + mi * 16 + q * 4 + r;
                int n = n0 + ni * 16 + l16;
                wbuf[(size_t)e * 512 + n] = f2bf(acc[mi][ni][r]);
            }
        }
    }
}

// ---------------- setup kernels ----------------
__global__ __launch_bounds__(128) void k_node_init(
    const float* __restrict__ na, const float* __restrict__ Wemb,
    const float* __restrict__ aE, float* __restrict__ h, float* __restrict__ e0buf)
{
    int n = blockIdx.x, c = threadIdx.x;
    float s = 0.f;
#pragma unroll
    for (int k = 0; k < 10; k++) s += na[n * 10 + k] * Wemb[k * C + c];
    h[(size_t)n * C + c] = s;
    if (c == 0) {
        float e = 0.f;
#pragma unroll
        for (int k = 0; k < 10; k++) e += na[n * 10 + k] * aE[k];
        e0buf[n] = e;
    }
}

__global__ __launch_bounds__(256) void k_ranges(const int* __restrict__ batch, int* __restrict__ gs)
{
    __shared__ int cnt[BG];
    if (threadIdx.x < BG) cnt[threadIdx.x] = 0;
    __syncthreads();
    for (int n = threadIdx.x; n < NA; n += 256) atomicAdd(&cnt[batch[n]], 1);
    __syncthreads();
    if (threadIdx.x == 0) {
        int s = 0;
        for (int b = 0; b < BG; b++) { gs[b] = s; s += cnt[b]; }
        gs[BG] = s;
    }
}

__device__ __forceinline__ float sincn(float x) {
    float px = 3.14159265358979323846f * x;
    return (fabsf(px) < 1e-8f) ? 1.0f : (sinf(px) / px);
}

__global__ __launch_bounds__(128) void k_kspace(
    const float* __restrict__ pos, const float* __restrict__ kgrid,
    float* __restrict__ cosd, float* __restrict__ sind)
{
    int n = blockIdx.x, k = threadIdx.x;
    float p0 = pos[n * 3 + 0], p1 = pos[n * 3 + 1], p2 = pos[n * 3 + 2];
    float sd = sincn(0.1f * p0) * sincn(0.1f * p1) * sincn(0.1f * p2);
    if (k < NK) {
        float d = p0 * kgrid[k * 3 + 0] + p1 * kgrid[k * 3 + 1] + p2 * kgrid[k * 3 + 2];
        float sn, cs;
        sincosf(d, &sn, &cs);
        cosd[(size_t)n * NKP + k] = sd * cs;
        sind[(size_t)n * NKP + k] = sd * sn;
    } else {
        cosd[(size_t)n * NKP + k] = 0.f;
        sind[(size_t)n * NKP + k] = 0.f;
    }
}

__global__ __launch_bounds__(1024) void k_kdown(
    const float* __restrict__ krbf, const float* __restrict__ Wdown, float* __restrict__ kdown)
{
    int t = threadIdx.x;
    if (t < NK * 8) {
        int k = t >> 3, j = t & 7;
        float s = 0.f;
        for (int r = 0; r < 128; r++) s += krbf[k * 128 + r] * Wdown[r * 8 + j];
        kdown[t] = s;
    }
}

__global__ __launch_bounds__(256) void k_edge_geom(
    const float* __restrict__ pos, const float* __restrict__ shifts,
    const int* __restrict__ eidx, float* __restrict__ Y, float* __restrict__ ef)
{
    int e = blockIdx.x * 256 + threadIdx.x;
    if (e >= NE) return;
    int s = eidx[e], d = eidx[NE + e];
    float vx = pos[d * 3 + 0] - pos[s * 3 + 0] + shifts[e * 3 + 0];
    float vy = pos[d * 3 + 1] - pos[s * 3 + 1] + shifts[e * 3 + 1];
    float vz = pos[d * 3 + 2] - pos[s * 3 + 2] + shifts[e * 3 + 2];
    float r = sqrtf(vx * vx + vy * vy + vz * vz);
    float rinv = 1.0f / fmaxf(r, 1e-9f);
    float x = vx * rinv, y = vy * rinv, z = vz * rinv;

    const float s3 = 1.7320508075688772f, s5 = 2.2360679774997896f, s15 = 3.8729833462074170f;
    const float c70 = 2.0916500663351889f;
    const float c105 = 10.246950765959598f;
    const float c42 = 1.6201851746019651f;
    const float c7 = 1.3228756555322954f;
    float o[16];
    o[0] = 1.0f;
    o[1] = s3 * x; o[2] = s3 * y; o[3] = s3 * z;
    o[4] = s15 * x * y; o[5] = s15 * y * z; o[6] = 0.5f * s5 * (3.f * z * z - 1.f);
    o[7] = s15 * x * z; o[8] = 0.5f * s15 * (x * x - y * y);
    o[9]  = c70 * y * (3.f * x * x - y * y);
    o[10] = c105 * x * y * z;
    o[11] = c42 * y * (5.f * z * z - 1.f);
    o[12] = c7 * z * (5.f * z * z - 3.f);
    o[13] = c42 * x * (5.f * z * z - 1.f);
    o[14] = 0.5f * c105 * z * (x * x - y * y);
    o[15] = c70 * x * (x * x - 3.f * y * y);
    float4* Y4 = (float4*)(Y + (size_t)e * 16);
    Y4[0] = make_float4(o[0], o[1], o[2], o[3]);
    Y4[1] = make_float4(o[4], o[5], o[6], o[7]);
    Y4[2] = make_float4(o[8], o[9], o[10], o[11]);
    Y4[3] = make_float4(o[12], o[13], o[14], o[15]);

    float uu = fminf(fmaxf(r * 0.2f, 0.f), 1.f);
    float u2 = uu * uu, u4 = u2 * u2, u5 = u4 * uu, u6 = u5 * uu, u7 = u6 * uu;
    float env = 1.f - 21.f * u5 + 35.f * u6 - 15.f * u7;
    env = (r < 5.0f) ? env : 0.0f;
    float pref = 0.63245553203367587f * rinv * env;
    const float pio5 = 0.62831853071795865f;
    float efv[8];
#pragma unroll
    for (int n1 = 1; n1 <= 8; n1++) efv[n1 - 1] = pref * sinf(n1 * pio5 * r);
    float4* E4 = (float4*)(ef + (size_t)e * 8);
    E4[0] = make_float4(efv[0], efv[1], efv[2], efv[3]);
    E4[1] = make_float4(efv[4], efv[5], efv[6], efv[7]);
}

// ---------------- CSR by dst ----------------
__global__ __launch_bounds__(256) void k_count(const int* __restrict__ eidx, int* __restrict__ deg)
{
    int e = blockIdx.x * 256 + threadIdx.x;
    if (e < NE) atomicAdd(&deg[eidx[NE + e]], 1);
}

__global__ __launch_bounds__(1024) void k_scan(
    const int* __restrict__ deg, int* __restrict__ offs, int* __restrict__ cursor)
{
    __shared__ int sc[1024];
    int tid = threadIdx.x;
    int base = tid * 4;
    int v[4]; int s = 0;
#pragma unroll
    for (int i = 0; i < 4; i++) {
        int idx = base + i;
        int d = (idx < NA) ? deg[idx] : 0;
        v[i] = s; s += d;
    }
    sc[tid] = s;
    __syncthreads();
    for (int ofs = 1; ofs < 1024; ofs <<= 1) {
        int t = (tid >= ofs) ? sc[tid - ofs] : 0;
        __syncthreads();
        sc[tid] += t;
        __syncthreads();
    }
    int excl = (tid > 0) ? sc[tid - 1] : 0;
#pragma unroll
    for (int i = 0; i < 4; i++) {
        int idx = base + i;
        if (idx < NA) { int o = excl + v[i]; offs[idx] = o; cursor[idx] = o; }
    }
    if (tid == 1023) offs[NA] = sc[1023];
}

__global__ __launch_bounds__(256) void k_fill(
    const int* __restrict__ eidx, int* __restrict__ cursor, int* __restrict__ perm)
{
    int e = blockIdx.x * 256 + threadIdx.x;
    if (e < NE) {
        int d = eidx[NE + e];
        int p = atomicAdd(&cursor[d], 1);
        perm[p] = e;
    }
}

// ---------------- Ewald kernels ----------------
__global__ __launch_bounds__(128) void k_kfilter(
    const float* __restrict__ kdown, const float* __restrict__ WupE, float* __restrict__ kf)
{
    int k = blockIdx.x, c = threadIdx.x;
    float s = 0.f;
#pragma unroll
    for (int j = 0; j < 8; j++) s += kdown[k * 8 + j] * WupE[j * C + c];
    kf[(size_t)k * C + c] = s;
}

__global__ __launch_bounds__(256, 4) void k_sf(
    const float* __restrict__ hres, const float* __restrict__ cosd, const float* __restrict__ sind,
    const int* __restrict__ gs, const float* __restrict__ kf,
    float* __restrict__ sfr, float* __restrict__ sfi)
{
    constexpr int SPLIT = 8;
    const int b = blockIdx.x, kt = blockIdx.y, sp = blockIdx.z;
    const int n0 = gs[b], n1 = gs[b + 1];
    const int cnt = n1 - n0;
    const int per = (cnt + SPLIT - 1) / SPLIT;
    const int cs = n0 + sp * per;
    const int ce = min(cs + per, n1);

    __shared__ float Hs[32 * 128];
    __shared__ float Cs[32 * 32];
    __shared__ float Ss[32 * 32];

    const int tid = threadIdx.x;
    const int tx = tid & 31;
    const int ty = tid >> 5;

    float accR[4][4], accI[4][4];
#pragma unroll
    for (int i = 0; i < 4; i++)
#pragma unroll
        for (int j = 0; j < 4; j++) { accR[i][j] = 0.f; accI[i][j] = 0.f; }

    float4* H4 = (float4*)Hs;
    float4* C4 = (float4*)Cs;
    float4* S4 = (float4*)Ss;

    for (int nb = cs; nb < ce; nb += 32) {
        __syncthreads();
        for (int idx = tid; idx < 32 * 32; idx += 256) {
            int r = idx >> 5, c4 = idx & 31;
            int n = nb + r;
            H4[idx] = (n < ce) ? ((const float4*)hres)[(size_t)n * 32 + c4]
                               : make_float4(0.f, 0.f, 0.f, 0.f);
        }
        for (int idx = tid; idx < 32 * 8; idx += 256) {
            int r = idx >> 3, k4 = idx & 7;
            int n = nb + r;
            float4 cv = make_float4(0.f, 0.f, 0.f, 0.f), sv = cv;
            if (n < ce) {
                cv = ((const float4*)cosd)[(size_t)n * 32 + kt * 8 + k4];
                sv = ((const float4*)sind)[(size_t)n * 32 + kt * 8 + k4];
            }
            C4[idx] = cv;
            S4[idx] = sv;
        }
        __syncthreads();
        const int lim = min(32, ce - nb);
        for (int n = 0; n < lim; n++) {
            float4 hv = H4[n * 32 + tx];
            float4 cv = C4[n * 8 + ty];
            float4 sv = S4[n * 8 + ty];
            float h[4] = { hv.x, hv.y, hv.z, hv.w };
            float ck[4] = { cv.x, cv.y, cv.z, cv.w };
            float sk[4] = { sv.x, sv.y, sv.z, sv.w };
#pragma unroll
            for (int i = 0; i < 4; i++)
#pragma unroll
                for (int j = 0; j < 4; j++) {
                    accR[i][j] += ck[i] * h[j];
                    accI[i][j] += sk[i] * h[j];
                }
        }
    }

    const int kbase = kt * 32 + ty * 4;
#pragma unroll
    for (int i = 0; i < 4; i++) {
        int k = kbase + i;
        if (k < NK) {
            float4 kfv = ((const float4*)kf)[(size_t)k * 32 + tx];
            float vx = kfv.x * 0.01f, vy = kfv.y * 0.01f, vz = kfv.z * 0.01f, vw = kfv.w * 0.01f;
            float* pR = sfr + ((size_t)(b * NK + k)) * C + tx * 4;
            float* pI = sfi + ((size_t)(b * NK + k)) * C + tx * 4;
            atomicAdd(pR + 0, accR[i][0] * vx);
            atomicAdd(pR + 1, accR[i][1] * vy);
            atomicAdd(pR + 2, accR[i][2] * vz);
            atomicAdd(pR + 3, accR[i][3] * vw);
            atomicAdd(pI + 0, accI[i][0] * vx);
            atomicAdd(pI + 1, accI[i][1] * vy);
            atomicAdd(pI + 2, accI[i][2] * vz);
            atomicAdd(pI + 3, accI[i][3] * vw);
        }
    }
}

__global__ __launch_bounds__(128) void k_he(
    const float* __restrict__ cosd, const float* __restrict__ sind,
    const float* __restrict__ sfr, const float* __restrict__ sfi,
    const int* __restrict__ batch, float* __restrict__ out)
{
    int n = blockIdx.x, c = threadIdx.x;
    int b = batch[n];
    const float* pr = sfr + (size_t)b * NK * C;
    const float* pi = sfi + (size_t)b * NK * C;
    const float* cdp = cosd + (size_t)n * NKP;
    const float* sdp = sind + (size_t)n * NKP;
    float acc = 0.f;
    for (int k = 0; k < NK; k++) {
        acc += cdp[k] * pr[(size_t)k * C + c] + sdp[k] * pi[(size_t)k * C + c];
    }
    out[(size_t)n * C + c] = acc;
}

// ---------------- message gather + symmetric contraction ----------------
__global__ __launch_bounds__(128) void k_gather(
    const unsigned short* __restrict__ wbuf, const float* __restrict__ hu,
    const float* __restrict__ Y, const int* __restrict__ srcArr,
    const int* __restrict__ offs, const int* __restrict__ perm,
    const float* __restrict__ w2, const float* __restrict__ w3,
    float* __restrict__ feats)
{
    int n = blockIdx.x, c = threadIdx.x;
    int j0 = offs[n], j1 = offs[n + 1];
    float A[16];
#pragma unroll
    for (int s = 0; s < 16; s++) A[s] = 0.f;
    for (int j = j0; j < j1; j++) {
        int e = perm[j];
        int s = srcArr[e];
        float huc = hu[(size_t)s * C + c];
        ushort4 wv = *(const ushort4*)(wbuf + (size_t)e * 512 + c * 4);
        const float4* Yp = (const float4*)(Y + (size_t)e * 16);
        float4 y0 = Yp[0], y1 = Yp[1], y2 = Yp[2], y3 = Yp[3];
        float m0 = bf2f(wv.x) * huc, m1 = bf2f(wv.y) * huc;
        float m2 = bf2f(wv.z) * huc, m3 = bf2f(wv.w) * huc;
        A[0] += m0 * y0.x;
        A[1] += m1 * y0.y;  A[2]  += m1 * y0.z;  A[3]  += m1 * y0.w;
        A[4] += m2 * y1.x;  A[5]  += m2 * y1.y;  A[6]  += m2 * y1.z;  A[7] += m2 * y1.w;
        A[8] += m2 * y2.x;
        A[9] += m3 * y2.y;  A[10] += m3 * y2.z;  A[11] += m3 * y2.w;
        A[12] += m3 * y3.x; A[13] += m3 * y3.y;  A[14] += m3 * y3.z;  A[15] += m3 * y3.w;
    }
    const float inv = 1.0f / AVGN;
#pragma unroll
    for (int s = 0; s < 16; s++) A[s] *= inv;
    float scal = A[0];
    float i0 = A[0] * A[0];
    float i1 = A[1] * A[1] + A[2] * A[2] + A[3] * A[3];
    float i2 = A[4] * A[4] + A[5] * A[5] + A[6] * A[6] + A[7] * A[7] + A[8] * A[8];
    float i3 = A[9] * A[9] + A[10] * A[10] + A[11] * A[11] + A[12] * A[12] +
               A[13] * A[13] + A[14] * A[14] + A[15] * A[15];
    float t2 = i0 * w2[c] + i1 * w2[C + c] + i2 * w2[2 * C + c] + i3 * w2[3 * C + c];
    float t3 = i0 * w3[c] + i1 * w3[C + c] + i2 * w3[2 * C + c] + i3 * w3[3 * C + c];
    feats[(size_t)n * C + c] = scal + t2 + scal * t3;
}

// ---------------- readout energy (per-node, no atomics) ----------------
__global__ __launch_bounds__(128) void k_node_energy(
    const float* __restrict__ h, const float* __restrict__ Wr0,
    const float* __restrict__ Wr1a, const float* __restrict__ Wr1b,
    int mode, float* __restrict__ nebuf)
{
    int n = blockIdx.x, t = threadIdx.x;
    __shared__ float hs[128];
    __shared__ float red[16];
    float hv = h[(size_t)n * C + t];
    if (mode == 0) {
        float v = hv * Wr0[t];
#pragma unroll
        for (int o = 32; o; o >>= 1) v += __shfl_down(v, o, 64);
        if ((t & 63) == 0) red[t >> 6] = v;
        __syncthreads();
        if (t == 0) nebuf[n] = red[0] + red[1];
    } else {
        hs[t] = hv;
        __syncthreads();
        if (t < 16) {
            float s = 0.f;
#pragma unroll 8
            for (int cc = 0; cc < 128; cc++) s += hs[cc] * Wr1a[cc * 16 + t];
            red[t] = dsilu(s) * Wr1b[t];
        }
        __syncthreads();
        if (t == 0) {
            float s = 0.f;
#pragma unroll
            for (int j = 0; j < 16; j++) s += red[j];
            nebuf[n] = s;
        }
    }
}

// ---------------- final per-graph energy reduction ----------------
__global__ __launch_bounds__(256) void k_reduceE(
    const float* __restrict__ e0buf, const float* __restrict__ nebuf,
    const int* __restrict__ gs, float* __restrict__ Eout)
{
    int b = blockIdx.x, t = threadIdx.x;
    int n0 = gs[b], n1 = gs[b + 1];
    float s = 0.f;
    for (int n = n0 + t; n < n1; n += 256)
        s += e0buf[n] + nebuf[n] + nebuf[NA + n];
#pragma unroll
    for (int o = 32; o; o >>= 1) s += __shfl_down(s, o, 64);
    __shared__ float red[4];
    if ((t & 63) == 0) red[t >> 6] = s;
    __syncthreads();
    if (t == 0) Eout[b] = red[0] + red[1] + red[2] + red[3];
}

// ---------------- workspace layout (floats) ----------------
constexpr size_t NAC   = (size_t)NA * C;
constexpr size_t F_COSD = 0;
constexpr size_t F_SIND = F_COSD + (size_t)NA * NKP;
constexpr size_t F_Y    = F_SIND + (size_t)NA * NKP;
constexpr size_t F_EF   = F_Y + (size_t)NE * 16;
constexpr size_t F_H    = F_EF + (size_t)NE * 8;
constexpr size_t F_HN   = F_H + NAC;
constexpr size_t F_HRES = F_HN + NAC;
constexpr size_t F_T1   = F_HRES + NAC;
constexpr size_t F_T2   = F_T1 + NAC;
constexpr size_t F_HE2  = F_T2 + NAC;
constexpr size_t F_HU   = F_HE2 + NAC;
constexpr size_t F_FE   = F_HU + NAC;
constexpr size_t F_TA   = F_FE + NAC;                // bf16 tA (NE*64) + hbuf (NE*64) shorts
constexpr size_t F_TB   = F_TA + (size_t)NE * 64;    // bf16 W4bt + W2bt + W3bt
constexpr size_t F_W    = F_TB + (size_t)NE * 64;    // bf16 wbuf: NE*512 shorts
constexpr size_t F_SFR  = F_W + (size_t)NE * 512;
constexpr size_t F_SFI  = F_SFR + (size_t)BG * NK * C;
constexpr size_t F_KD   = F_SFI + (size_t)BG * NK * C;
constexpr size_t F_KF   = F_KD + 1024;
constexpr size_t F_E0   = F_KF + (size_t)NK * C;     // e0buf: NA
constexpr size_t F_NE   = F_E0 + NA;                 // nebuf: 2*NA
constexpr size_t F_END  = F_NE + 2 * (size_t)NA;
constexpr size_t I_BASE = ((F_END * 4 + 255) / 256) * 256;

extern "C" void kernel_launch(void* const* d_in, const int* in_sizes, int n_in,
                              void* d_out, int out_size, void* d_ws, size_t ws_size,
                              hipStream_t stream) {
    const float* pos    = (const float*)d_in[0];
    const float* na     = (const float*)d_in[1];
    const float* shifts = (const float*)d_in[2];
    const int*   eidx   = (const int*)d_in[3];
    const int*   batch  = (const int*)d_in[4];
    const float* kgrid  = (const float*)d_in[5];
    const float* krbf   = (const float*)d_in[6];
    const float* Wemb   = (const float*)d_in[7];
    const float* aE     = (const float*)d_in[8];
    const float* rW1    = (const float*)d_in[9];
    const float* rb1    = (const float*)d_in[10];
    const float* rW2    = (const float*)d_in[11];
    const float* rb2    = (const float*)d_in[12];
    const float* rW3    = (const float*)d_in[13];
    const float* rb3    = (const float*)d_in[14];
    const float* rW4    = (const float*)d_in[15];
    const float* Wup    = (const float*)d_in[16];
    const float* w2     = (const float*)d_in[17];
    const float* w3     = (const float*)d_in[18];
    const float* Wmix   = (const float*)d_in[19];
    const float* Wr0    = (const float*)d_in[20];
    const float* Wr1a   = (const float*)d_in[21];
    const float* Wr1b   = (const float*)d_in[22];
    const float* Wdown  = (const float*)d_in[23];
    const float* WupE   = (const float*)d_in[24];
    const float* Wpre1  = (const float*)d_in[25];
    const float* bpre1  = (const float*)d_in[26];
    const float* Wpre2  = (const float*)d_in[27];
    const float* bpre2  = (const float*)d_in[28];
    const float* Wm1    = (const float*)d_in[29];
    const float* bm1    = (const float*)d_in[30];
    const float* Wm2    = (const float*)d_in[31];
    const float* bm2    = (const float*)d_in[32];

    float* fw = (float*)d_ws;
    float* cosd = fw + F_COSD;
    float* sind = fw + F_SIND;
    float* Ybuf = fw + F_Y;
    float* efb  = fw + F_EF;
    float* h    = fw + F_H;
    float* hn   = fw + F_HN;
    float* hres = fw + F_HRES;
    float* t1   = fw + F_T1;
    float* t2   = fw + F_T2;
    float* he2  = fw + F_HE2;
    float* hu   = fw + F_HU;
    float* fe   = fw + F_FE;
    unsigned short* tA   = (unsigned short*)(fw + F_TA);
    unsigned short* hbuf = tA + (size_t)NE * 64;
    unsigned short* W4bt = (unsigned short*)(fw + F_TB);
    unsigned short* W2bt = W4bt + (size_t)2 * 512 * 64;
    unsigned short* W3bt = W2bt + (size_t)2 * 64 * 64;
    unsigned short* wbuf = (unsigned short*)(fw + F_W);
    float* sfr  = fw + F_SFR;
    float* sfi  = fw + F_SFI;
    float* kdwn = fw + F_KD;
    float* kfil = fw + F_KF;
    float* e0buf = fw + F_E0;
    float* nebuf = fw + F_NE;

    int* ip     = (int*)((char*)d_ws + I_BASE);
    int* deg    = ip;
    int* offs   = ip + NA;
    int* cursor = ip + 2 * NA + 1;
    int* perm   = ip + 3 * NA + 1;
    int* gs     = perm + NE;

    float* Eout = (float*)d_out;

    hipMemsetAsync(deg, 0, NA * sizeof(int), stream);

    k_node_init<<<NA, 128, 0, stream>>>(na, Wemb, aE, h, e0buf);
    k_ranges<<<1, 256, 0, stream>>>(batch, gs);
    k_kspace<<<NA, 128, 0, stream>>>(pos, kgrid, cosd, sind);
    k_kdown<<<1, 1024, 0, stream>>>(krbf, Wdown, kdwn);
    k_edge_geom<<<NE / 256, 256, 0, stream>>>(pos, shifts, eidx, Ybuf, efb);
    k_count<<<NE / 256, 256, 0, stream>>>(eidx, deg);
    k_scan<<<1, 1024, 0, stream>>>(deg, offs, cursor);
    k_fill<<<NE / 256, 256, 0, stream>>>(eidx, cursor, perm);
    k_convW4<<<1024, 64, 0, stream>>>(rW4, W4bt);
    k_convW64<<<128, 64, 0, stream>>>(rW2, W2bt);
    k_convW64<<<128, 64, 0, stream>>>(rW3, W3bt);

    const dim3 gA(NA / 64, C / 64);
    const dim3 gDual(NA / 64, 4);
    const dim3 gSF(BG, 4, 8);
    const dim3 gWB(NE / 256, 512 / 64);

    for (int i = 0; i < 2; i++) {
        const float* Wpre1_i = Wpre1 + (size_t)i * C * C;
        const float* bpre1_i = bpre1 + (size_t)i * C;
        const float* Wpre2_i = Wpre2 + (size_t)i * C * C;
        const float* bpre2_i = bpre2 + (size_t)i * C;
        const float* WupE_i  = WupE + (size_t)i * 8 * C;
        const float* Wm1_i   = Wm1 + (size_t)i * C * C;
        const float* bm1_i   = bm1 + (size_t)i * C;
        const float* Wm2_i   = Wm2 + (size_t)i * C * C;
        const float* bm2_i   = bm2 + (size_t)i * C;
        const float* Wup_i   = Wup + (size_t)i * C * C;
        const float* rW1_i   = rW1 + (size_t)i * 8 * 64;
        const float* rb1_i   = rb1 + (size_t)i * 64;
        const float* rb2_i   = rb2 + (size_t)i * 64;
        const float* rb3_i   = rb3 + (size_t)i * 64;
        const float* w2_i    = w2 + (size_t)i * 4 * C;
        const float* w3_i    = w3 + (size_t)i * 4 * C;
        const float* Wmix_i  = Wmix + (size_t)i * C * C;
        const unsigned short* W4bt_i = W4bt + (size_t)i * 512 * 64;
        const unsigned short* W2bt_i = W2bt + (size_t)i * 64 * 64;
        const unsigned short* W3bt_i = W3bt + (size_t)i * 64 * 64;

        // dual: t1 = silu(h@Wpre1+b), hu = h@Wup
        gemm_dual<<<gDual, 256, 0, stream>>>(h, Wpre1_i, Wup_i, bpre1_i, t1, hu);
        gemm_kernel<128, 0, 0><<<gA, 256, 0, stream>>>(t1, Wpre2_i, bpre2_i, h, nullptr, hres, NA, C, 1.f);

        // edge branch: L1 (f32 GEMM -> bf16), L2/L3 (MFMA), W4 expand (MFMA)
        gemm_kernel<8, 1, 1><<<dim3(NE / 64, 1), 256, 0, stream>>>(efb, rW1_i, rb1_i, nullptr, nullptr, hbuf, NE, 64, 1.f);
        k_mlp_mfma<<<NE / 128, 128, 0, stream>>>(hbuf, W2bt_i, rb2_i, tA);
        k_mlp_mfma<<<NE / 128, 128, 0, stream>>>(tA, W3bt_i, rb3_i, hbuf);
        k_wbuf_mfma<<<gWB, 256, 0, stream>>>(hbuf, W4bt_i, wbuf);

        // Ewald branch
        k_kfilter<<<NK, 128, 0, stream>>>(kdwn, WupE_i, kfil);
        hipMemsetAsync(sfr, 0, 2 * (size_t)BG * NK * C * sizeof(float), stream);
        k_sf<<<gSF, 256, 0, stream>>>(hres, cosd, sind, gs, kfil, sfr, sfi);
        k_he<<<NA, 128, 0, stream>>>(cosd, sind, sfr, sfi, batch, t1);
        gemm_kernel<128, 1, 0><<<gA, 256, 0, stream>>>(t1, Wm1_i, bm1_i, nullptr, nullptr, t2, NA, C, 1.f);
        gemm_kernel<128, 1, 0><<<gA, 256, 0, stream>>>(t2, Wm2_i, bm2_i, nullptr, nullptr, he2, NA, C, 1.f);

        // gather + combine
        k_gather<<<NA, 128, 0, stream>>>(wbuf, hu, Ybuf, eidx, offs, perm, w2_i, w3_i, fe);
        gemm_kernel<128, 0, 0><<<gA, 256, 0, stream>>>(fe, Wmix_i, nullptr, h, he2, hn, NA, C, SKIPF);
        k_node_energy<<<NA, 128, 0, stream>>>(hn, Wr0, Wr1a, Wr1b, (i == 0) ? 0 : 1, nebuf + (size_t)i * NA);

        float* tmp = h; h = hn; hn = tmp;
    }

    k_reduceE<<<BG, 256, 0, stream>>>(e0buf, nebuf, gs, Eout);
}

// Round 7
// 494.579 us; speedup vs baseline: 1.5542x; 1.1253x over previous
//
#include <hip/hip_runtime.h>
#include <hip/hip_bf16.h>
#include <math.h>

// ---------------- problem constants ----------------
constexpr int NA  = 3200;     // atoms
constexpr int NE  = 51200;    // edges
constexpr int C   = 128;      // channels
constexpr int NK  = 123;      // k-points with |k| <= 0.6
constexpr int NKP = 128;      // padded stride for cosd/sind
constexpr int BG  = 8;        // graphs
constexpr int SFSPLIT = 8;    // k_sf split factor
constexpr float SKIPF = 0.57735026918962576f;  // 3^-0.5
constexpr float AVGN  = 16.0f;
constexpr size_t SFSZ = (size_t)BG * NK * C;   // one sf plane (125952)

__device__ __forceinline__ float dsilu(float x) { return x / (1.0f + expf(-x)); }

__device__ __forceinline__ unsigned short f2bf(float f) {
    unsigned int u = __float_as_uint(f);
    unsigned int r = (u + 0x7fffu + ((u >> 16) & 1u)) >> 16;
    return (unsigned short)r;
}
__device__ __forceinline__ float bf2f(unsigned short s) {
    return __uint_as_float(((unsigned int)s) << 16);
}

typedef __attribute__((ext_vector_type(8))) short short8;
typedef __attribute__((ext_vector_type(4))) float f32x4;

// ---------------- generic tiled f32 GEMM ----------------
template <int K, int ACT, int OBF16>
__global__ __launch_bounds__(256, 4) void gemm_kernel(
    const float* __restrict__ X, const float* __restrict__ W,
    const float* __restrict__ bias, const float* __restrict__ res1,
    const float* __restrict__ res2, void* __restrict__ outv,
    int M, int N, float scale)
{
    constexpr int K4 = K / 4;
    constexpr int BK  = (K < 64) ? K : 64;
    constexpr int BK4 = BK / 4;
    constexpr int BK4P = BK4 + 1;
    __shared__ float As[64 * BK4P * 4];
    __shared__ float Bs[BK * 64];
    const int tid = threadIdx.x;
    const int m0 = blockIdx.x * 64;
    const int n0 = blockIdx.y * 64;

    const float4* X4 = (const float4*)X;
    const float4* W4 = (const float4*)W;
    float4* As4 = (float4*)As;
    float4* Bs4 = (float4*)Bs;
    const int N4 = N >> 2;

    const int tx = tid & 15;
    const int ty = tid >> 4;
    float acc[4][4];
#pragma unroll
    for (int i = 0; i < 4; i++)
#pragma unroll
        for (int j = 0; j < 4; j++) acc[i][j] = 0.0f;

    for (int k0 = 0; k0 < K4; k0 += BK4) {
        if (k0) __syncthreads();
        for (int idx = tid; idx < 64 * BK4; idx += 256) {
            int r = idx / BK4, k4 = idx - r * BK4;
            As4[r * BK4P + k4] = X4[(size_t)(m0 + r) * K4 + k0 + k4];
        }
        for (int idx = tid; idx < BK * 16; idx += 256) {
            int kr = idx >> 4, c4 = idx & 15;
            Bs4[idx] = W4[(size_t)(k0 * 4 + kr) * N4 + (n0 >> 2) + c4];
        }
        __syncthreads();

#pragma unroll 4
        for (int k4 = 0; k4 < BK4; k4++) {
            float a[4][4];
#pragma unroll
            for (int i = 0; i < 4; i++) {
                float4 av = As4[(ty * 4 + i) * BK4P + k4];
                a[i][0] = av.x; a[i][1] = av.y; a[i][2] = av.z; a[i][3] = av.w;
            }
#pragma unroll
            for (int kk = 0; kk < 4; kk++) {
                float4 bv = Bs4[(k4 * 4 + kk) * 16 + tx];
#pragma unroll
                for (int i = 0; i < 4; i++) {
                    acc[i][0] += a[i][kk] * bv.x;
                    acc[i][1] += a[i][kk] * bv.y;
                    acc[i][2] += a[i][kk] * bv.z;
                    acc[i][3] += a[i][kk] * bv.w;
                }
            }
        }
    }

    float4 bv = make_float4(0.f, 0.f, 0.f, 0.f);
    if (bias) bv = ((const float4*)bias)[(n0 >> 2) + tx];
#pragma unroll
    for (int i = 0; i < 4; i++) {
        int row = m0 + ty * 4 + i;
        size_t o = (size_t)row * N + n0 + tx * 4;
        float4 v;
        v.x = acc[i][0] + bv.x; v.y = acc[i][1] + bv.y;
        v.z = acc[i][2] + bv.z; v.w = acc[i][3] + bv.w;
        if (ACT) { v.x = dsilu(v.x); v.y = dsilu(v.y); v.z = dsilu(v.z); v.w = dsilu(v.w); }
        if (res1) { float4 r = *(const float4*)(res1 + o); v.x += r.x; v.y += r.y; v.z += r.z; v.w += r.w; }
        if (res2) { float4 r = *(const float4*)(res2 + o); v.x += r.x; v.y += r.y; v.z += r.z; v.w += r.w; }
        v.x *= scale; v.y *= scale; v.z *= scale; v.w *= scale;
        if (OBF16) {
            ushort4 pk;
            pk.x = f2bf(v.x); pk.y = f2bf(v.y); pk.z = f2bf(v.z); pk.w = f2bf(v.w);
            *(ushort4*)((unsigned short*)outv + o) = pk;
        } else {
            *(float4*)((float*)outv + o) = v;
        }
    }
}

// ---------------- dual GEMM: t1 = silu(h@Wa + bias), hu = h@Wb ----------------
__global__ __launch_bounds__(256, 4) void gemm_dual(
    const float* __restrict__ X, const float* __restrict__ Wa,
    const float* __restrict__ Wb, const float* __restrict__ bias,
    float* __restrict__ outa, float* __restrict__ outb)
{
    constexpr int K4 = 32, BK4 = 16, BK4P = 17;
    __shared__ float As[64 * BK4P * 4];
    __shared__ float Bs[64 * 64];
    const int tid = threadIdx.x;
    const int m0 = blockIdx.x * 64;
    const int sel = blockIdx.y >> 1;
    const int n0 = (blockIdx.y & 1) * 64;
    const float* W = sel ? Wb : Wa;
    float* out = sel ? outb : outa;

    const float4* X4 = (const float4*)X;
    const float4* W4 = (const float4*)W;
    float4* As4 = (float4*)As;
    float4* Bs4 = (float4*)Bs;

    const int tx = tid & 15;
    const int ty = tid >> 4;
    float acc[4][4];
#pragma unroll
    for (int i = 0; i < 4; i++)
#pragma unroll
        for (int j = 0; j < 4; j++) acc[i][j] = 0.0f;

    for (int k0 = 0; k0 < K4; k0 += BK4) {
        if (k0) __syncthreads();
        for (int idx = tid; idx < 64 * BK4; idx += 256) {
            int r = idx / BK4, k4 = idx - r * BK4;
            As4[r * BK4P + k4] = X4[(size_t)(m0 + r) * K4 + k0 + k4];
        }
        for (int idx = tid; idx < 64 * 16; idx += 256) {
            int kr = idx >> 4, c4 = idx & 15;
            Bs4[idx] = W4[(size_t)(k0 * 4 + kr) * 32 + (n0 >> 2) + c4];
        }
        __syncthreads();

#pragma unroll 4
        for (int k4 = 0; k4 < BK4; k4++) {
            float a[4][4];
#pragma unroll
            for (int i = 0; i < 4; i++) {
                float4 av = As4[(ty * 4 + i) * BK4P + k4];
                a[i][0] = av.x; a[i][1] = av.y; a[i][2] = av.z; a[i][3] = av.w;
            }
#pragma unroll
            for (int kk = 0; kk < 4; kk++) {
                float4 bv = Bs4[(k4 * 4 + kk) * 16 + tx];
#pragma unroll
                for (int i = 0; i < 4; i++) {
                    acc[i][0] += a[i][kk] * bv.x;
                    acc[i][1] += a[i][kk] * bv.y;
                    acc[i][2] += a[i][kk] * bv.z;
                    acc[i][3] += a[i][kk] * bv.w;
                }
            }
        }
    }

    float4 bv = make_float4(0.f, 0.f, 0.f, 0.f);
    if (!sel) bv = ((const float4*)bias)[(n0 >> 2) + tx];
#pragma unroll
    for (int i = 0; i < 4; i++) {
        int row = m0 + ty * 4 + i;
        size_t o = (size_t)row * 128 + n0 + tx * 4;
        float4 v;
        v.x = acc[i][0] + bv.x; v.y = acc[i][1] + bv.y;
        v.z = acc[i][2] + bv.z; v.w = acc[i][3] + bv.w;
        if (!sel) { v.x = dsilu(v.x); v.y = dsilu(v.y); v.z = dsilu(v.z); v.w = dsilu(v.w); }
        *(float4*)(out + o) = v;
    }
}

// ---------------- MFMA MLP layer: out = silu(X @ Wt^T + bias), all bf16 ----------------
__global__ __launch_bounds__(128, 2) void k_mlp_mfma(
    const unsigned short* __restrict__ X, const unsigned short* __restrict__ Wt,
    const float* __restrict__ bias, unsigned short* __restrict__ out)
{
    constexpr int MT = 128, AS = 72;
    __shared__ unsigned short Als[MT * AS];
    __shared__ unsigned short Bls[64 * AS];
    const int tid = threadIdx.x;
    const int m0 = blockIdx.x * MT;

    for (int idx = tid; idx < MT * 8; idx += 128) {
        int r = idx >> 3, s = idx & 7;
        *(short8*)(Als + r * AS + s * 8) = ((const short8*)X)[(size_t)(m0 + r) * 8 + s];
    }
    for (int idx = tid; idx < 64 * 8; idx += 128) {
        int r = idx >> 3, s = idx & 7;
        *(short8*)(Bls + r * AS + s * 8) = ((const short8*)Wt)[(size_t)r * 8 + s];
    }
    __syncthreads();

    const int wave = tid >> 6;
    const int lane = tid & 63;
    const int q = lane >> 4;
    const int l16 = lane & 15;
    const int mw = wave * 64;

    f32x4 acc[4][4];
#pragma unroll
    for (int mi = 0; mi < 4; mi++)
#pragma unroll
        for (int ni = 0; ni < 4; ni++) acc[mi][ni] = (f32x4){0.f, 0.f, 0.f, 0.f};

#pragma unroll
    for (int kc = 0; kc < 2; kc++) {
        short8 a[4], b[4];
#pragma unroll
        for (int mi = 0; mi < 4; mi++)
            a[mi] = *(const short8*)(Als + (mw + mi * 16 + l16) * AS + kc * 32 + q * 8);
#pragma unroll
        for (int ni = 0; ni < 4; ni++)
            b[ni] = *(const short8*)(Bls + (ni * 16 + l16) * AS + kc * 32 + q * 8);
#pragma unroll
        for (int mi = 0; mi < 4; mi++)
#pragma unroll
            for (int ni = 0; ni < 4; ni++)
                acc[mi][ni] = __builtin_amdgcn_mfma_f32_16x16x32_bf16(a[mi], b[ni], acc[mi][ni], 0, 0, 0);
    }

#pragma unroll
    for (int ni = 0; ni < 4; ni++) {
        float bv = bias[ni * 16 + l16];
#pragma unroll
        for (int mi = 0; mi < 4; mi++) {
#pragma unroll
            for (int r = 0; r < 4; r++) {
                int e = m0 + mw + mi * 16 + q * 4 + r;
                int n = ni * 16 + l16;
                out[(size_t)e * 64 + n] = f2bf(dsilu(acc[mi][ni][r] + bv));
            }
        }
    }
}

// ---------------- weight converts ----------------
__global__ __launch_bounds__(64) void k_convW4(
    const float* __restrict__ rW4, unsigned short* __restrict__ W4bt)
{
    int b = blockIdx.x;
    int layer = b >> 9, n = b & 511;
    int k = threadIdx.x;
    W4bt[((size_t)layer * 512 + n) * 64 + k] = f2bf(rW4[((size_t)layer * 64 + k) * 512 + n]);
}

__global__ __launch_bounds__(64) void k_convW64(
    const float* __restrict__ rW, unsigned short* __restrict__ Wbt)
{
    int b = blockIdx.x;
    int layer = b >> 6, n = b & 63;
    int k = threadIdx.x;
    Wbt[((size_t)layer * 64 + n) * 64 + k] = f2bf(rW[((size_t)layer * 64 + k) * 64 + n]);
}

// ---------------- MFMA GEMM: wbuf[e][n] = tA[e][0:64] @ W4t[n][0:64], bf16 ----------------
__global__ __launch_bounds__(256, 2) void k_wbuf_mfma(
    const unsigned short* __restrict__ tA, const unsigned short* __restrict__ W4t,
    unsigned short* __restrict__ wbuf)
{
    constexpr int MT = 256, NT = 64, AS = 72;
    __shared__ unsigned short Als[MT * AS];
    __shared__ unsigned short Bls[NT * AS];
    const int tid = threadIdx.x;
    const int m0 = blockIdx.x * MT;
    const int n0 = blockIdx.y * NT;

    for (int idx = tid; idx < MT * 8; idx += 256) {
        int r = idx >> 3, s = idx & 7;
        *(short8*)(Als + r * AS + s * 8) = ((const short8*)tA)[(size_t)(m0 + r) * 8 + s];
    }
    for (int idx = tid; idx < NT * 8; idx += 256) {
        int r = idx >> 3, s = idx & 7;
        *(short8*)(Bls + r * AS + s * 8) = ((const short8*)W4t)[(size_t)(n0 + r) * 8 + s];
    }
    __syncthreads();

    const int wave = tid >> 6;
    const int lane = tid & 63;
    const int q = lane >> 4;
    const int l16 = lane & 15;
    const int mw = wave * 64;

    f32x4 acc[4][4];
#pragma unroll
    for (int mi = 0; mi < 4; mi++)
#pragma unroll
        for (int ni = 0; ni < 4; ni++) acc[mi][ni] = (f32x4){0.f, 0.f, 0.f, 0.f};

#pragma unroll
    for (int kc = 0; kc < 2; kc++) {
        short8 a[4], b[4];
#pragma unroll
        for (int mi = 0; mi < 4; mi++)
            a[mi] = *(const short8*)(Als + (mw + mi * 16 + l16) * AS + kc * 32 + q * 8);
#pragma unroll
        for (int ni = 0; ni < 4; ni++)
            b[ni] = *(const short8*)(Bls + (ni * 16 + l16) * AS + kc * 32 + q * 8);
#pragma unroll
        for (int mi = 0; mi < 4; mi++)
#pragma unroll
            for (int ni = 0; ni < 4; ni++)
                acc[mi][ni] = __builtin_amdgcn_mfma_f32_16x16x32_bf16(a[mi], b[ni], acc[mi][ni], 0, 0, 0);
    }

#pragma unroll
    for (int mi = 0; mi < 4; mi++) {
#pragma unroll
        for (int ni = 0; ni < 4; ni++) {
#pragma unroll
            for (int r = 0; r < 4; r++) {
                int e = m0 + mw + mi * 16 + q * 4 + r;
                int n = n0 + ni * 16 + l16;
                wbuf[(size_t)e * 512 + n] = f2bf(acc[mi][ni][r]);
            }
        }
    }
}

// ---------------- setup kernels ----------------
__global__ __launch_bounds__(128) void k_node_init(
    const float* __restrict__ na, const float* __restrict__ Wemb,
    const float* __restrict__ aE, float* __restrict__ h, float* __restrict__ e0buf)
{
    int n = blockIdx.x, c = threadIdx.x;
    float s = 0.f;
#pragma unroll
    for (int k = 0; k < 10; k++) s += na[n * 10 + k] * Wemb[k * C + c];
    h[(size_t)n * C + c] = s;
    if (c == 0) {
        float e = 0.f;
#pragma unroll
        for (int k = 0; k < 10; k++) e += na[n * 10 + k] * aE[k];
        e0buf[n] = e;
    }
}

__global__ __launch_bounds__(256) void k_ranges(const int* __restrict__ batch, int* __restrict__ gs)
{
    __shared__ int cnt[BG];
    if (threadIdx.x < BG) cnt[threadIdx.x] = 0;
    __syncthreads();
    for (int n = threadIdx.x; n < NA; n += 256) atomicAdd(&cnt[batch[n]], 1);
    __syncthreads();
    if (threadIdx.x == 0) {
        int s = 0;
        for (int b = 0; b < BG; b++) { gs[b] = s; s += cnt[b]; }
        gs[BG] = s;
    }
}

__device__ __forceinline__ float sincn(float x) {
    float px = 3.14159265358979323846f * x;
    return (fabsf(px) < 1e-8f) ? 1.0f : (sinf(px) / px);
}

__global__ __launch_bounds__(128) void k_kspace(
    const float* __restrict__ pos, const float* __restrict__ kgrid,
    float* __restrict__ cosd, float* __restrict__ sind)
{
    int n = blockIdx.x, k = threadIdx.x;
    float p0 = pos[n * 3 + 0], p1 = pos[n * 3 + 1], p2 = pos[n * 3 + 2];
    float sd = sincn(0.1f * p0) * sincn(0.1f * p1) * sincn(0.1f * p2);
    if (k < NK) {
        float d = p0 * kgrid[k * 3 + 0] + p1 * kgrid[k * 3 + 1] + p2 * kgrid[k * 3 + 2];
        float sn, cs;
        sincosf(d, &sn, &cs);
        cosd[(size_t)n * NKP + k] = sd * cs;
        sind[(size_t)n * NKP + k] = sd * sn;
    } else {
        cosd[(size_t)n * NKP + k] = 0.f;
        sind[(size_t)n * NKP + k] = 0.f;
    }
}

__global__ __launch_bounds__(1024) void k_kdown(
    const float* __restrict__ krbf, const float* __restrict__ Wdown, float* __restrict__ kdown)
{
    int t = threadIdx.x;
    if (t < NK * 8) {
        int k = t >> 3, j = t & 7;
        float s = 0.f;
        for (int r = 0; r < 128; r++) s += krbf[k * 128 + r] * Wdown[r * 8 + j];
        kdown[t] = s;
    }
}

__global__ __launch_bounds__(256) void k_edge_geom(
    const float* __restrict__ pos, const float* __restrict__ shifts,
    const int* __restrict__ eidx, float* __restrict__ Y, float* __restrict__ ef)
{
    int e = blockIdx.x * 256 + threadIdx.x;
    if (e >= NE) return;
    int s = eidx[e], d = eidx[NE + e];
    float vx = pos[d * 3 + 0] - pos[s * 3 + 0] + shifts[e * 3 + 0];
    float vy = pos[d * 3 + 1] - pos[s * 3 + 1] + shifts[e * 3 + 1];
    float vz = pos[d * 3 + 2] - pos[s * 3 + 2] + shifts[e * 3 + 2];
    float r = sqrtf(vx * vx + vy * vy + vz * vz);
    float rinv = 1.0f / fmaxf(r, 1e-9f);
    float x = vx * rinv, y = vy * rinv, z = vz * rinv;

    const float s3 = 1.7320508075688772f, s5 = 2.2360679774997896f, s15 = 3.8729833462074170f;
    const float c70 = 2.0916500663351889f;
    const float c105 = 10.246950765959598f;
    const float c42 = 1.6201851746019651f;
    const float c7 = 1.3228756555322954f;
    float o[16];
    o[0] = 1.0f;
    o[1] = s3 * x; o[2] = s3 * y; o[3] = s3 * z;
    o[4] = s15 * x * y; o[5] = s15 * y * z; o[6] = 0.5f * s5 * (3.f * z * z - 1.f);
    o[7] = s15 * x * z; o[8] = 0.5f * s15 * (x * x - y * y);
    o[9]  = c70 * y * (3.f * x * x - y * y);
    o[10] = c105 * x * y * z;
    o[11] = c42 * y * (5.f * z * z - 1.f);
    o[12] = c7 * z * (5.f * z * z - 3.f);
    o[13] = c42 * x * (5.f * z * z - 1.f);
    o[14] = 0.5f * c105 * z * (x * x - y * y);
    o[15] = c70 * x * (x * x - 3.f * y * y);
    float4* Y4 = (float4*)(Y + (size_t)e * 16);
    Y4[0] = make_float4(o[0], o[1], o[2], o[3]);
    Y4[1] = make_float4(o[4], o[5], o[6], o[7]);
    Y4[2] = make_float4(o[8], o[9], o[10], o[11]);
    Y4[3] = make_float4(o[12], o[13], o[14], o[15]);

    float uu = fminf(fmaxf(r * 0.2f, 0.f), 1.f);
    float u2 = uu * uu, u4 = u2 * u2, u5 = u4 * uu, u6 = u5 * uu, u7 = u6 * uu;
    float env = 1.f - 21.f * u5 + 35.f * u6 - 15.f * u7;
    env = (r < 5.0f) ? env : 0.0f;
    float pref = 0.63245553203367587f * rinv * env;
    const float pio5 = 0.62831853071795865f;
    float efv[8];
#pragma unroll
    for (int n1 = 1; n1 <= 8; n1++) efv[n1 - 1] = pref * sinf(n1 * pio5 * r);
    float4* E4 = (float4*)(ef + (size_t)e * 8);
    E4[0] = make_float4(efv[0], efv[1], efv[2], efv[3]);
    E4[1] = make_float4(efv[4], efv[5], efv[6], efv[7]);
}

// ---------------- CSR by dst ----------------
__global__ __launch_bounds__(256) void k_count(const int* __restrict__ eidx, int* __restrict__ deg)
{
    int e = blockIdx.x * 256 + threadIdx.x;
    if (e < NE) atomicAdd(&deg[eidx[NE + e]], 1);
}

__global__ __launch_bounds__(1024) void k_scan(
    const int* __restrict__ deg, int* __restrict__ offs, int* __restrict__ cursor)
{
    __shared__ int sc[1024];
    int tid = threadIdx.x;
    int base = tid * 4;
    int v[4]; int s = 0;
#pragma unroll
    for (int i = 0; i < 4; i++) {
        int idx = base + i;
        int d = (idx < NA) ? deg[idx] : 0;
        v[i] = s; s += d;
    }
    sc[tid] = s;
    __syncthreads();
    for (int ofs = 1; ofs < 1024; ofs <<= 1) {
        int t = (tid >= ofs) ? sc[tid - ofs] : 0;
        __syncthreads();
        sc[tid] += t;
        __syncthreads();
    }
    int excl = (tid > 0) ? sc[tid - 1] : 0;
#pragma unroll
    for (int i = 0; i < 4; i++) {
        int idx = base + i;
        if (idx < NA) { int o = excl + v[i]; offs[idx] = o; cursor[idx] = o; }
    }
    if (tid == 1023) offs[NA] = sc[1023];
}

__global__ __launch_bounds__(256) void k_fill(
    const int* __restrict__ eidx, int* __restrict__ cursor, int* __restrict__ perm)
{
    int e = blockIdx.x * 256 + threadIdx.x;
    if (e < NE) {
        int d = eidx[NE + e];
        int p = atomicAdd(&cursor[d], 1);
        perm[p] = e;
    }
}

// ---------------- Ewald kernels ----------------
__global__ __launch_bounds__(128) void k_kfilter(
    const float* __restrict__ kdown, const float* __restrict__ WupE, float* __restrict__ kf)
{
    int k = blockIdx.x, c = threadIdx.x;
    float s = 0.f;
#pragma unroll
    for (int j = 0; j < 8; j++) s += kdown[k * 8 + j] * WupE[j * C + c];
    kf[(size_t)k * C + c] = s;
}

// structure-factor partials: plain stores per split, no atomics.
// sfp layout: [r: sp=0..7][i: sp=0..7], each plane SFSZ floats.
__global__ __launch_bounds__(256, 4) void k_sf(
    const float* __restrict__ hres, const float* __restrict__ cosd, const float* __restrict__ sind,
    const int* __restrict__ gs, const float* __restrict__ kf,
    float* __restrict__ sfp)
{
    const int b = blockIdx.x, kt = blockIdx.y, sp = blockIdx.z;
    const int n0 = gs[b], n1 = gs[b + 1];
    const int cnt = n1 - n0;
    const int per = (cnt + SFSPLIT - 1) / SFSPLIT;
    const int cs = n0 + sp * per;
    const int ce = min(cs + per, n1);

    __shared__ float Hs[32 * 128];
    __shared__ float Cs[32 * 32];
    __shared__ float Ss[32 * 32];

    const int tid = threadIdx.x;
    const int tx = tid & 31;
    const int ty = tid >> 5;

    float accR[4][4], accI[4][4];
#pragma unroll
    for (int i = 0; i < 4; i++)
#pragma unroll
        for (int j = 0; j < 4; j++) { accR[i][j] = 0.f; accI[i][j] = 0.f; }

    float4* H4 = (float4*)Hs;
    float4* C4 = (float4*)Cs;
    float4* S4 = (float4*)Ss;

    for (int nb = cs; nb < ce; nb += 32) {
        __syncthreads();
        for (int idx = tid; idx < 32 * 32; idx += 256) {
            int r = idx >> 5, c4 = idx & 31;
            int n = nb + r;
            H4[idx] = (n < ce) ? ((const float4*)hres)[(size_t)n * 32 + c4]
                               : make_float4(0.f, 0.f, 0.f, 0.f);
        }
        for (int idx = tid; idx < 32 * 8; idx += 256) {
            int r = idx >> 3, k4 = idx & 7;
            int n = nb + r;
            float4 cv = make_float4(0.f, 0.f, 0.f, 0.f), sv = cv;
            if (n < ce) {
                cv = ((const float4*)cosd)[(size_t)n * 32 + kt * 8 + k4];
                sv = ((const float4*)sind)[(size_t)n * 32 + kt * 8 + k4];
            }
            C4[idx] = cv;
            S4[idx] = sv;
        }
        __syncthreads();
        const int lim = min(32, ce - nb);
        for (int n = 0; n < lim; n++) {
            float4 hv = H4[n * 32 + tx];
            float4 cv = C4[n * 8 + ty];
            float4 sv = S4[n * 8 + ty];
            float h[4] = { hv.x, hv.y, hv.z, hv.w };
            float ck[4] = { cv.x, cv.y, cv.z, cv.w };
            float sk[4] = { sv.x, sv.y, sv.z, sv.w };
#pragma unroll
            for (int i = 0; i < 4; i++)
#pragma unroll
                for (int j = 0; j < 4; j++) {
                    accR[i][j] += ck[i] * h[j];
                    accI[i][j] += sk[i] * h[j];
                }
        }
    }

    const int kbase = kt * 32 + ty * 4;
    float* baseR = sfp + (size_t)sp * SFSZ;
    float* baseI = sfp + (size_t)(SFSPLIT + sp) * SFSZ;
#pragma unroll
    for (int i = 0; i < 4; i++) {
        int k = kbase + i;
        if (k < NK) {
            float4 kfv = ((const float4*)kf)[(size_t)k * 32 + tx];
            float vx = kfv.x * 0.01f, vy = kfv.y * 0.01f, vz = kfv.z * 0.01f, vw = kfv.w * 0.01f;
            size_t o = ((size_t)(b * NK + k)) * C + tx * 4;
            *(float4*)(baseR + o) = make_float4(accR[i][0] * vx, accR[i][1] * vy,
                                                accR[i][2] * vz, accR[i][3] * vw);
            *(float4*)(baseI + o) = make_float4(accI[i][0] * vx, accI[i][1] * vy,
                                                accI[i][2] * vz, accI[i][3] * vw);
        }
    }
}

// reduce split partials -> sfr, sfi
__global__ __launch_bounds__(256) void k_sfred(
    const float* __restrict__ sfp, float* __restrict__ sfr, float* __restrict__ sfi)
{
    const size_t S4 = SFSZ / 4;
    size_t o4 = (size_t)blockIdx.x * 256 + threadIdx.x;
    if (o4 >= S4) return;
    const float4* p = (const float4*)sfp;
    float4 ar = make_float4(0.f, 0.f, 0.f, 0.f), ai = ar;
#pragma unroll
    for (int sp = 0; sp < SFSPLIT; sp++) {
        float4 r = p[(size_t)sp * S4 + o4];
        ar.x += r.x; ar.y += r.y; ar.z += r.z; ar.w += r.w;
        float4 q = p[(size_t)(SFSPLIT + sp) * S4 + o4];
        ai.x += q.x; ai.y += q.y; ai.z += q.z; ai.w += q.w;
    }
    ((float4*)sfr)[o4] = ar;
    ((float4*)sfi)[o4] = ai;
}

__global__ __launch_bounds__(128) void k_he(
    const float* __restrict__ cosd, const float* __restrict__ sind,
    const float* __restrict__ sfr, const float* __restrict__ sfi,
    const int* __restrict__ batch, float* __restrict__ out)
{
    int n = blockIdx.x, c = threadIdx.x;
    int b = batch[n];
    const float* pr = sfr + (size_t)b * NK * C;
    const float* pi = sfi + (size_t)b * NK * C;
    const float* cdp = cosd + (size_t)n * NKP;
    const float* sdp = sind + (size_t)n * NKP;
    float acc = 0.f;
    for (int k = 0; k < NK; k++) {
        acc += cdp[k] * pr[(size_t)k * C + c] + sdp[k] * pi[(size_t)k * C + c];
    }
    out[(size_t)n * C + c] = acc;
}

// ---------------- message gather + symmetric contraction ----------------
__global__ __launch_bounds__(128) void k_gather(
    const unsigned short* __restrict__ wbuf, const float* __restrict__ hu,
    const float* __restrict__ Y, const int* __restrict__ srcArr,
    const int* __restrict__ offs, const int* __restrict__ perm,
    const float* __restrict__ w2, const float* __restrict__ w3,
    float* __restrict__ feats)
{
    int n = blockIdx.x, c = threadIdx.x;
    int j0 = offs[n], j1 = offs[n + 1];
    float A[16];
#pragma unroll
    for (int s = 0; s < 16; s++) A[s] = 0.f;
    for (int j = j0; j < j1; j++) {
        int e = perm[j];
        int s = srcArr[e];
        float huc = hu[(size_t)s * C + c];
        ushort4 wv = *(const ushort4*)(wbuf + (size_t)e * 512 + c * 4);
        const float4* Yp = (const float4*)(Y + (size_t)e * 16);
        float4 y0 = Yp[0], y1 = Yp[1], y2 = Yp[2], y3 = Yp[3];
        float m0 = bf2f(wv.x) * huc, m1 = bf2f(wv.y) * huc;
        float m2 = bf2f(wv.z) * huc, m3 = bf2f(wv.w) * huc;
        A[0] += m0 * y0.x;
        A[1] += m1 * y0.y;  A[2]  += m1 * y0.z;  A[3]  += m1 * y0.w;
        A[4] += m2 * y1.x;  A[5]  += m2 * y1.y;  A[6]  += m2 * y1.z;  A[7] += m2 * y1.w;
        A[8] += m2 * y2.x;
        A[9] += m3 * y2.y;  A[10] += m3 * y2.z;  A[11] += m3 * y2.w;
        A[12] += m3 * y3.x; A[13] += m3 * y3.y;  A[14] += m3 * y3.z;  A[15] += m3 * y3.w;
    }
    const float inv = 1.0f / AVGN;
#pragma unroll
    for (int s = 0; s < 16; s++) A[s] *= inv;
    float scal = A[0];
    float i0 = A[0] * A[0];
    float i1 = A[1] * A[1] + A[2] * A[2] + A[3] * A[3];
    float i2 = A[4] * A[4] + A[5] * A[5] + A[6] * A[6] + A[7] * A[7] + A[8] * A[8];
    float i3 = A[9] * A[9] + A[10] * A[10] + A[11] * A[11] + A[12] * A[12] +
               A[13] * A[13] + A[14] * A[14] + A[15] * A[15];
    float t2 = i0 * w2[c] + i1 * w2[C + c] + i2 * w2[2 * C + c] + i3 * w2[3 * C + c];
    float t3 = i0 * w3[c] + i1 * w3[C + c] + i2 * w3[2 * C + c] + i3 * w3[3 * C + c];
    feats[(size_t)n * C + c] = scal + t2 + scal * t3;
}

// ---------------- readout energy (per-node, no atomics) ----------------
__global__ __launch_bounds__(128) void k_node_energy(
    const float* __restrict__ h, const float* __restrict__ Wr0,
    const float* __restrict__ Wr1a, const float* __restrict__ Wr1b,
    int mode, float* __restrict__ nebuf)
{
    int n = blockIdx.x, t = threadIdx.x;
    __shared__ float hs[128];
    __shared__ float red[16];
    float hv = h[(size_t)n * C + t];
    if (mode == 0) {
        float v = hv * Wr0[t];
#pragma unroll
        for (int o = 32; o; o >>= 1) v += __shfl_down(v, o, 64);
        if ((t & 63) == 0) red[t >> 6] = v;
        __syncthreads();
        if (t == 0) nebuf[n] = red[0] + red[1];
    } else {
        hs[t] = hv;
        __syncthreads();
        if (t < 16) {
            float s = 0.f;
#pragma unroll 8
            for (int cc = 0; cc < 128; cc++) s += hs[cc] * Wr1a[cc * 16 + t];
            red[t] = dsilu(s) * Wr1b[t];
        }
        __syncthreads();
        if (t == 0) {
            float s = 0.f;
#pragma unroll
            for (int j = 0; j < 16; j++) s += red[j];
            nebuf[n] = s;
        }
    }
}

// ---------------- final per-graph energy reduction ----------------
__global__ __launch_bounds__(256) void k_reduceE(
    const float* __restrict__ e0buf, const float* __restrict__ nebuf,
    const int* __restrict__ gs, float* __restrict__ Eout)
{
    int b = blockIdx.x, t = threadIdx.x;
    int n0 = gs[b], n1 = gs[b + 1];
    float s = 0.f;
    for (int n = n0 + t; n < n1; n += 256)
        s += e0buf[n] + nebuf[n] + nebuf[NA + n];
#pragma unroll
    for (int o = 32; o; o >>= 1) s += __shfl_down(s, o, 64);
    __shared__ float red[4];
    if ((t & 63) == 0) red[t >> 6] = s;
    __syncthreads();
    if (t == 0) Eout[b] = red[0] + red[1] + red[2] + red[3];
}

// ---------------- workspace layout (floats) ----------------
constexpr size_t NAC   = (size_t)NA * C;
constexpr size_t F_COSD = 0;
constexpr size_t F_SIND = F_COSD + (size_t)NA * NKP;
constexpr size_t F_Y    = F_SIND + (size_t)NA * NKP;
constexpr size_t F_EF   = F_Y + (size_t)NE * 16;
constexpr size_t F_H    = F_EF + (size_t)NE * 8;
constexpr size_t F_HN   = F_H + NAC;
constexpr size_t F_HRES = F_HN + NAC;
constexpr size_t F_T1   = F_HRES + NAC;
constexpr size_t F_T2   = F_T1 + NAC;
constexpr size_t F_HE2  = F_T2 + NAC;
constexpr size_t F_HU   = F_HE2 + NAC;
constexpr size_t F_FE   = F_HU + NAC;
constexpr size_t F_TA   = F_FE + NAC;                // bf16 tA (NE*64) + hbuf (NE*64) shorts
constexpr size_t F_TB   = F_TA + (size_t)NE * 64;    // bf16 W4bt + W2bt + W3bt
constexpr size_t F_W    = F_TB + (size_t)NE * 64;    // bf16 wbuf: NE*512 shorts
constexpr size_t F_SFR  = F_W + (size_t)NE * 512;
constexpr size_t F_SFI  = F_SFR + SFSZ;
constexpr size_t F_SFP  = F_SFI + SFSZ;              // 16 planes of SFSZ
constexpr size_t F_KD   = F_SFP + 2 * (size_t)SFSPLIT * SFSZ;
constexpr size_t F_KF   = F_KD + 1024;
constexpr size_t F_E0   = F_KF + (size_t)NK * C;     // e0buf: NA
constexpr size_t F_NE   = F_E0 + NA;                 // nebuf: 2*NA
constexpr size_t F_END  = F_NE + 2 * (size_t)NA;
constexpr size_t I_BASE = ((F_END * 4 + 255) / 256) * 256;

extern "C" void kernel_launch(void* const* d_in, const int* in_sizes, int n_in,
                              void* d_out, int out_size, void* d_ws, size_t ws_size,
                              hipStream_t stream) {
    const float* pos    = (const float*)d_in[0];
    const float* na     = (const float*)d_in[1];
    const float* shifts = (const float*)d_in[2];
    const int*   eidx   = (const int*)d_in[3];
    const int*   batch  = (const int*)d_in[4];
    const float* kgrid  = (const float*)d_in[5];
    const float* krbf   = (const float*)d_in[6];
    const float* Wemb   = (const float*)d_in[7];
    const float* aE     = (const float*)d_in[8];
    const float* rW1    = (const float*)d_in[9];
    const float* rb1    = (const float*)d_in[10];
    const float* rW2    = (const float*)d_in[11];
    const float* rb2    = (const float*)d_in[12];
    const float* rW3    = (const float*)d_in[13];
    const float* rb3    = (const float*)d_in[14];
    const float* rW4    = (const float*)d_in[15];
    const float* Wup    = (const float*)d_in[16];
    const float* w2     = (const float*)d_in[17];
    const float* w3     = (const float*)d_in[18];
    const float* Wmix   = (const float*)d_in[19];
    const float* Wr0    = (const float*)d_in[20];
    const float* Wr1a   = (const float*)d_in[21];
    const float* Wr1b   = (const float*)d_in[22];
    const float* Wdown  = (const float*)d_in[23];
    const float* WupE   = (const float*)d_in[24];
    const float* Wpre1  = (const float*)d_in[25];
    const float* bpre1  = (const float*)d_in[26];
    const float* Wpre2  = (const float*)d_in[27];
    const float* bpre2  = (const float*)d_in[28];
    const float* Wm1    = (const float*)d_in[29];
    const float* bm1    = (const float*)d_in[30];
    const float* Wm2    = (const float*)d_in[31];
    const float* bm2    = (const float*)d_in[32];

    float* fw = (float*)d_ws;
    float* cosd = fw + F_COSD;
    float* sind = fw + F_SIND;
    float* Ybuf = fw + F_Y;
    float* efb  = fw + F_EF;
    float* h    = fw + F_H;
    float* hn   = fw + F_HN;
    float* hres = fw + F_HRES;
    float* t1   = fw + F_T1;
    float* t2   = fw + F_T2;
    float* he2  = fw + F_HE2;
    float* hu   = fw + F_HU;
    float* fe   = fw + F_FE;
    unsigned short* tA   = (unsigned short*)(fw + F_TA);
    unsigned short* hbuf = tA + (size_t)NE * 64;
    unsigned short* W4bt = (unsigned short*)(fw + F_TB);
    unsigned short* W2bt = W4bt + (size_t)2 * 512 * 64;
    unsigned short* W3bt = W2bt + (size_t)2 * 64 * 64;
    unsigned short* wbuf = (unsigned short*)(fw + F_W);
    float* sfr  = fw + F_SFR;
    float* sfi  = fw + F_SFI;
    float* sfp  = fw + F_SFP;
    float* kdwn = fw + F_KD;
    float* kfil = fw + F_KF;
    float* e0buf = fw + F_E0;
    float* nebuf = fw + F_NE;

    int* ip     = (int*)((char*)d_ws + I_BASE);
    int* deg    = ip;
    int* offs   = ip + NA;
    int* cursor = ip + 2 * NA + 1;
    int* perm   = ip + 3 * NA + 1;
    int* gs     = perm + NE;

    float* Eout = (float*)d_out;

    hipMemsetAsync(deg, 0, NA * sizeof(int), stream);

    k_node_init<<<NA, 128, 0, stream>>>(na, Wemb, aE, h, e0buf);
    k_ranges<<<1, 256, 0, stream>>>(batch, gs);
    k_kspace<<<NA, 128, 0, stream>>>(pos, kgrid, cosd, sind);
    k_kdown<<<1, 1024, 0, stream>>>(krbf, Wdown, kdwn);
    k_edge_geom<<<NE / 256, 256, 0, stream>>>(pos, shifts, eidx, Ybuf, efb);
    k_count<<<NE / 256, 256, 0, stream>>>(eidx, deg);
    k_scan<<<1, 1024, 0, stream>>>(deg, offs, cursor);
    k_fill<<<NE / 256, 256, 0, stream>>>(eidx, cursor, perm);
    k_convW4<<<1024, 64, 0, stream>>>(rW4, W4bt);
    k_convW64<<<128, 64, 0, stream>>>(rW2, W2bt);
    k_convW64<<<128, 64, 0, stream>>>(rW3, W3bt);

    const dim3 gA(NA / 64, C / 64);
    const dim3 gDual(NA / 64, 4);
    const dim3 gSF(BG, 4, SFSPLIT);
    const dim3 gWB(NE / 256, 512 / 64);
    const int gRED = (int)((SFSZ / 4 + 255) / 256);

    for (int i = 0; i < 2; i++) {
        const float* Wpre1_i = Wpre1 + (size_t)i * C * C;
        const float* bpre1_i = bpre1 + (size_t)i * C;
        const float* Wpre2_i = Wpre2 + (size_t)i * C * C;
        const float* bpre2_i = bpre2 + (size_t)i * C;
        const float* WupE_i  = WupE + (size_t)i * 8 * C;
        const float* Wm1_i   = Wm1 + (size_t)i * C * C;
        const float* bm1_i   = bm1 + (size_t)i * C;
        const float* Wm2_i   = Wm2 + (size_t)i * C * C;
        const float* bm2_i   = bm2 + (size_t)i * C;
        const float* Wup_i   = Wup + (size_t)i * C * C;
        const float* rW1_i   = rW1 + (size_t)i * 8 * 64;
        const float* rb1_i   = rb1 + (size_t)i * 64;
        const float* rb2_i   = rb2 + (size_t)i * 64;
        const float* rb3_i   = rb3 + (size_t)i * 64;
        const float* w2_i    = w2 + (size_t)i * 4 * C;
        const float* w3_i    = w3 + (size_t)i * 4 * C;
        const float* Wmix_i  = Wmix + (size_t)i * C * C;
        const unsigned short* W4bt_i = W4bt + (size_t)i * 512 * 64;
        const unsigned short* W2bt_i = W2bt + (size_t)i * 64 * 64;
        const unsigned short* W3bt_i = W3bt + (size_t)i * 64 * 64;

        // dual: t1 = silu(h@Wpre1+b), hu = h@Wup
        gemm_dual<<<gDual, 256, 0, stream>>>(h, Wpre1_i, Wup_i, bpre1_i, t1, hu);
        gemm_kernel<128, 0, 0><<<gA, 256, 0, stream>>>(t1, Wpre2_i, bpre2_i, h, nullptr, hres, NA, C, 1.f);

        // edge branch: L1 (f32 GEMM -> bf16), L2/L3 (MFMA), W4 expand (MFMA)
        gemm_kernel<8, 1, 1><<<dim3(NE / 64, 1), 256, 0, stream>>>(efb, rW1_i, rb1_i, nullptr, nullptr, hbuf, NE, 64, 1.f);
        k_mlp_mfma<<<NE / 128, 128, 0, stream>>>(hbuf, W2bt_i, rb2_i, tA);
        k_mlp_mfma<<<NE / 128, 128, 0, stream>>>(tA, W3bt_i, rb3_i, hbuf);
        k_wbuf_mfma<<<gWB, 256, 0, stream>>>(hbuf, W4bt_i, wbuf);

        // Ewald branch
        k_kfilter<<<NK, 128, 0, stream>>>(kdwn, WupE_i, kfil);
        k_sf<<<gSF, 256, 0, stream>>>(hres, cosd, sind, gs, kfil, sfp);
        k_sfred<<<gRED, 256, 0, stream>>>(sfp, sfr, sfi);
        k_he<<<NA, 128, 0, stream>>>(cosd, sind, sfr, sfi, batch, t1);
        gemm_kernel<128, 1, 0><<<gA, 256, 0, stream>>>(t1, Wm1_i, bm1_i, nullptr, nullptr, t2, NA, C, 1.f);
        gemm_kernel<128, 1, 0><<<gA, 256, 0, stream>>>(t2, Wm2_i, bm2_i, nullptr, nullptr, he2, NA, C, 1.f);

        // gather + combine
        k_gather<<<NA, 128, 0, stream>>>(wbuf, hu, Ybuf, eidx, offs, perm, w2_i, w3_i, fe);
        gemm_kernel<128, 0, 0><<<gA, 256, 0, stream>>>(fe, Wmix_i, nullptr, h, he2, hn, NA, C, SKIPF);
        k_node_energy<<<NA, 128, 0, stream>>>(hn, Wr0, Wr1a, Wr1b, (i == 0) ? 0 : 1, nebuf + (size_t)i * NA);

        float* tmp = h; h = hn; hn = tmp;
    }

    k_reduceE<<<BG, 256, 0, stream>>>(e0buf, nebuf, gs, Eout);
}

// Round 8
// 467.631 us; speedup vs baseline: 1.6438x; 1.0576x over previous
//
#include <hip/hip_runtime.h>
#include <hip/hip_bf16.h>
#include <math.h>

// ---------------- problem constants ----------------
constexpr int NA  = 3200;     // atoms
constexpr int NE  = 51200;    // edges
constexpr int C   = 128;      // channels
constexpr int NK  = 123;      // k-points with |k| <= 0.6
constexpr int NKP = 128;      // padded stride for cosd/sind
constexpr int BG  = 8;        // graphs
constexpr int SFSPLIT = 8;    // k_sf split factor
constexpr float SKIPF = 0.57735026918962576f;  // 3^-0.5
constexpr float AVGN  = 16.0f;
constexpr size_t SFSZ = (size_t)BG * NK * C;   // one sf plane (125952)

__device__ __forceinline__ float dsilu(float x) { return x / (1.0f + expf(-x)); }

__device__ __forceinline__ unsigned short f2bf(float f) {
    unsigned int u = __float_as_uint(f);
    unsigned int r = (u + 0x7fffu + ((u >> 16) & 1u)) >> 16;
    return (unsigned short)r;
}
__device__ __forceinline__ float bf2f(unsigned short s) {
    return __uint_as_float(((unsigned int)s) << 16);
}

typedef __attribute__((ext_vector_type(8))) short short8;
typedef __attribute__((ext_vector_type(4))) float f32x4;

// ---------------- generic tiled f32 GEMM ----------------
template <int K, int ACT, int OBF16>
__global__ __launch_bounds__(256, 4) void gemm_kernel(
    const float* __restrict__ X, const float* __restrict__ W,
    const float* __restrict__ bias, const float* __restrict__ res1,
    const float* __restrict__ res2, void* __restrict__ outv,
    int M, int N, float scale)
{
    constexpr int K4 = K / 4;
    constexpr int BK  = (K < 64) ? K : 64;
    constexpr int BK4 = BK / 4;
    constexpr int BK4P = BK4 + 1;
    __shared__ float As[64 * BK4P * 4];
    __shared__ float Bs[BK * 64];
    const int tid = threadIdx.x;
    const int m0 = blockIdx.x * 64;
    const int n0 = blockIdx.y * 64;

    const float4* X4 = (const float4*)X;
    const float4* W4 = (const float4*)W;
    float4* As4 = (float4*)As;
    float4* Bs4 = (float4*)Bs;
    const int N4 = N >> 2;

    const int tx = tid & 15;
    const int ty = tid >> 4;
    float acc[4][4];
#pragma unroll
    for (int i = 0; i < 4; i++)
#pragma unroll
        for (int j = 0; j < 4; j++) acc[i][j] = 0.0f;

    for (int k0 = 0; k0 < K4; k0 += BK4) {
        if (k0) __syncthreads();
        for (int idx = tid; idx < 64 * BK4; idx += 256) {
            int r = idx / BK4, k4 = idx - r * BK4;
            As4[r * BK4P + k4] = X4[(size_t)(m0 + r) * K4 + k0 + k4];
        }
        for (int idx = tid; idx < BK * 16; idx += 256) {
            int kr = idx >> 4, c4 = idx & 15;
            Bs4[idx] = W4[(size_t)(k0 * 4 + kr) * N4 + (n0 >> 2) + c4];
        }
        __syncthreads();

#pragma unroll 4
        for (int k4 = 0; k4 < BK4; k4++) {
            float a[4][4];
#pragma unroll
            for (int i = 0; i < 4; i++) {
                float4 av = As4[(ty * 4 + i) * BK4P + k4];
                a[i][0] = av.x; a[i][1] = av.y; a[i][2] = av.z; a[i][3] = av.w;
            }
#pragma unroll
            for (int kk = 0; kk < 4; kk++) {
                float4 bv = Bs4[(k4 * 4 + kk) * 16 + tx];
#pragma unroll
                for (int i = 0; i < 4; i++) {
                    acc[i][0] += a[i][kk] * bv.x;
                    acc[i][1] += a[i][kk] * bv.y;
                    acc[i][2] += a[i][kk] * bv.z;
                    acc[i][3] += a[i][kk] * bv.w;
                }
            }
        }
    }

    float4 bv = make_float4(0.f, 0.f, 0.f, 0.f);
    if (bias) bv = ((const float4*)bias)[(n0 >> 2) + tx];
#pragma unroll
    for (int i = 0; i < 4; i++) {
        int row = m0 + ty * 4 + i;
        size_t o = (size_t)row * N + n0 + tx * 4;
        float4 v;
        v.x = acc[i][0] + bv.x; v.y = acc[i][1] + bv.y;
        v.z = acc[i][2] + bv.z; v.w = acc[i][3] + bv.w;
        if (ACT) { v.x = dsilu(v.x); v.y = dsilu(v.y); v.z = dsilu(v.z); v.w = dsilu(v.w); }
        if (res1) { float4 r = *(const float4*)(res1 + o); v.x += r.x; v.y += r.y; v.z += r.z; v.w += r.w; }
        if (res2) { float4 r = *(const float4*)(res2 + o); v.x += r.x; v.y += r.y; v.z += r.z; v.w += r.w; }
        v.x *= scale; v.y *= scale; v.z *= scale; v.w *= scale;
        if (OBF16) {
            ushort4 pk;
            pk.x = f2bf(v.x); pk.y = f2bf(v.y); pk.z = f2bf(v.z); pk.w = f2bf(v.w);
            *(ushort4*)((unsigned short*)outv + o) = pk;
        } else {
            *(float4*)((float*)outv + o) = v;
        }
    }
}

// ---------------- dual GEMM: t1 = silu(h@Wa + bias), hu = h@Wb ----------------
__global__ __launch_bounds__(256, 4) void gemm_dual(
    const float* __restrict__ X, const float* __restrict__ Wa,
    const float* __restrict__ Wb, const float* __restrict__ bias,
    float* __restrict__ outa, float* __restrict__ outb)
{
    constexpr int K4 = 32, BK4 = 16, BK4P = 17;
    __shared__ float As[64 * BK4P * 4];
    __shared__ float Bs[64 * 64];
    const int tid = threadIdx.x;
    const int m0 = blockIdx.x * 64;
    const int sel = blockIdx.y >> 1;
    const int n0 = (blockIdx.y & 1) * 64;
    const float* W = sel ? Wb : Wa;
    float* out = sel ? outb : outa;

    const float4* X4 = (const float4*)X;
    const float4* W4 = (const float4*)W;
    float4* As4 = (float4*)As;
    float4* Bs4 = (float4*)Bs;

    const int tx = tid & 15;
    const int ty = tid >> 4;
    float acc[4][4];
#pragma unroll
    for (int i = 0; i < 4; i++)
#pragma unroll
        for (int j = 0; j < 4; j++) acc[i][j] = 0.0f;

    for (int k0 = 0; k0 < K4; k0 += BK4) {
        if (k0) __syncthreads();
        for (int idx = tid; idx < 64 * BK4; idx += 256) {
            int r = idx / BK4, k4 = idx - r * BK4;
            As4[r * BK4P + k4] = X4[(size_t)(m0 + r) * K4 + k0 + k4];
        }
        for (int idx = tid; idx < 64 * 16; idx += 256) {
            int kr = idx >> 4, c4 = idx & 15;
            Bs4[idx] = W4[(size_t)(k0 * 4 + kr) * 32 + (n0 >> 2) + c4];
        }
        __syncthreads();

#pragma unroll 4
        for (int k4 = 0; k4 < BK4; k4++) {
            float a[4][4];
#pragma unroll
            for (int i = 0; i < 4; i++) {
                float4 av = As4[(ty * 4 + i) * BK4P + k4];
                a[i][0] = av.x; a[i][1] = av.y; a[i][2] = av.z; a[i][3] = av.w;
            }
#pragma unroll
            for (int kk = 0; kk < 4; kk++) {
                float4 bv = Bs4[(k4 * 4 + kk) * 16 + tx];
#pragma unroll
                for (int i = 0; i < 4; i++) {
                    acc[i][0] += a[i][kk] * bv.x;
                    acc[i][1] += a[i][kk] * bv.y;
                    acc[i][2] += a[i][kk] * bv.z;
                    acc[i][3] += a[i][kk] * bv.w;
                }
            }
        }
    }

    float4 bv = make_float4(0.f, 0.f, 0.f, 0.f);
    if (!sel) bv = ((const float4*)bias)[(n0 >> 2) + tx];
#pragma unroll
    for (int i = 0; i < 4; i++) {
        int row = m0 + ty * 4 + i;
        size_t o = (size_t)row * 128 + n0 + tx * 4;
        float4 v;
        v.x = acc[i][0] + bv.x; v.y = acc[i][1] + bv.y;
        v.z = acc[i][2] + bv.z; v.w = acc[i][3] + bv.w;
        if (!sel) { v.x = dsilu(v.x); v.y = dsilu(v.y); v.z = dsilu(v.z); v.w = dsilu(v.w); }
        *(float4*)(out + o) = v;
    }
}

// ---------------- MFMA MLP layer, 2-layer batched: rows [0,NE) use weights
// of layer 0, rows [NE,2NE) layer 1. out = silu(X @ Wt^T + bias), all bf16.
__global__ __launch_bounds__(128, 2) void k_mlp_mfma(
    const unsigned short* __restrict__ X, const unsigned short* __restrict__ Wbase,
    const float* __restrict__ bbase, unsigned short* __restrict__ out)
{
    constexpr int MT = 128, AS = 72;
    __shared__ unsigned short Als[MT * AS];
    __shared__ unsigned short Bls[64 * AS];
    const int tid = threadIdx.x;
    const int m0 = blockIdx.x * MT;
    const int layer = (m0 >= NE) ? 1 : 0;
    const unsigned short* Wt = Wbase + (size_t)layer * 64 * 64;
    const float* bias = bbase + (size_t)layer * 64;

    for (int idx = tid; idx < MT * 8; idx += 128) {
        int r = idx >> 3, s = idx & 7;
        *(short8*)(Als + r * AS + s * 8) = ((const short8*)X)[(size_t)(m0 + r) * 8 + s];
    }
    for (int idx = tid; idx < 64 * 8; idx += 128) {
        int r = idx >> 3, s = idx & 7;
        *(short8*)(Bls + r * AS + s * 8) = ((const short8*)Wt)[(size_t)r * 8 + s];
    }
    __syncthreads();

    const int wave = tid >> 6;
    const int lane = tid & 63;
    const int q = lane >> 4;
    const int l16 = lane & 15;
    const int mw = wave * 64;

    f32x4 acc[4][4];
#pragma unroll
    for (int mi = 0; mi < 4; mi++)
#pragma unroll
        for (int ni = 0; ni < 4; ni++) acc[mi][ni] = (f32x4){0.f, 0.f, 0.f, 0.f};

#pragma unroll
    for (int kc = 0; kc < 2; kc++) {
        short8 a[4], b[4];
#pragma unroll
        for (int mi = 0; mi < 4; mi++)
            a[mi] = *(const short8*)(Als + (mw + mi * 16 + l16) * AS + kc * 32 + q * 8);
#pragma unroll
        for (int ni = 0; ni < 4; ni++)
            b[ni] = *(const short8*)(Bls + (ni * 16 + l16) * AS + kc * 32 + q * 8);
#pragma unroll
        for (int mi = 0; mi < 4; mi++)
#pragma unroll
            for (int ni = 0; ni < 4; ni++)
                acc[mi][ni] = __builtin_amdgcn_mfma_f32_16x16x32_bf16(a[mi], b[ni], acc[mi][ni], 0, 0, 0);
    }

#pragma unroll
    for (int ni = 0; ni < 4; ni++) {
        float bv = bias[ni * 16 + l16];
#pragma unroll
        for (int mi = 0; mi < 4; mi++) {
#pragma unroll
            for (int r = 0; r < 4; r++) {
                int e = m0 + mw + mi * 16 + q * 4 + r;
                int n = ni * 16 + l16;
                out[(size_t)e * 64 + n] = f2bf(dsilu(acc[mi][ni][r] + bv));
            }
        }
    }
}

// ---------------- weight converts ----------------
__global__ __launch_bounds__(64) void k_convW4(
    const float* __restrict__ rW4, unsigned short* __restrict__ W4bt)
{
    int b = blockIdx.x;
    int layer = b >> 9, n = b & 511;
    int k = threadIdx.x;
    W4bt[((size_t)layer * 512 + n) * 64 + k] = f2bf(rW4[((size_t)layer * 64 + k) * 512 + n]);
}

__global__ __launch_bounds__(64) void k_convW64(
    const float* __restrict__ rW, unsigned short* __restrict__ Wbt)
{
    int b = blockIdx.x;
    int layer = b >> 6, n = b & 63;
    int k = threadIdx.x;
    Wbt[((size_t)layer * 64 + n) * 64 + k] = f2bf(rW[((size_t)layer * 64 + k) * 64 + n]);
}

// ---------------- MFMA GEMM, 2-layer batched: wbuf[e][n] = X[e] @ W4t_l[n] ----------------
__global__ __launch_bounds__(256, 2) void k_wbuf_mfma(
    const unsigned short* __restrict__ X, const unsigned short* __restrict__ W4base,
    unsigned short* __restrict__ wbuf)
{
    constexpr int MT = 256, NT = 64, AS = 72;
    __shared__ unsigned short Als[MT * AS];
    __shared__ unsigned short Bls[NT * AS];
    const int tid = threadIdx.x;
    const int m0 = blockIdx.x * MT;
    const int n0 = blockIdx.y * NT;
    const int layer = (m0 >= NE) ? 1 : 0;
    const unsigned short* W4t = W4base + (size_t)layer * 512 * 64;

    for (int idx = tid; idx < MT * 8; idx += 256) {
        int r = idx >> 3, s = idx & 7;
        *(short8*)(Als + r * AS + s * 8) = ((const short8*)X)[(size_t)(m0 + r) * 8 + s];
    }
    for (int idx = tid; idx < NT * 8; idx += 256) {
        int r = idx >> 3, s = idx & 7;
        *(short8*)(Bls + r * AS + s * 8) = ((const short8*)W4t)[(size_t)(n0 + r) * 8 + s];
    }
    __syncthreads();

    const int wave = tid >> 6;
    const int lane = tid & 63;
    const int q = lane >> 4;
    const int l16 = lane & 15;
    const int mw = wave * 64;

    f32x4 acc[4][4];
#pragma unroll
    for (int mi = 0; mi < 4; mi++)
#pragma unroll
        for (int ni = 0; ni < 4; ni++) acc[mi][ni] = (f32x4){0.f, 0.f, 0.f, 0.f};

#pragma unroll
    for (int kc = 0; kc < 2; kc++) {
        short8 a[4], b[4];
#pragma unroll
        for (int mi = 0; mi < 4; mi++)
            a[mi] = *(const short8*)(Als + (mw + mi * 16 + l16) * AS + kc * 32 + q * 8);
#pragma unroll
        for (int ni = 0; ni < 4; ni++)
            b[ni] = *(const short8*)(Bls + (ni * 16 + l16) * AS + kc * 32 + q * 8);
#pragma unroll
        for (int mi = 0; mi < 4; mi++)
#pragma unroll
            for (int ni = 0; ni < 4; ni++)
                acc[mi][ni] = __builtin_amdgcn_mfma_f32_16x16x32_bf16(a[mi], b[ni], acc[mi][ni], 0, 0, 0);
    }

#pragma unroll
    for (int mi = 0; mi < 4; mi++) {
#pragma unroll
        for (int ni = 0; ni < 4; ni++) {
#pragma unroll
            for (int r = 0; r < 4; r++) {
                int e = m0 + mw + mi * 16 + q * 4 + r;
                int n = n0 + ni * 16 + l16;
                wbuf[(size_t)e * 512 + n] = f2bf(acc[mi][ni][r]);
            }
        }
    }
}

// ---------------- setup kernels ----------------
__global__ __launch_bounds__(128) void k_node_init(
    const float* __restrict__ na, const float* __restrict__ Wemb,
    const float* __restrict__ aE, float* __restrict__ h, float* __restrict__ e0buf)
{
    int n = blockIdx.x, c = threadIdx.x;
    float s = 0.f;
#pragma unroll
    for (int k = 0; k < 10; k++) s += na[n * 10 + k] * Wemb[k * C + c];
    h[(size_t)n * C + c] = s;
    if (c == 0) {
        float e = 0.f;
#pragma unroll
        for (int k = 0; k < 10; k++) e += na[n * 10 + k] * aE[k];
        e0buf[n] = e;
    }
}

__global__ __launch_bounds__(256) void k_ranges(const int* __restrict__ batch, int* __restrict__ gs)
{
    __shared__ int cnt[BG];
    if (threadIdx.x < BG) cnt[threadIdx.x] = 0;
    __syncthreads();
    for (int n = threadIdx.x; n < NA; n += 256) atomicAdd(&cnt[batch[n]], 1);
    __syncthreads();
    if (threadIdx.x == 0) {
        int s = 0;
        for (int b = 0; b < BG; b++) { gs[b] = s; s += cnt[b]; }
        gs[BG] = s;
    }
}

__device__ __forceinline__ float sincn(float x) {
    float px = 3.14159265358979323846f * x;
    return (fabsf(px) < 1e-8f) ? 1.0f : (sinf(px) / px);
}

__global__ __launch_bounds__(128) void k_kspace(
    const float* __restrict__ pos, const float* __restrict__ kgrid,
    float* __restrict__ cosd, float* __restrict__ sind)
{
    int n = blockIdx.x, k = threadIdx.x;
    float p0 = pos[n * 3 + 0], p1 = pos[n * 3 + 1], p2 = pos[n * 3 + 2];
    float sd = sincn(0.1f * p0) * sincn(0.1f * p1) * sincn(0.1f * p2);
    if (k < NK) {
        float d = p0 * kgrid[k * 3 + 0] + p1 * kgrid[k * 3 + 1] + p2 * kgrid[k * 3 + 2];
        float sn, cs;
        sincosf(d, &sn, &cs);
        cosd[(size_t)n * NKP + k] = sd * cs;
        sind[(size_t)n * NKP + k] = sd * sn;
    } else {
        cosd[(size_t)n * NKP + k] = 0.f;
        sind[(size_t)n * NKP + k] = 0.f;
    }
}

__global__ __launch_bounds__(1024) void k_kdown(
    const float* __restrict__ krbf, const float* __restrict__ Wdown, float* __restrict__ kdown)
{
    int t = threadIdx.x;
    if (t < NK * 8) {
        int k = t >> 3, j = t & 7;
        float s = 0.f;
        for (int r = 0; r < 128; r++) s += krbf[k * 128 + r] * Wdown[r * 8 + j];
        kdown[t] = s;
    }
}

__global__ __launch_bounds__(256) void k_edge_geom(
    const float* __restrict__ pos, const float* __restrict__ shifts,
    const int* __restrict__ eidx, float* __restrict__ Y, float* __restrict__ ef)
{
    int e = blockIdx.x * 256 + threadIdx.x;
    if (e >= NE) return;
    int s = eidx[e], d = eidx[NE + e];
    float vx = pos[d * 3 + 0] - pos[s * 3 + 0] + shifts[e * 3 + 0];
    float vy = pos[d * 3 + 1] - pos[s * 3 + 1] + shifts[e * 3 + 1];
    float vz = pos[d * 3 + 2] - pos[s * 3 + 2] + shifts[e * 3 + 2];
    float r = sqrtf(vx * vx + vy * vy + vz * vz);
    float rinv = 1.0f / fmaxf(r, 1e-9f);
    float x = vx * rinv, y = vy * rinv, z = vz * rinv;

    const float s3 = 1.7320508075688772f, s5 = 2.2360679774997896f, s15 = 3.8729833462074170f;
    const float c70 = 2.0916500663351889f;
    const float c105 = 10.246950765959598f;
    const float c42 = 1.6201851746019651f;
    const float c7 = 1.3228756555322954f;
    float o[16];
    o[0] = 1.0f;
    o[1] = s3 * x; o[2] = s3 * y; o[3] = s3 * z;
    o[4] = s15 * x * y; o[5] = s15 * y * z; o[6] = 0.5f * s5 * (3.f * z * z - 1.f);
    o[7] = s15 * x * z; o[8] = 0.5f * s15 * (x * x - y * y);
    o[9]  = c70 * y * (3.f * x * x - y * y);
    o[10] = c105 * x * y * z;
    o[11] = c42 * y * (5.f * z * z - 1.f);
    o[12] = c7 * z * (5.f * z * z - 3.f);
    o[13] = c42 * x * (5.f * z * z - 1.f);
    o[14] = 0.5f * c105 * z * (x * x - y * y);
    o[15] = c70 * x * (x * x - 3.f * y * y);
    float4* Y4 = (float4*)(Y + (size_t)e * 16);
    Y4[0] = make_float4(o[0], o[1], o[2], o[3]);
    Y4[1] = make_float4(o[4], o[5], o[6], o[7]);
    Y4[2] = make_float4(o[8], o[9], o[10], o[11]);
    Y4[3] = make_float4(o[12], o[13], o[14], o[15]);

    float uu = fminf(fmaxf(r * 0.2f, 0.f), 1.f);
    float u2 = uu * uu, u4 = u2 * u2, u5 = u4 * uu, u6 = u5 * uu, u7 = u6 * uu;
    float env = 1.f - 21.f * u5 + 35.f * u6 - 15.f * u7;
    env = (r < 5.0f) ? env : 0.0f;
    float pref = 0.63245553203367587f * rinv * env;
    const float pio5 = 0.62831853071795865f;
    float efv[8];
#pragma unroll
    for (int n1 = 1; n1 <= 8; n1++) efv[n1 - 1] = pref * sinf(n1 * pio5 * r);
    float4* E4 = (float4*)(ef + (size_t)e * 8);
    E4[0] = make_float4(efv[0], efv[1], efv[2], efv[3]);
    E4[1] = make_float4(efv[4], efv[5], efv[6], efv[7]);
}

// ---------------- CSR by dst ----------------
__global__ __launch_bounds__(256) void k_count(const int* __restrict__ eidx, int* __restrict__ deg)
{
    int e = blockIdx.x * 256 + threadIdx.x;
    if (e < NE) atomicAdd(&deg[eidx[NE + e]], 1);
}

__global__ __launch_bounds__(1024) void k_scan(
    const int* __restrict__ deg, int* __restrict__ offs, int* __restrict__ cursor)
{
    __shared__ int sc[1024];
    int tid = threadIdx.x;
    int base = tid * 4;
    int v[4]; int s = 0;
#pragma unroll
    for (int i = 0; i < 4; i++) {
        int idx = base + i;
        int d = (idx < NA) ? deg[idx] : 0;
        v[i] = s; s += d;
    }
    sc[tid] = s;
    __syncthreads();
    for (int ofs = 1; ofs < 1024; ofs <<= 1) {
        int t = (tid >= ofs) ? sc[tid - ofs] : 0;
        __syncthreads();
        sc[tid] += t;
        __syncthreads();
    }
    int excl = (tid > 0) ? sc[tid - 1] : 0;
#pragma unroll
    for (int i = 0; i < 4; i++) {
        int idx = base + i;
        if (idx < NA) { int o = excl + v[i]; offs[idx] = o; cursor[idx] = o; }
    }
    if (tid == 1023) offs[NA] = sc[1023];
}

__global__ __launch_bounds__(256) void k_fill(
    const int* __restrict__ eidx, int* __restrict__ cursor, int* __restrict__ perm)
{
    int e = blockIdx.x * 256 + threadIdx.x;
    if (e < NE) {
        int d = eidx[NE + e];
        int p = atomicAdd(&cursor[d], 1);
        perm[p] = e;
    }
}

// ---------------- Ewald: structure-factor partials (kfilter fused inline) ----------------
// sfp layout: [r: sp=0..7][i: sp=0..7], each plane SFSZ floats.
__global__ __launch_bounds__(256, 4) void k_sf(
    const float* __restrict__ hres, const float* __restrict__ cosd, const float* __restrict__ sind,
    const int* __restrict__ gs, const float* __restrict__ kdwn, const float* __restrict__ WupE,
    float* __restrict__ sfp)
{
    const int b = blockIdx.x, kt = blockIdx.y, sp = blockIdx.z;
    const int n0 = gs[b], n1 = gs[b + 1];
    const int cnt = n1 - n0;
    const int per = (cnt + SFSPLIT - 1) / SFSPLIT;
    const int cs = n0 + sp * per;
    const int ce = min(cs + per, n1);

    __shared__ float Hs[32 * 128];
    __shared__ float Cs[32 * 32];
    __shared__ float Ss[32 * 32];

    const int tid = threadIdx.x;
    const int tx = tid & 31;
    const int ty = tid >> 5;

    float accR[4][4], accI[4][4];
#pragma unroll
    for (int i = 0; i < 4; i++)
#pragma unroll
        for (int j = 0; j < 4; j++) { accR[i][j] = 0.f; accI[i][j] = 0.f; }

    float4* H4 = (float4*)Hs;
    float4* C4 = (float4*)Cs;
    float4* S4 = (float4*)Ss;

    for (int nb = cs; nb < ce; nb += 32) {
        __syncthreads();
        for (int idx = tid; idx < 32 * 32; idx += 256) {
            int r = idx >> 5, c4 = idx & 31;
            int n = nb + r;
            H4[idx] = (n < ce) ? ((const float4*)hres)[(size_t)n * 32 + c4]
                               : make_float4(0.f, 0.f, 0.f, 0.f);
        }
        for (int idx = tid; idx < 32 * 8; idx += 256) {
            int r = idx >> 3, k4 = idx & 7;
            int n = nb + r;
            float4 cv = make_float4(0.f, 0.f, 0.f, 0.f), sv = cv;
            if (n < ce) {
                cv = ((const float4*)cosd)[(size_t)n * 32 + kt * 8 + k4];
                sv = ((const float4*)sind)[(size_t)n * 32 + kt * 8 + k4];
            }
            C4[idx] = cv;
            S4[idx] = sv;
        }
        __syncthreads();
        const int lim = min(32, ce - nb);
        for (int n = 0; n < lim; n++) {
            float4 hv = H4[n * 32 + tx];
            float4 cv = C4[n * 8 + ty];
            float4 sv = S4[n * 8 + ty];
            float h[4] = { hv.x, hv.y, hv.z, hv.w };
            float ck[4] = { cv.x, cv.y, cv.z, cv.w };
            float sk[4] = { sv.x, sv.y, sv.z, sv.w };
#pragma unroll
            for (int i = 0; i < 4; i++)
#pragma unroll
                for (int j = 0; j < 4; j++) {
                    accR[i][j] += ck[i] * h[j];
                    accI[i][j] += sk[i] * h[j];
                }
        }
    }

    const int kbase = kt * 32 + ty * 4;
    float* baseR = sfp + (size_t)sp * SFSZ;
    float* baseI = sfp + (size_t)(SFSPLIT + sp) * SFSZ;
#pragma unroll
    for (int i = 0; i < 4; i++) {
        int k = kbase + i;
        if (k < NK) {
            // kf[k, c=tx*4..tx*4+3] = sum_j kdown[k,j] * WupE[j,c]  (fused kfilter)
            float4 kfv = make_float4(0.f, 0.f, 0.f, 0.f);
#pragma unroll
            for (int j = 0; j < 8; j++) {
                float kd = kdwn[k * 8 + j];
                float4 wv = ((const float4*)WupE)[(size_t)j * 32 + tx];
                kfv.x += kd * wv.x; kfv.y += kd * wv.y;
                kfv.z += kd * wv.z; kfv.w += kd * wv.w;
            }
            float vx = kfv.x * 0.01f, vy = kfv.y * 0.01f, vz = kfv.z * 0.01f, vw = kfv.w * 0.01f;
            size_t o = ((size_t)(b * NK + k)) * C + tx * 4;
            *(float4*)(baseR + o) = make_float4(accR[i][0] * vx, accR[i][1] * vy,
                                                accR[i][2] * vz, accR[i][3] * vw);
            *(float4*)(baseI + o) = make_float4(accI[i][0] * vx, accI[i][1] * vy,
                                                accI[i][2] * vz, accI[i][3] * vw);
        }
    }
}

// reduce split partials -> sfr, sfi
__global__ __launch_bounds__(256) void k_sfred(
    const float* __restrict__ sfp, float* __restrict__ sfr, float* __restrict__ sfi)
{
    const size_t S4 = SFSZ / 4;
    size_t o4 = (size_t)blockIdx.x * 256 + threadIdx.x;
    if (o4 >= S4) return;
    const float4* p = (const float4*)sfp;
    float4 ar = make_float4(0.f, 0.f, 0.f, 0.f), ai = ar;
#pragma unroll
    for (int sp = 0; sp < SFSPLIT; sp++) {
        float4 r = p[(size_t)sp * S4 + o4];
        ar.x += r.x; ar.y += r.y; ar.z += r.z; ar.w += r.w;
        float4 q = p[(size_t)(SFSPLIT + sp) * S4 + o4];
        ai.x += q.x; ai.y += q.y; ai.z += q.z; ai.w += q.w;
    }
    ((float4*)sfr)[o4] = ar;
    ((float4*)sfi)[o4] = ai;
}

__global__ __launch_bounds__(128) void k_he(
    const float* __restrict__ cosd, const float* __restrict__ sind,
    const float* __restrict__ sfr, const float* __restrict__ sfi,
    const int* __restrict__ batch, float* __restrict__ out)
{
    int n = blockIdx.x, c = threadIdx.x;
    int b = batch[n];
    const float* pr = sfr + (size_t)b * NK * C;
    const float* pi = sfi + (size_t)b * NK * C;
    const float* cdp = cosd + (size_t)n * NKP;
    const float* sdp = sind + (size_t)n * NKP;
    float acc = 0.f;
    for (int k = 0; k < NK; k++) {
        acc += cdp[k] * pr[(size_t)k * C + c] + sdp[k] * pi[(size_t)k * C + c];
    }
    out[(size_t)n * C + c] = acc;
}

// ---------------- message gather + symmetric contraction ----------------
__global__ __launch_bounds__(128) void k_gather(
    const unsigned short* __restrict__ wbuf, const float* __restrict__ hu,
    const float* __restrict__ Y, const int* __restrict__ srcArr,
    const int* __restrict__ offs, const int* __restrict__ perm,
    const float* __restrict__ w2, const float* __restrict__ w3,
    float* __restrict__ feats)
{
    int n = blockIdx.x, c = threadIdx.x;
    int j0 = offs[n], j1 = offs[n + 1];
    float A[16];
#pragma unroll
    for (int s = 0; s < 16; s++) A[s] = 0.f;
    for (int j = j0; j < j1; j++) {
        int e = perm[j];
        int s = srcArr[e];
        float huc = hu[(size_t)s * C + c];
        ushort4 wv = *(const ushort4*)(wbuf + (size_t)e * 512 + c * 4);
        const float4* Yp = (const float4*)(Y + (size_t)e * 16);
        float4 y0 = Yp[0], y1 = Yp[1], y2 = Yp[2], y3 = Yp[3];
        float m0 = bf2f(wv.x) * huc, m1 = bf2f(wv.y) * huc;
        float m2 = bf2f(wv.z) * huc, m3 = bf2f(wv.w) * huc;
        A[0] += m0 * y0.x;
        A[1] += m1 * y0.y;  A[2]  += m1 * y0.z;  A[3]  += m1 * y0.w;
        A[4] += m2 * y1.x;  A[5]  += m2 * y1.y;  A[6]  += m2 * y1.z;  A[7] += m2 * y1.w;
        A[8] += m2 * y2.x;
        A[9] += m3 * y2.y;  A[10] += m3 * y2.z;  A[11] += m3 * y2.w;
        A[12] += m3 * y3.x; A[13] += m3 * y3.y;  A[14] += m3 * y3.z;  A[15] += m3 * y3.w;
    }
    const float inv = 1.0f / AVGN;
#pragma unroll
    for (int s = 0; s < 16; s++) A[s] *= inv;
    float scal = A[0];
    float i0 = A[0] * A[0];
    float i1 = A[1] * A[1] + A[2] * A[2] + A[3] * A[3];
    float i2 = A[4] * A[4] + A[5] * A[5] + A[6] * A[6] + A[7] * A[7] + A[8] * A[8];
    float i3 = A[9] * A[9] + A[10] * A[10] + A[11] * A[11] + A[12] * A[12] +
               A[13] * A[13] + A[14] * A[14] + A[15] * A[15];
    float t2 = i0 * w2[c] + i1 * w2[C + c] + i2 * w2[2 * C + c] + i3 * w2[3 * C + c];
    float t3 = i0 * w3[c] + i1 * w3[C + c] + i2 * w3[2 * C + c] + i3 * w3[3 * C + c];
    feats[(size_t)n * C + c] = scal + t2 + scal * t3;
}

// ---------------- readout energy (per-node, no atomics) ----------------
__global__ __launch_bounds__(128) void k_node_energy(
    const float* __restrict__ h, const float* __restrict__ Wr0,
    const float* __restrict__ Wr1a, const float* __restrict__ Wr1b,
    int mode, float* __restrict__ nebuf)
{
    int n = blockIdx.x, t = threadIdx.x;
    __shared__ float hs[128];
    __shared__ float red[16];
    float hv = h[(size_t)n * C + t];
    if (mode == 0) {
        float v = hv * Wr0[t];
#pragma unroll
        for (int o = 32; o; o >>= 1) v += __shfl_down(v, o, 64);
        if ((t & 63) == 0) red[t >> 6] = v;
        __syncthreads();
        if (t == 0) nebuf[n] = red[0] + red[1];
    } else {
        hs[t] = hv;
        __syncthreads();
        if (t < 16) {
            float s = 0.f;
#pragma unroll 8
            for (int cc = 0; cc < 128; cc++) s += hs[cc] * Wr1a[cc * 16 + t];
            red[t] = dsilu(s) * Wr1b[t];
        }
        __syncthreads();
        if (t == 0) {
            float s = 0.f;
#pragma unroll
            for (int j = 0; j < 16; j++) s += red[j];
            nebuf[n] = s;
        }
    }
}

// ---------------- final per-graph energy reduction ----------------
__global__ __launch_bounds__(256) void k_reduceE(
    const float* __restrict__ e0buf, const float* __restrict__ nebuf,
    const int* __restrict__ gs, float* __restrict__ Eout)
{
    int b = blockIdx.x, t = threadIdx.x;
    int n0 = gs[b], n1 = gs[b + 1];
    float s = 0.f;
    for (int n = n0 + t; n < n1; n += 256)
        s += e0buf[n] + nebuf[n] + nebuf[NA + n];
#pragma unroll
    for (int o = 32; o; o >>= 1) s += __shfl_down(s, o, 64);
    __shared__ float red[4];
    if ((t & 63) == 0) red[t >> 6] = s;
    __syncthreads();
    if (t == 0) Eout[b] = red[0] + red[1] + red[2] + red[3];
}

// ---------------- workspace layout (floats) ----------------
constexpr size_t NAC   = (size_t)NA * C;
constexpr size_t F_COSD = 0;
constexpr size_t F_SIND = F_COSD + (size_t)NA * NKP;
constexpr size_t F_Y    = F_SIND + (size_t)NA * NKP;
constexpr size_t F_EF   = F_Y + (size_t)NE * 16;
constexpr size_t F_H    = F_EF + (size_t)NE * 8;
constexpr size_t F_HN   = F_H + NAC;
constexpr size_t F_HRES = F_HN + NAC;
constexpr size_t F_T1   = F_HRES + NAC;
constexpr size_t F_T2   = F_T1 + NAC;
constexpr size_t F_HE2  = F_T2 + NAC;
constexpr size_t F_HU   = F_HE2 + NAC;
constexpr size_t F_FE   = F_HU + NAC;
constexpr size_t F_TA   = F_FE + NAC;                // bf16 tA: 2*NE*64 shorts
constexpr size_t F_TB   = F_TA + (size_t)NE * 64;    // bf16 hbuf: 2*NE*64 shorts
constexpr size_t F_WTS  = F_TB + (size_t)NE * 64;    // bf16 W4bt(2*512*64) + W2bt + W3bt
constexpr size_t F_W    = F_WTS + 48 * 1024;         // bf16 wbuf: 2*NE*512 shorts
constexpr size_t F_SFR  = F_W + (size_t)NE * 512;
constexpr size_t F_SFI  = F_SFR + SFSZ;
constexpr size_t F_SFP  = F_SFI + SFSZ;              // 16 planes of SFSZ
constexpr size_t F_KD   = F_SFP + 2 * (size_t)SFSPLIT * SFSZ;
constexpr size_t F_E0   = F_KD + 1024;               // e0buf: NA
constexpr size_t F_NE   = F_E0 + NA;                 // nebuf: 2*NA
constexpr size_t F_END  = F_NE + 2 * (size_t)NA;
constexpr size_t I_BASE = ((F_END * 4 + 255) / 256) * 256;

extern "C" void kernel_launch(void* const* d_in, const int* in_sizes, int n_in,
                              void* d_out, int out_size, void* d_ws, size_t ws_size,
                              hipStream_t stream) {
    const float* pos    = (const float*)d_in[0];
    const float* na     = (const float*)d_in[1];
    const float* shifts = (const float*)d_in[2];
    const int*   eidx   = (const int*)d_in[3];
    const int*   batch  = (const int*)d_in[4];
    const float* kgrid  = (const float*)d_in[5];
    const float* krbf   = (const float*)d_in[6];
    const float* Wemb   = (const float*)d_in[7];
    const float* aE     = (const float*)d_in[8];
    const float* rW1    = (const float*)d_in[9];
    const float* rb1    = (const float*)d_in[10];
    const float* rW2    = (const float*)d_in[11];
    const float* rb2    = (const float*)d_in[12];
    const float* rW3    = (const float*)d_in[13];
    const float* rb3    = (const float*)d_in[14];
    const float* rW4    = (const float*)d_in[15];
    const float* Wup    = (const float*)d_in[16];
    const float* w2     = (const float*)d_in[17];
    const float* w3     = (const float*)d_in[18];
    const float* Wmix   = (const float*)d_in[19];
    const float* Wr0    = (const float*)d_in[20];
    const float* Wr1a   = (const float*)d_in[21];
    const float* Wr1b   = (const float*)d_in[22];
    const float* Wdown  = (const float*)d_in[23];
    const float* WupE   = (const float*)d_in[24];
    const float* Wpre1  = (const float*)d_in[25];
    const float* bpre1  = (const float*)d_in[26];
    const float* Wpre2  = (const float*)d_in[27];
    const float* bpre2  = (const float*)d_in[28];
    const float* Wm1    = (const float*)d_in[29];
    const float* bm1    = (const float*)d_in[30];
    const float* Wm2    = (const float*)d_in[31];
    const float* bm2    = (const float*)d_in[32];

    float* fw = (float*)d_ws;
    float* cosd = fw + F_COSD;
    float* sind = fw + F_SIND;
    float* Ybuf = fw + F_Y;
    float* efb  = fw + F_EF;
    float* h    = fw + F_H;
    float* hn   = fw + F_HN;
    float* hres = fw + F_HRES;
    float* t1   = fw + F_T1;
    float* t2   = fw + F_T2;
    float* he2  = fw + F_HE2;
    float* hu   = fw + F_HU;
    float* fe   = fw + F_FE;
    unsigned short* tA   = (unsigned short*)(fw + F_TA);   // 2*NE*64
    unsigned short* hbuf = (unsigned short*)(fw + F_TB);   // 2*NE*64
    unsigned short* W4bt = (unsigned short*)(fw + F_WTS);
    unsigned short* W2bt = W4bt + (size_t)2 * 512 * 64;
    unsigned short* W3bt = W2bt + (size_t)2 * 64 * 64;
    unsigned short* wbuf = (unsigned short*)(fw + F_W);    // 2*NE*512
    float* sfr  = fw + F_SFR;
    float* sfi  = fw + F_SFI;
    float* sfp  = fw + F_SFP;
    float* kdwn = fw + F_KD;
    float* e0buf = fw + F_E0;
    float* nebuf = fw + F_NE;

    int* ip     = (int*)((char*)d_ws + I_BASE);
    int* deg    = ip;
    int* offs   = ip + NA;
    int* cursor = ip + 2 * NA + 1;
    int* perm   = ip + 3 * NA + 1;
    int* gs     = perm + NE;

    float* Eout = (float*)d_out;

    hipMemsetAsync(deg, 0, NA * sizeof(int), stream);

    k_node_init<<<NA, 128, 0, stream>>>(na, Wemb, aE, h, e0buf);
    k_ranges<<<1, 256, 0, stream>>>(batch, gs);
    k_kspace<<<NA, 128, 0, stream>>>(pos, kgrid, cosd, sind);
    k_kdown<<<1, 1024, 0, stream>>>(krbf, Wdown, kdwn);
    k_edge_geom<<<NE / 256, 256, 0, stream>>>(pos, shifts, eidx, Ybuf, efb);
    k_count<<<NE / 256, 256, 0, stream>>>(eidx, deg);
    k_scan<<<1, 1024, 0, stream>>>(deg, offs, cursor);
    k_fill<<<NE / 256, 256, 0, stream>>>(eidx, cursor, perm);
    k_convW4<<<1024, 64, 0, stream>>>(rW4, W4bt);
    k_convW64<<<128, 64, 0, stream>>>(rW2, W2bt);
    k_convW64<<<128, 64, 0, stream>>>(rW3, W3bt);

    // ---- edge branch, both layers batched (independent of h) ----
    for (int i = 0; i < 2; i++) {
        gemm_kernel<8, 1, 1><<<dim3(NE / 64, 1), 256, 0, stream>>>(
            efb, rW1 + (size_t)i * 8 * 64, rb1 + (size_t)i * 64,
            nullptr, nullptr, hbuf + (size_t)i * NE * 64, NE, 64, 1.f);
    }
    k_mlp_mfma<<<2 * NE / 128, 128, 0, stream>>>(hbuf, W2bt, rb2, tA);
    k_mlp_mfma<<<2 * NE / 128, 128, 0, stream>>>(tA, W3bt, rb3, hbuf);
    k_wbuf_mfma<<<dim3(2 * NE / 256, 512 / 64), 256, 0, stream>>>(hbuf, W4bt, wbuf);

    const dim3 gA(NA / 64, C / 64);
    const dim3 gDual(NA / 64, 4);
    const dim3 gSF(BG, 4, SFSPLIT);
    const int gRED = (int)((SFSZ / 4 + 255) / 256);

    for (int i = 0; i < 2; i++) {
        const float* Wpre1_i = Wpre1 + (size_t)i * C * C;
        const float* bpre1_i = bpre1 + (size_t)i * C;
        const float* Wpre2_i = Wpre2 + (size_t)i * C * C;
        const float* bpre2_i = bpre2 + (size_t)i * C;
        const float* WupE_i  = WupE + (size_t)i * 8 * C;
        const float* Wm1_i   = Wm1 + (size_t)i * C * C;
        const float* bm1_i   = bm1 + (size_t)i * C;
        const float* Wm2_i   = Wm2 + (size_t)i * C * C;
        const float* bm2_i   = bm2 + (size_t)i * C;
        const float* Wup_i   = Wup + (size_t)i * C * C;
        const float* w2_i    = w2 + (size_t)i * 4 * C;
        const float* w3_i    = w3 + (size_t)i * 4 * C;
        const float* Wmix_i  = Wmix + (size_t)i * C * C;
        const unsigned short* wbuf_i = wbuf + (size_t)i * NE * 512;

        // dual: t1 = silu(h@Wpre1+b), hu = h@Wup
        gemm_dual<<<gDual, 256, 0, stream>>>(h, Wpre1_i, Wup_i, bpre1_i, t1, hu);
        gemm_kernel<128, 0, 0><<<gA, 256, 0, stream>>>(t1, Wpre2_i, bpre2_i, h, nullptr, hres, NA, C, 1.f);

        // Ewald branch (kfilter fused into k_sf)
        k_sf<<<gSF, 256, 0, stream>>>(hres, cosd, sind, gs, kdwn, WupE_i, sfp);
        k_sfred<<<gRED, 256, 0, stream>>>(sfp, sfr, sfi);
        k_he<<<NA, 128, 0, stream>>>(cosd, sind, sfr, sfi, batch, t1);
        gemm_kernel<128, 1, 0><<<gA, 256, 0, stream>>>(t1, Wm1_i, bm1_i, nullptr, nullptr, t2, NA, C, 1.f);
        gemm_kernel<128, 1, 0><<<gA, 256, 0, stream>>>(t2, Wm2_i, bm2_i, nullptr, nullptr, he2, NA, C, 1.f);

        // gather + combine
        k_gather<<<NA, 128, 0, stream>>>(wbuf_i, hu, Ybuf, eidx, offs, perm, w2_i, w3_i, fe);
        gemm_kernel<128, 0, 0><<<gA, 256, 0, stream>>>(fe, Wmix_i, nullptr, h, he2, hn, NA, C, SKIPF);
        k_node_energy<<<NA, 128, 0, stream>>>(hn, Wr0, Wr1a, Wr1b, (i == 0) ? 0 : 1, nebuf + (size_t)i * NA);

        float* tmp = h; h = hn; hn = tmp;
    }

    k_reduceE<<<BG, 256, 0, stream>>>(e0buf, nebuf, gs, Eout);
}

// Round 9
// 422.291 us; speedup vs baseline: 1.8202x; 1.1074x over previous
//
#include <hip/hip_runtime.h>
#include <hip/hip_bf16.h>
#include <math.h>

// ---------------- problem constants ----------------
constexpr int NA  = 3200;     // atoms
constexpr int NE  = 51200;    // edges
constexpr int C   = 128;      // channels
constexpr int NK  = 123;      // k-points with |k| <= 0.6
constexpr int NKP = 128;      // padded stride for cosd/sind
constexpr int BG  = 8;        // graphs
constexpr int SFSPLIT = 8;    // k_sf split factor
constexpr float SKIPF = 0.57735026918962576f;  // 3^-0.5
constexpr float AVGN  = 16.0f;
constexpr size_t SFSZ = (size_t)BG * NK * C;   // one sf plane (125952)

__device__ __forceinline__ float dsilu(float x) { return x / (1.0f + expf(-x)); }

__device__ __forceinline__ unsigned short f2bf(float f) {
    unsigned int u = __float_as_uint(f);
    unsigned int r = (u + 0x7fffu + ((u >> 16) & 1u)) >> 16;
    return (unsigned short)r;
}
__device__ __forceinline__ float bf2f(unsigned short s) {
    return __uint_as_float(((unsigned int)s) << 16);
}

typedef __attribute__((ext_vector_type(8))) short short8;
typedef __attribute__((ext_vector_type(4))) float f32x4;

// ---------------- generic tiled f32 GEMM (LB: batch 2 layers over blockIdx.z) ----------------
template <int K, int ACT, int OBF16, int LB = 0>
__global__ __launch_bounds__(256, 4) void gemm_kernel(
    const float* __restrict__ X, const float* __restrict__ W,
    const float* __restrict__ bias, const float* __restrict__ res1,
    const float* __restrict__ res2, void* __restrict__ outv,
    int M, int N, float scale)
{
    if (LB) {
        int L = blockIdx.z;
        W += (size_t)L * K * N;
        if (bias) bias += (size_t)L * N;
        outv = OBF16 ? (void*)((unsigned short*)outv + (size_t)L * M * N)
                     : (void*)((float*)outv + (size_t)L * M * N);
    }
    constexpr int K4 = K / 4;
    constexpr int BK  = (K < 64) ? K : 64;
    constexpr int BK4 = BK / 4;
    constexpr int BK4P = BK4 + 1;
    __shared__ float As[64 * BK4P * 4];
    __shared__ float Bs[BK * 64];
    const int tid = threadIdx.x;
    const int m0 = blockIdx.x * 64;
    const int n0 = blockIdx.y * 64;

    const float4* X4 = (const float4*)X;
    const float4* W4 = (const float4*)W;
    float4* As4 = (float4*)As;
    float4* Bs4 = (float4*)Bs;
    const int N4 = N >> 2;

    const int tx = tid & 15;
    const int ty = tid >> 4;
    float acc[4][4];
#pragma unroll
    for (int i = 0; i < 4; i++)
#pragma unroll
        for (int j = 0; j < 4; j++) acc[i][j] = 0.0f;

    for (int k0 = 0; k0 < K4; k0 += BK4) {
        if (k0) __syncthreads();
        for (int idx = tid; idx < 64 * BK4; idx += 256) {
            int r = idx / BK4, k4 = idx - r * BK4;
            As4[r * BK4P + k4] = X4[(size_t)(m0 + r) * K4 + k0 + k4];
        }
        for (int idx = tid; idx < BK * 16; idx += 256) {
            int kr = idx >> 4, c4 = idx & 15;
            Bs4[idx] = W4[(size_t)(k0 * 4 + kr) * N4 + (n0 >> 2) + c4];
        }
        __syncthreads();

#pragma unroll 4
        for (int k4 = 0; k4 < BK4; k4++) {
            float a[4][4];
#pragma unroll
            for (int i = 0; i < 4; i++) {
                float4 av = As4[(ty * 4 + i) * BK4P + k4];
                a[i][0] = av.x; a[i][1] = av.y; a[i][2] = av.z; a[i][3] = av.w;
            }
#pragma unroll
            for (int kk = 0; kk < 4; kk++) {
                float4 bv = Bs4[(k4 * 4 + kk) * 16 + tx];
#pragma unroll
                for (int i = 0; i < 4; i++) {
                    acc[i][0] += a[i][kk] * bv.x;
                    acc[i][1] += a[i][kk] * bv.y;
                    acc[i][2] += a[i][kk] * bv.z;
                    acc[i][3] += a[i][kk] * bv.w;
                }
            }
        }
    }

    float4 bv = make_float4(0.f, 0.f, 0.f, 0.f);
    if (bias) bv = ((const float4*)bias)[(n0 >> 2) + tx];
#pragma unroll
    for (int i = 0; i < 4; i++) {
        int row = m0 + ty * 4 + i;
        size_t o = (size_t)row * N + n0 + tx * 4;
        float4 v;
        v.x = acc[i][0] + bv.x; v.y = acc[i][1] + bv.y;
        v.z = acc[i][2] + bv.z; v.w = acc[i][3] + bv.w;
        if (ACT) { v.x = dsilu(v.x); v.y = dsilu(v.y); v.z = dsilu(v.z); v.w = dsilu(v.w); }
        if (res1) { float4 r = *(const float4*)(res1 + o); v.x += r.x; v.y += r.y; v.z += r.z; v.w += r.w; }
        if (res2) { float4 r = *(const float4*)(res2 + o); v.x += r.x; v.y += r.y; v.z += r.z; v.w += r.w; }
        v.x *= scale; v.y *= scale; v.z *= scale; v.w *= scale;
        if (OBF16) {
            ushort4 pk;
            pk.x = f2bf(v.x); pk.y = f2bf(v.y); pk.z = f2bf(v.z); pk.w = f2bf(v.w);
            *(ushort4*)((unsigned short*)outv + o) = pk;
        } else {
            *(float4*)((float*)outv + o) = v;
        }
    }
}

// ---------------- dual GEMM: t1 = silu(h@Wa + bias), hu = h@Wb ----------------
__global__ __launch_bounds__(256, 4) void gemm_dual(
    const float* __restrict__ X, const float* __restrict__ Wa,
    const float* __restrict__ Wb, const float* __restrict__ bias,
    float* __restrict__ outa, float* __restrict__ outb)
{
    constexpr int K4 = 32, BK4 = 16, BK4P = 17;
    __shared__ float As[64 * BK4P * 4];
    __shared__ float Bs[64 * 64];
    const int tid = threadIdx.x;
    const int m0 = blockIdx.x * 64;
    const int sel = blockIdx.y >> 1;
    const int n0 = (blockIdx.y & 1) * 64;
    const float* W = sel ? Wb : Wa;
    float* out = sel ? outb : outa;

    const float4* X4 = (const float4*)X;
    const float4* W4 = (const float4*)W;
    float4* As4 = (float4*)As;
    float4* Bs4 = (float4*)Bs;

    const int tx = tid & 15;
    const int ty = tid >> 4;
    float acc[4][4];
#pragma unroll
    for (int i = 0; i < 4; i++)
#pragma unroll
        for (int j = 0; j < 4; j++) acc[i][j] = 0.0f;

    for (int k0 = 0; k0 < K4; k0 += BK4) {
        if (k0) __syncthreads();
        for (int idx = tid; idx < 64 * BK4; idx += 256) {
            int r = idx / BK4, k4 = idx - r * BK4;
            As4[r * BK4P + k4] = X4[(size_t)(m0 + r) * K4 + k0 + k4];
        }
        for (int idx = tid; idx < 64 * 16; idx += 256) {
            int kr = idx >> 4, c4 = idx & 15;
            Bs4[idx] = W4[(size_t)(k0 * 4 + kr) * 32 + (n0 >> 2) + c4];
        }
        __syncthreads();

#pragma unroll 4
        for (int k4 = 0; k4 < BK4; k4++) {
            float a[4][4];
#pragma unroll
            for (int i = 0; i < 4; i++) {
                float4 av = As4[(ty * 4 + i) * BK4P + k4];
                a[i][0] = av.x; a[i][1] = av.y; a[i][2] = av.z; a[i][3] = av.w;
            }
#pragma unroll
            for (int kk = 0; kk < 4; kk++) {
                float4 bv = Bs4[(k4 * 4 + kk) * 16 + tx];
#pragma unroll
                for (int i = 0; i < 4; i++) {
                    acc[i][0] += a[i][kk] * bv.x;
                    acc[i][1] += a[i][kk] * bv.y;
                    acc[i][2] += a[i][kk] * bv.z;
                    acc[i][3] += a[i][kk] * bv.w;
                }
            }
        }
    }

    float4 bv = make_float4(0.f, 0.f, 0.f, 0.f);
    if (!sel) bv = ((const float4*)bias)[(n0 >> 2) + tx];
#pragma unroll
    for (int i = 0; i < 4; i++) {
        int row = m0 + ty * 4 + i;
        size_t o = (size_t)row * 128 + n0 + tx * 4;
        float4 v;
        v.x = acc[i][0] + bv.x; v.y = acc[i][1] + bv.y;
        v.z = acc[i][2] + bv.z; v.w = acc[i][3] + bv.w;
        if (!sel) { v.x = dsilu(v.x); v.y = dsilu(v.y); v.z = dsilu(v.z); v.w = dsilu(v.w); }
        *(float4*)(out + o) = v;
    }
}

// ---------------- MFMA MLP layer, 2-layer batched ----------------
__global__ __launch_bounds__(128, 2) void k_mlp_mfma(
    const unsigned short* __restrict__ X, const unsigned short* __restrict__ Wbase,
    const float* __restrict__ bbase, unsigned short* __restrict__ out)
{
    constexpr int MT = 128, AS = 72;
    __shared__ unsigned short Als[MT * AS];
    __shared__ unsigned short Bls[64 * AS];
    const int tid = threadIdx.x;
    const int m0 = blockIdx.x * MT;
    const int layer = (m0 >= NE) ? 1 : 0;
    const unsigned short* Wt = Wbase + (size_t)layer * 64 * 64;
    const float* bias = bbase + (size_t)layer * 64;

    for (int idx = tid; idx < MT * 8; idx += 128) {
        int r = idx >> 3, s = idx & 7;
        *(short8*)(Als + r * AS + s * 8) = ((const short8*)X)[(size_t)(m0 + r) * 8 + s];
    }
    for (int idx = tid; idx < 64 * 8; idx += 128) {
        int r = idx >> 3, s = idx & 7;
        *(short8*)(Bls + r * AS + s * 8) = ((const short8*)Wt)[(size_t)r * 8 + s];
    }
    __syncthreads();

    const int wave = tid >> 6;
    const int lane = tid & 63;
    const int q = lane >> 4;
    const int l16 = lane & 15;
    const int mw = wave * 64;

    f32x4 acc[4][4];
#pragma unroll
    for (int mi = 0; mi < 4; mi++)
#pragma unroll
        for (int ni = 0; ni < 4; ni++) acc[mi][ni] = (f32x4){0.f, 0.f, 0.f, 0.f};

#pragma unroll
    for (int kc = 0; kc < 2; kc++) {
        short8 a[4], b[4];
#pragma unroll
        for (int mi = 0; mi < 4; mi++)
            a[mi] = *(const short8*)(Als + (mw + mi * 16 + l16) * AS + kc * 32 + q * 8);
#pragma unroll
        for (int ni = 0; ni < 4; ni++)
            b[ni] = *(const short8*)(Bls + (ni * 16 + l16) * AS + kc * 32 + q * 8);
#pragma unroll
        for (int mi = 0; mi < 4; mi++)
#pragma unroll
            for (int ni = 0; ni < 4; ni++)
                acc[mi][ni] = __builtin_amdgcn_mfma_f32_16x16x32_bf16(a[mi], b[ni], acc[mi][ni], 0, 0, 0);
    }

#pragma unroll
    for (int ni = 0; ni < 4; ni++) {
        float bv = bias[ni * 16 + l16];
#pragma unroll
        for (int mi = 0; mi < 4; mi++) {
#pragma unroll
            for (int r = 0; r < 4; r++) {
                int e = m0 + mw + mi * 16 + q * 4 + r;
                int n = ni * 16 + l16;
                out[(size_t)e * 64 + n] = f2bf(dsilu(acc[mi][ni][r] + bv));
            }
        }
    }
}

// ---------------- fused he-MLP: he2 = silu(silu(t1@Wm1+b1)@Wm2+b2), bf16 MFMA ----------------
// Wm1t/Wm2t: bf16 [n][k] 128x128 (per-layer pointers). 256 thr, 64 rows/block.
__global__ __launch_bounds__(256, 2) void k_hemlp(
    const float* __restrict__ t1,
    const unsigned short* __restrict__ Wm1t, const float* __restrict__ bm1,
    const unsigned short* __restrict__ Wm2t, const float* __restrict__ bm2,
    float* __restrict__ he2)
{
    constexpr int MT = 64, ASH = 136;
    __shared__ unsigned short Xs[MT * ASH];    // ~17 KB
    __shared__ unsigned short Ws[128 * ASH];   // ~35 KB
    __shared__ unsigned short Ts[MT * ASH];    // ~17 KB
    const int tid = threadIdx.x;
    const int m0 = blockIdx.x * MT;

    // stage t1 -> bf16
    for (int idx = tid; idx < MT * 32; idx += 256) {
        int r = idx >> 5, c4 = idx & 31;
        float4 v = ((const float4*)t1)[(size_t)(m0 + r) * 32 + c4];
        ushort4 pk;
        pk.x = f2bf(v.x); pk.y = f2bf(v.y); pk.z = f2bf(v.z); pk.w = f2bf(v.w);
        *(ushort4*)(Xs + r * ASH + c4 * 4) = pk;
    }
    // stage Wm1t
    for (int idx = tid; idx < 128 * 16; idx += 256) {
        int r = idx >> 4, s = idx & 15;
        *(short8*)(Ws + r * ASH + s * 8) = ((const short8*)Wm1t)[(size_t)r * 16 + s];
    }
    __syncthreads();

    const int wave = tid >> 6;
    const int lane = tid & 63;
    const int q = lane >> 4;
    const int l16 = lane & 15;
    const int mrow = wave * 16;   // 4 waves x 16 rows

    f32x4 acc[8];
#pragma unroll
    for (int ni = 0; ni < 8; ni++) acc[ni] = (f32x4){0.f, 0.f, 0.f, 0.f};
#pragma unroll
    for (int kc = 0; kc < 4; kc++) {
        short8 a = *(const short8*)(Xs + (mrow + l16) * ASH + kc * 32 + q * 8);
#pragma unroll
        for (int ni = 0; ni < 8; ni++) {
            short8 b = *(const short8*)(Ws + (ni * 16 + l16) * ASH + kc * 32 + q * 8);
            acc[ni] = __builtin_amdgcn_mfma_f32_16x16x32_bf16(a, b, acc[ni], 0, 0, 0);
        }
    }
    // t2 = silu(acc + bm1) -> Ts (row-major bf16)
#pragma unroll
    for (int ni = 0; ni < 8; ni++) {
        float bv = bm1[ni * 16 + l16];
#pragma unroll
        for (int r = 0; r < 4; r++) {
            int row = mrow + q * 4 + r;
            int col = ni * 16 + l16;
            Ts[row * ASH + col] = f2bf(dsilu(acc[ni][r] + bv));
        }
    }
    __syncthreads();
    // stage Wm2t (overwrite Ws)
    for (int idx = tid; idx < 128 * 16; idx += 256) {
        int r = idx >> 4, s = idx & 15;
        *(short8*)(Ws + r * ASH + s * 8) = ((const short8*)Wm2t)[(size_t)r * 16 + s];
    }
    __syncthreads();

#pragma unroll
    for (int ni = 0; ni < 8; ni++) acc[ni] = (f32x4){0.f, 0.f, 0.f, 0.f};
#pragma unroll
    for (int kc = 0; kc < 4; kc++) {
        short8 a = *(const short8*)(Ts + (mrow + l16) * ASH + kc * 32 + q * 8);
#pragma unroll
        for (int ni = 0; ni < 8; ni++) {
            short8 b = *(const short8*)(Ws + (ni * 16 + l16) * ASH + kc * 32 + q * 8);
            acc[ni] = __builtin_amdgcn_mfma_f32_16x16x32_bf16(a, b, acc[ni], 0, 0, 0);
        }
    }
#pragma unroll
    for (int ni = 0; ni < 8; ni++) {
        float bv = bm2[ni * 16 + l16];
#pragma unroll
        for (int r = 0; r < 4; r++) {
            int row = m0 + mrow + q * 4 + r;
            int col = ni * 16 + l16;
            he2[(size_t)row * C + col] = dsilu(acc[ni][r] + bv);
        }
    }
}

// ---------------- weight converts ----------------
__global__ __launch_bounds__(64) void k_convW4(
    const float* __restrict__ rW4, unsigned short* __restrict__ W4bt)
{
    int b = blockIdx.x;
    int layer = b >> 9, n = b & 511;
    int k = threadIdx.x;
    W4bt[((size_t)layer * 512 + n) * 64 + k] = f2bf(rW4[((size_t)layer * 64 + k) * 512 + n]);
}

__global__ __launch_bounds__(64) void k_convW64(
    const float* __restrict__ rW, unsigned short* __restrict__ Wbt)
{
    int b = blockIdx.x;
    int layer = b >> 6, n = b & 63;
    int k = threadIdx.x;
    Wbt[((size_t)layer * 64 + n) * 64 + k] = f2bf(rW[((size_t)layer * 64 + k) * 64 + n]);
}

// f32 [L][128][128] -> bf16 transposed [L][128][128] ([n][k])
__global__ __launch_bounds__(128) void k_convT128(
    const float* __restrict__ W, unsigned short* __restrict__ Wt)
{
    int b = blockIdx.x;           // layer*128 + n
    int layer = b >> 7, n = b & 127;
    int k = threadIdx.x;
    Wt[((size_t)layer * 128 + n) * 128 + k] = f2bf(W[((size_t)layer * 128 + k) * 128 + n]);
}

// ---------------- MFMA GEMM, 2-layer batched: wbuf[e][n] = X[e] @ W4t_l[n] ----------------
__global__ __launch_bounds__(256, 2) void k_wbuf_mfma(
    const unsigned short* __restrict__ X, const unsigned short* __restrict__ W4base,
    unsigned short* __restrict__ wbuf)
{
    constexpr int MT = 256, NT = 64, AS = 72;
    __shared__ unsigned short Als[MT * AS];
    __shared__ unsigned short Bls[NT * AS];
    const int tid = threadIdx.x;
    const int m0 = blockIdx.x * MT;
    const int n0 = blockIdx.y * NT;
    const int layer = (m0 >= NE) ? 1 : 0;
    const unsigned short* W4t = W4base + (size_t)layer * 512 * 64;

    for (int idx = tid; idx < MT * 8; idx += 256) {
        int r = idx >> 3, s = idx & 7;
        *(short8*)(Als + r * AS + s * 8) = ((const short8*)X)[(size_t)(m0 + r) * 8 + s];
    }
    for (int idx = tid; idx < NT * 8; idx += 256) {
        int r = idx >> 3, s = idx & 7;
        *(short8*)(Bls + r * AS + s * 8) = ((const short8*)W4t)[(size_t)(n0 + r) * 8 + s];
    }
    __syncthreads();

    const int wave = tid >> 6;
    const int lane = tid & 63;
    const int q = lane >> 4;
    const int l16 = lane & 15;
    const int mw = wave * 64;

    f32x4 acc[4][4];
#pragma unroll
    for (int mi = 0; mi < 4; mi++)
#pragma unroll
        for (int ni = 0; ni < 4; ni++) acc[mi][ni] = (f32x4){0.f, 0.f, 0.f, 0.f};

#pragma unroll
    for (int kc = 0; kc < 2; kc++) {
        short8 a[4], b[4];
#pragma unroll
        for (int mi = 0; mi < 4; mi++)
            a[mi] = *(const short8*)(Als + (mw + mi * 16 + l16) * AS + kc * 32 + q * 8);
#pragma unroll
        for (int ni = 0; ni < 4; ni++)
            b[ni] = *(const short8*)(Bls + (ni * 16 + l16) * AS + kc * 32 + q * 8);
#pragma unroll
        for (int mi = 0; mi < 4; mi++)
#pragma unroll
            for (int ni = 0; ni < 4; ni++)
                acc[mi][ni] = __builtin_amdgcn_mfma_f32_16x16x32_bf16(a[mi], b[ni], acc[mi][ni], 0, 0, 0);
    }

#pragma unroll
    for (int mi = 0; mi < 4; mi++) {
#pragma unroll
        for (int ni = 0; ni < 4; ni++) {
#pragma unroll
            for (int r = 0; r < 4; r++) {
                int e = m0 + mw + mi * 16 + q * 4 + r;
                int n = n0 + ni * 16 + l16;
                wbuf[(size_t)e * 512 + n] = f2bf(acc[mi][ni][r]);
            }
        }
    }
}

// ---------------- setup kernels ----------------
__global__ __launch_bounds__(128) void k_node_init(
    const float* __restrict__ na, const float* __restrict__ Wemb,
    const float* __restrict__ aE, float* __restrict__ h, float* __restrict__ e0buf)
{
    int n = blockIdx.x, c = threadIdx.x;
    float s = 0.f;
#pragma unroll
    for (int k = 0; k < 10; k++) s += na[n * 10 + k] * Wemb[k * C + c];
    h[(size_t)n * C + c] = s;
    if (c == 0) {
        float e = 0.f;
#pragma unroll
        for (int k = 0; k < 10; k++) e += na[n * 10 + k] * aE[k];
        e0buf[n] = e;
    }
}

__global__ __launch_bounds__(256) void k_ranges(const int* __restrict__ batch, int* __restrict__ gs)
{
    __shared__ int cnt[BG];
    if (threadIdx.x < BG) cnt[threadIdx.x] = 0;
    __syncthreads();
    for (int n = threadIdx.x; n < NA; n += 256) atomicAdd(&cnt[batch[n]], 1);
    __syncthreads();
    if (threadIdx.x == 0) {
        int s = 0;
        for (int b = 0; b < BG; b++) { gs[b] = s; s += cnt[b]; }
        gs[BG] = s;
    }
}

__device__ __forceinline__ float sincn(float x) {
    float px = 3.14159265358979323846f * x;
    return (fabsf(px) < 1e-8f) ? 1.0f : (sinf(px) / px);
}

__global__ __launch_bounds__(128) void k_kspace(
    const float* __restrict__ pos, const float* __restrict__ kgrid,
    float* __restrict__ cosd, float* __restrict__ sind)
{
    int n = blockIdx.x, k = threadIdx.x;
    float p0 = pos[n * 3 + 0], p1 = pos[n * 3 + 1], p2 = pos[n * 3 + 2];
    float sd = sincn(0.1f * p0) * sincn(0.1f * p1) * sincn(0.1f * p2);
    if (k < NK) {
        float d = p0 * kgrid[k * 3 + 0] + p1 * kgrid[k * 3 + 1] + p2 * kgrid[k * 3 + 2];
        float sn, cs;
        sincosf(d, &sn, &cs);
        cosd[(size_t)n * NKP + k] = sd * cs;
        sind[(size_t)n * NKP + k] = sd * sn;
    } else {
        cosd[(size_t)n * NKP + k] = 0.f;
        sind[(size_t)n * NKP + k] = 0.f;
    }
}

__global__ __launch_bounds__(1024) void k_kdown(
    const float* __restrict__ krbf, const float* __restrict__ Wdown, float* __restrict__ kdown)
{
    int t = threadIdx.x;
    if (t < NK * 8) {
        int k = t >> 3, j = t & 7;
        float s = 0.f;
        for (int r = 0; r < 128; r++) s += krbf[k * 128 + r] * Wdown[r * 8 + j];
        kdown[t] = s;
    }
}

__global__ __launch_bounds__(256) void k_edge_geom(
    const float* __restrict__ pos, const float* __restrict__ shifts,
    const int* __restrict__ eidx, float* __restrict__ Y, float* __restrict__ ef)
{
    int e = blockIdx.x * 256 + threadIdx.x;
    if (e >= NE) return;
    int s = eidx[e], d = eidx[NE + e];
    float vx = pos[d * 3 + 0] - pos[s * 3 + 0] + shifts[e * 3 + 0];
    float vy = pos[d * 3 + 1] - pos[s * 3 + 1] + shifts[e * 3 + 1];
    float vz = pos[d * 3 + 2] - pos[s * 3 + 2] + shifts[e * 3 + 2];
    float r = sqrtf(vx * vx + vy * vy + vz * vz);
    float rinv = 1.0f / fmaxf(r, 1e-9f);
    float x = vx * rinv, y = vy * rinv, z = vz * rinv;

    const float s3 = 1.7320508075688772f, s5 = 2.2360679774997896f, s15 = 3.8729833462074170f;
    const float c70 = 2.0916500663351889f;
    const float c105 = 10.246950765959598f;
    const float c42 = 1.6201851746019651f;
    const float c7 = 1.3228756555322954f;
    float o[16];
    o[0] = 1.0f;
    o[1] = s3 * x; o[2] = s3 * y; o[3] = s3 * z;
    o[4] = s15 * x * y; o[5] = s15 * y * z; o[6] = 0.5f * s5 * (3.f * z * z - 1.f);
    o[7] = s15 * x * z; o[8] = 0.5f * s15 * (x * x - y * y);
    o[9]  = c70 * y * (3.f * x * x - y * y);
    o[10] = c105 * x * y * z;
    o[11] = c42 * y * (5.f * z * z - 1.f);
    o[12] = c7 * z * (5.f * z * z - 3.f);
    o[13] = c42 * x * (5.f * z * z - 1.f);
    o[14] = 0.5f * c105 * z * (x * x - y * y);
    o[15] = c70 * x * (x * x - 3.f * y * y);
    float4* Y4 = (float4*)(Y + (size_t)e * 16);
    Y4[0] = make_float4(o[0], o[1], o[2], o[3]);
    Y4[1] = make_float4(o[4], o[5], o[6], o[7]);
    Y4[2] = make_float4(o[8], o[9], o[10], o[11]);
    Y4[3] = make_float4(o[12], o[13], o[14], o[15]);

    float uu = fminf(fmaxf(r * 0.2f, 0.f), 1.f);
    float u2 = uu * uu, u4 = u2 * u2, u5 = u4 * uu, u6 = u5 * uu, u7 = u6 * uu;
    float env = 1.f - 21.f * u5 + 35.f * u6 - 15.f * u7;
    env = (r < 5.0f) ? env : 0.0f;
    float pref = 0.63245553203367587f * rinv * env;
    const float pio5 = 0.62831853071795865f;
    float efv[8];
#pragma unroll
    for (int n1 = 1; n1 <= 8; n1++) efv[n1 - 1] = pref * sinf(n1 * pio5 * r);
    float4* E4 = (float4*)(ef + (size_t)e * 8);
    E4[0] = make_float4(efv[0], efv[1], efv[2], efv[3]);
    E4[1] = make_float4(efv[4], efv[5], efv[6], efv[7]);
}

// ---------------- CSR by dst ----------------
__global__ __launch_bounds__(256) void k_count(const int* __restrict__ eidx, int* __restrict__ deg)
{
    int e = blockIdx.x * 256 + threadIdx.x;
    if (e < NE) atomicAdd(&deg[eidx[NE + e]], 1);
}

__global__ __launch_bounds__(1024) void k_scan(
    const int* __restrict__ deg, int* __restrict__ offs, int* __restrict__ cursor)
{
    __shared__ int sc[1024];
    int tid = threadIdx.x;
    int base = tid * 4;
    int v[4]; int s = 0;
#pragma unroll
    for (int i = 0; i < 4; i++) {
        int idx = base + i;
        int d = (idx < NA) ? deg[idx] : 0;
        v[i] = s; s += d;
    }
    sc[tid] = s;
    __syncthreads();
    for (int ofs = 1; ofs < 1024; ofs <<= 1) {
        int t = (tid >= ofs) ? sc[tid - ofs] : 0;
        __syncthreads();
        sc[tid] += t;
        __syncthreads();
    }
    int excl = (tid > 0) ? sc[tid - 1] : 0;
#pragma unroll
    for (int i = 0; i < 4; i++) {
        int idx = base + i;
        if (idx < NA) { int o = excl + v[i]; offs[idx] = o; cursor[idx] = o; }
    }
    if (tid == 1023) offs[NA] = sc[1023];
}

__global__ __launch_bounds__(256) void k_fill(
    const int* __restrict__ eidx, int* __restrict__ cursor, int* __restrict__ perm)
{
    int e = blockIdx.x * 256 + threadIdx.x;
    if (e < NE) {
        int d = eidx[NE + e];
        int p = atomicAdd(&cursor[d], 1);
        perm[p] = e;
    }
}

// ---------------- Ewald: structure-factor partials (kfilter fused inline) ----------------
__global__ __launch_bounds__(256, 4) void k_sf(
    const float* __restrict__ hres, const float* __restrict__ cosd, const float* __restrict__ sind,
    const int* __restrict__ gs, const float* __restrict__ kdwn, const float* __restrict__ WupE,
    float* __restrict__ sfp)
{
    const int b = blockIdx.x, kt = blockIdx.y, sp = blockIdx.z;
    const int n0 = gs[b], n1 = gs[b + 1];
    const int cnt = n1 - n0;
    const int per = (cnt + SFSPLIT - 1) / SFSPLIT;
    const int cs = n0 + sp * per;
    const int ce = min(cs + per, n1);

    __shared__ float Hs[32 * 128];
    __shared__ float Cs[32 * 32];
    __shared__ float Ss[32 * 32];

    const int tid = threadIdx.x;
    const int tx = tid & 31;
    const int ty = tid >> 5;

    float accR[4][4], accI[4][4];
#pragma unroll
    for (int i = 0; i < 4; i++)
#pragma unroll
        for (int j = 0; j < 4; j++) { accR[i][j] = 0.f; accI[i][j] = 0.f; }

    float4* H4 = (float4*)Hs;
    float4* C4 = (float4*)Cs;
    float4* S4 = (float4*)Ss;

    for (int nb = cs; nb < ce; nb += 32) {
        __syncthreads();
        for (int idx = tid; idx < 32 * 32; idx += 256) {
            int r = idx >> 5, c4 = idx & 31;
            int n = nb + r;
            H4[idx] = (n < ce) ? ((const float4*)hres)[(size_t)n * 32 + c4]
                               : make_float4(0.f, 0.f, 0.f, 0.f);
        }
        for (int idx = tid; idx < 32 * 8; idx += 256) {
            int r = idx >> 3, k4 = idx & 7;
            int n = nb + r;
            float4 cv = make_float4(0.f, 0.f, 0.f, 0.f), sv = cv;
            if (n < ce) {
                cv = ((const float4*)cosd)[(size_t)n * 32 + kt * 8 + k4];
                sv = ((const float4*)sind)[(size_t)n * 32 + kt * 8 + k4];
            }
            C4[idx] = cv;
            S4[idx] = sv;
        }
        __syncthreads();
        const int lim = min(32, ce - nb);
        for (int n = 0; n < lim; n++) {
            float4 hv = H4[n * 32 + tx];
            float4 cv = C4[n * 8 + ty];
            float4 sv = S4[n * 8 + ty];
            float h[4] = { hv.x, hv.y, hv.z, hv.w };
            float ck[4] = { cv.x, cv.y, cv.z, cv.w };
            float sk[4] = { sv.x, sv.y, sv.z, sv.w };
#pragma unroll
            for (int i = 0; i < 4; i++)
#pragma unroll
                for (int j = 0; j < 4; j++) {
                    accR[i][j] += ck[i] * h[j];
                    accI[i][j] += sk[i] * h[j];
                }
        }
    }

    const int kbase = kt * 32 + ty * 4;
    float* baseR = sfp + (size_t)sp * SFSZ;
    float* baseI = sfp + (size_t)(SFSPLIT + sp) * SFSZ;
#pragma unroll
    for (int i = 0; i < 4; i++) {
        int k = kbase + i;
        if (k < NK) {
            float4 kfv = make_float4(0.f, 0.f, 0.f, 0.f);
#pragma unroll
            for (int j = 0; j < 8; j++) {
                float kd = kdwn[k * 8 + j];
                float4 wv = ((const float4*)WupE)[(size_t)j * 32 + tx];
                kfv.x += kd * wv.x; kfv.y += kd * wv.y;
                kfv.z += kd * wv.z; kfv.w += kd * wv.w;
            }
            float vx = kfv.x * 0.01f, vy = kfv.y * 0.01f, vz = kfv.z * 0.01f, vw = kfv.w * 0.01f;
            size_t o = ((size_t)(b * NK + k)) * C + tx * 4;
            *(float4*)(baseR + o) = make_float4(accR[i][0] * vx, accR[i][1] * vy,
                                                accR[i][2] * vz, accR[i][3] * vw);
            *(float4*)(baseI + o) = make_float4(accI[i][0] * vx, accI[i][1] * vy,
                                                accI[i][2] * vz, accI[i][3] * vw);
        }
    }
}

__global__ __launch_bounds__(256) void k_sfred(
    const float* __restrict__ sfp, float* __restrict__ sfr, float* __restrict__ sfi)
{
    const size_t S4 = SFSZ / 4;
    size_t o4 = (size_t)blockIdx.x * 256 + threadIdx.x;
    if (o4 >= S4) return;
    const float4* p = (const float4*)sfp;
    float4 ar = make_float4(0.f, 0.f, 0.f, 0.f), ai = ar;
#pragma unroll
    for (int sp = 0; sp < SFSPLIT; sp++) {
        float4 r = p[(size_t)sp * S4 + o4];
        ar.x += r.x; ar.y += r.y; ar.z += r.z; ar.w += r.w;
        float4 q = p[(size_t)(SFSPLIT + sp) * S4 + o4];
        ai.x += q.x; ai.y += q.y; ai.z += q.z; ai.w += q.w;
    }
    ((float4*)sfr)[o4] = ar;
    ((float4*)sfi)[o4] = ai;
}

__global__ __launch_bounds__(128) void k_he(
    const float* __restrict__ cosd, const float* __restrict__ sind,
    const float* __restrict__ sfr, const float* __restrict__ sfi,
    const int* __restrict__ batch, float* __restrict__ out)
{
    int n = blockIdx.x, c = threadIdx.x;
    int b = batch[n];
    const float* pr = sfr + (size_t)b * NK * C;
    const float* pi = sfi + (size_t)b * NK * C;
    const float* cdp = cosd + (size_t)n * NKP;
    const float* sdp = sind + (size_t)n * NKP;
    float acc = 0.f;
    for (int k = 0; k < NK; k++) {
        acc += cdp[k] * pr[(size_t)k * C + c] + sdp[k] * pi[(size_t)k * C + c];
    }
    out[(size_t)n * C + c] = acc;
}

// ---------------- fused gather + symm-contraction + Wmix + residual + energy ----------------
__global__ __launch_bounds__(128) void k_gather_mix(
    const unsigned short* __restrict__ wbuf, const float* __restrict__ hu,
    const float* __restrict__ Y, const int* __restrict__ srcArr,
    const int* __restrict__ offs, const int* __restrict__ perm,
    const float* __restrict__ w2, const float* __restrict__ w3,
    const float* __restrict__ Wmix, const float* __restrict__ h,
    const float* __restrict__ he2,
    const float* __restrict__ Wr0, const float* __restrict__ Wr1a,
    const float* __restrict__ Wr1b, int mode,
    float* __restrict__ hn, float* __restrict__ nebuf)
{
    int n = blockIdx.x, c = threadIdx.x;
    int j0 = offs[n], j1 = offs[n + 1];
    float A[16];
#pragma unroll
    for (int s = 0; s < 16; s++) A[s] = 0.f;
    for (int j = j0; j < j1; j++) {
        int e = perm[j];
        int s = srcArr[e];
        float huc = hu[(size_t)s * C + c];
        ushort4 wv = *(const ushort4*)(wbuf + (size_t)e * 512 + c * 4);
        const float4* Yp = (const float4*)(Y + (size_t)e * 16);
        float4 y0 = Yp[0], y1 = Yp[1], y2 = Yp[2], y3 = Yp[3];
        float m0 = bf2f(wv.x) * huc, m1 = bf2f(wv.y) * huc;
        float m2 = bf2f(wv.z) * huc, m3 = bf2f(wv.w) * huc;
        A[0] += m0 * y0.x;
        A[1] += m1 * y0.y;  A[2]  += m1 * y0.z;  A[3]  += m1 * y0.w;
        A[4] += m2 * y1.x;  A[5]  += m2 * y1.y;  A[6]  += m2 * y1.z;  A[7] += m2 * y1.w;
        A[8] += m2 * y2.x;
        A[9] += m3 * y2.y;  A[10] += m3 * y2.z;  A[11] += m3 * y2.w;
        A[12] += m3 * y3.x; A[13] += m3 * y3.y;  A[14] += m3 * y3.z;  A[15] += m3 * y3.w;
    }
    const float inv = 1.0f / AVGN;
#pragma unroll
    for (int s = 0; s < 16; s++) A[s] *= inv;
    float scal = A[0];
    float i0 = A[0] * A[0];
    float i1 = A[1] * A[1] + A[2] * A[2] + A[3] * A[3];
    float i2 = A[4] * A[4] + A[5] * A[5] + A[6] * A[6] + A[7] * A[7] + A[8] * A[8];
    float i3 = A[9] * A[9] + A[10] * A[10] + A[11] * A[11] + A[12] * A[12] +
               A[13] * A[13] + A[14] * A[14] + A[15] * A[15];
    float t2 = i0 * w2[c] + i1 * w2[C + c] + i2 * w2[2 * C + c] + i3 * w2[3 * C + c];
    float t3 = i0 * w3[c] + i1 * w3[C + c] + i2 * w3[2 * C + c] + i3 * w3[3 * C + c];
    float fe_c = scal + t2 + scal * t3;

    __shared__ float fs[128];
    __shared__ float red[16];
    fs[c] = fe_c;
    __syncthreads();

    // mix[c] = sum_k fs[k] * Wmix[k][c]
    float mix = 0.f;
#pragma unroll 8
    for (int k = 0; k < 128; k++) mix += fs[k] * Wmix[(size_t)k * C + c];

    float hnv = SKIPF * (mix + h[(size_t)n * C + c] + he2[(size_t)n * C + c]);
    hn[(size_t)n * C + c] = hnv;

    __syncthreads();        // done reading fs; reuse for energy
    fs[c] = hnv;
    __syncthreads();

    if (mode == 0) {
        float v = hnv * Wr0[c];
#pragma unroll
        for (int o = 32; o; o >>= 1) v += __shfl_down(v, o, 64);
        if ((c & 63) == 0) red[c >> 6] = v;
        __syncthreads();
        if (c == 0) nebuf[n] = red[0] + red[1];
    } else {
        if (c < 16) {
            float s = 0.f;
#pragma unroll 8
            for (int cc = 0; cc < 128; cc++) s += fs[cc] * Wr1a[cc * 16 + c];
            red[c] = dsilu(s) * Wr1b[c];
        }
        __syncthreads();
        if (c == 0) {
            float s = 0.f;
#pragma unroll
            for (int j = 0; j < 16; j++) s += red[j];
            nebuf[n] = s;
        }
    }
}

// ---------------- final per-graph energy reduction ----------------
__global__ __launch_bounds__(256) void k_reduceE(
    const float* __restrict__ e0buf, const float* __restrict__ nebuf,
    const int* __restrict__ gs, float* __restrict__ Eout)
{
    int b = blockIdx.x, t = threadIdx.x;
    int n0 = gs[b], n1 = gs[b + 1];
    float s = 0.f;
    for (int n = n0 + t; n < n1; n += 256)
        s += e0buf[n] + nebuf[n] + nebuf[NA + n];
#pragma unroll
    for (int o = 32; o; o >>= 1) s += __shfl_down(s, o, 64);
    __shared__ float red[4];
    if ((t & 63) == 0) red[t >> 6] = s;
    __syncthreads();
    if (t == 0) Eout[b] = red[0] + red[1] + red[2] + red[3];
}

// ---------------- workspace layout (floats) ----------------
constexpr size_t NAC   = (size_t)NA * C;
constexpr size_t F_COSD = 0;
constexpr size_t F_SIND = F_COSD + (size_t)NA * NKP;
constexpr size_t F_Y    = F_SIND + (size_t)NA * NKP;
constexpr size_t F_EF   = F_Y + (size_t)NE * 16;
constexpr size_t F_H    = F_EF + (size_t)NE * 8;
constexpr size_t F_HN   = F_H + NAC;
constexpr size_t F_HRES = F_HN + NAC;
constexpr size_t F_T1   = F_HRES + NAC;
constexpr size_t F_HE2  = F_T1 + NAC;
constexpr size_t F_HU   = F_HE2 + NAC;
constexpr size_t F_TA   = F_HU + NAC;                // bf16 tA: 2*NE*64 shorts
constexpr size_t F_TB   = F_TA + (size_t)NE * 64;    // bf16 hbuf: 2*NE*64 shorts
constexpr size_t F_WTS  = F_TB + (size_t)NE * 64;    // bf16 weight stash
constexpr size_t F_W    = F_WTS + 80 * 1024;         // bf16 wbuf: 2*NE*512 shorts
constexpr size_t F_SFR  = F_W + (size_t)NE * 512;
constexpr size_t F_SFI  = F_SFR + SFSZ;
constexpr size_t F_SFP  = F_SFI + SFSZ;              // 16 planes of SFSZ
constexpr size_t F_KD   = F_SFP + 2 * (size_t)SFSPLIT * SFSZ;
constexpr size_t F_E0   = F_KD + 1024;               // e0buf: NA
constexpr size_t F_NE   = F_E0 + NA;                 // nebuf: 2*NA
constexpr size_t F_END  = F_NE + 2 * (size_t)NA;
constexpr size_t I_BASE = ((F_END * 4 + 255) / 256) * 256;

extern "C" void kernel_launch(void* const* d_in, const int* in_sizes, int n_in,
                              void* d_out, int out_size, void* d_ws, size_t ws_size,
                              hipStream_t stream) {
    const float* pos    = (const float*)d_in[0];
    const float* na     = (const float*)d_in[1];
    const float* shifts = (const float*)d_in[2];
    const int*   eidx   = (const int*)d_in[3];
    const int*   batch  = (const int*)d_in[4];
    const float* kgrid  = (const float*)d_in[5];
    const float* krbf   = (const float*)d_in[6];
    const float* Wemb   = (const float*)d_in[7];
    const float* aE     = (const float*)d_in[8];
    const float* rW1    = (const float*)d_in[9];
    const float* rb1    = (const float*)d_in[10];
    const float* rW2    = (const float*)d_in[11];
    const float* rb2    = (const float*)d_in[12];
    const float* rW3    = (const float*)d_in[13];
    const float* rb3    = (const float*)d_in[14];
    const float* rW4    = (const float*)d_in[15];
    const float* Wup    = (const float*)d_in[16];
    const float* w2     = (const float*)d_in[17];
    const float* w3     = (const float*)d_in[18];
    const float* Wmix   = (const float*)d_in[19];
    const float* Wr0    = (const float*)d_in[20];
    const float* Wr1a   = (const float*)d_in[21];
    const float* Wr1b   = (const float*)d_in[22];
    const float* Wdown  = (const float*)d_in[23];
    const float* WupE   = (const float*)d_in[24];
    const float* Wpre1  = (const float*)d_in[25];
    const float* bpre1  = (const float*)d_in[26];
    const float* Wpre2  = (const float*)d_in[27];
    const float* bpre2  = (const float*)d_in[28];
    const float* Wm1    = (const float*)d_in[29];
    const float* bm1    = (const float*)d_in[30];
    const float* Wm2    = (const float*)d_in[31];
    const float* bm2    = (const float*)d_in[32];

    float* fw = (float*)d_ws;
    float* cosd = fw + F_COSD;
    float* sind = fw + F_SIND;
    float* Ybuf = fw + F_Y;
    float* efb  = fw + F_EF;
    float* h    = fw + F_H;
    float* hn   = fw + F_HN;
    float* hres = fw + F_HRES;
    float* t1   = fw + F_T1;
    float* he2  = fw + F_HE2;
    float* hu   = fw + F_HU;
    unsigned short* tA   = (unsigned short*)(fw + F_TA);   // 2*NE*64
    unsigned short* hbuf = (unsigned short*)(fw + F_TB);   // 2*NE*64
    unsigned short* W4bt = (unsigned short*)(fw + F_WTS);
    unsigned short* W2bt = W4bt + (size_t)2 * 512 * 64;
    unsigned short* W3bt = W2bt + (size_t)2 * 64 * 64;
    unsigned short* Wm1bt = W3bt + (size_t)2 * 64 * 64;
    unsigned short* Wm2bt = Wm1bt + (size_t)2 * 128 * 128;
    unsigned short* wbuf = (unsigned short*)(fw + F_W);    // 2*NE*512
    float* sfr  = fw + F_SFR;
    float* sfi  = fw + F_SFI;
    float* sfp  = fw + F_SFP;
    float* kdwn = fw + F_KD;
    float* e0buf = fw + F_E0;
    float* nebuf = fw + F_NE;

    int* ip     = (int*)((char*)d_ws + I_BASE);
    int* deg    = ip;
    int* offs   = ip + NA;
    int* cursor = ip + 2 * NA + 1;
    int* perm   = ip + 3 * NA + 1;
    int* gs     = perm + NE;

    float* Eout = (float*)d_out;

    hipMemsetAsync(deg, 0, NA * sizeof(int), stream);

    k_node_init<<<NA, 128, 0, stream>>>(na, Wemb, aE, h, e0buf);
    k_ranges<<<1, 256, 0, stream>>>(batch, gs);
    k_kspace<<<NA, 128, 0, stream>>>(pos, kgrid, cosd, sind);
    k_kdown<<<1, 1024, 0, stream>>>(krbf, Wdown, kdwn);
    k_edge_geom<<<NE / 256, 256, 0, stream>>>(pos, shifts, eidx, Ybuf, efb);
    k_count<<<NE / 256, 256, 0, stream>>>(eidx, deg);
    k_scan<<<1, 1024, 0, stream>>>(deg, offs, cursor);
    k_fill<<<NE / 256, 256, 0, stream>>>(eidx, cursor, perm);
    k_convW4<<<1024, 64, 0, stream>>>(rW4, W4bt);
    k_convW64<<<128, 64, 0, stream>>>(rW2, W2bt);
    k_convW64<<<128, 64, 0, stream>>>(rW3, W3bt);
    k_convT128<<<256, 128, 0, stream>>>(Wm1, Wm1bt);
    k_convT128<<<256, 128, 0, stream>>>(Wm2, Wm2bt);

    // ---- edge branch, both layers batched (independent of h) ----
    gemm_kernel<8, 1, 1, 1><<<dim3(NE / 64, 1, 2), 256, 0, stream>>>(
        efb, rW1, rb1, nullptr, nullptr, hbuf, NE, 64, 1.f);
    k_mlp_mfma<<<2 * NE / 128, 128, 0, stream>>>(hbuf, W2bt, rb2, tA);
    k_mlp_mfma<<<2 * NE / 128, 128, 0, stream>>>(tA, W3bt, rb3, hbuf);
    k_wbuf_mfma<<<dim3(2 * NE / 256, 512 / 64), 256, 0, stream>>>(hbuf, W4bt, wbuf);

    const dim3 gA(NA / 64, C / 64);
    const dim3 gDual(NA / 64, 4);
    const dim3 gSF(BG, 4, SFSPLIT);
    const int gRED = (int)((SFSZ / 4 + 255) / 256);

    for (int i = 0; i < 2; i++) {
        const float* Wpre1_i = Wpre1 + (size_t)i * C * C;
        const float* bpre1_i = bpre1 + (size_t)i * C;
        const float* Wpre2_i = Wpre2 + (size_t)i * C * C;
        const float* bpre2_i = bpre2 + (size_t)i * C;
        const float* WupE_i  = WupE + (size_t)i * 8 * C;
        const float* bm1_i   = bm1 + (size_t)i * C;
        const float* bm2_i   = bm2 + (size_t)i * C;
        const float* Wup_i   = Wup + (size_t)i * C * C;
        const float* w2_i    = w2 + (size_t)i * 4 * C;
        const float* w3_i    = w3 + (size_t)i * 4 * C;
        const float* Wmix_i  = Wmix + (size_t)i * C * C;
        const unsigned short* Wm1bt_i = Wm1bt + (size_t)i * 128 * 128;
        const unsigned short* Wm2bt_i = Wm2bt + (size_t)i * 128 * 128;
        const unsigned short* wbuf_i = wbuf + (size_t)i * NE * 512;

        // dual: t1 = silu(h@Wpre1+b), hu = h@Wup
        gemm_dual<<<gDual, 256, 0, stream>>>(h, Wpre1_i, Wup_i, bpre1_i, t1, hu);
        gemm_kernel<128, 0, 0><<<gA, 256, 0, stream>>>(t1, Wpre2_i, bpre2_i, h, nullptr, hres, NA, C, 1.f);

        // Ewald branch
        k_sf<<<gSF, 256, 0, stream>>>(hres, cosd, sind, gs, kdwn, WupE_i, sfp);
        k_sfred<<<gRED, 256, 0, stream>>>(sfp, sfr, sfi);
        k_he<<<NA, 128, 0, stream>>>(cosd, sind, sfr, sfi, batch, t1);
        k_hemlp<<<NA / 64, 256, 0, stream>>>(t1, Wm1bt_i, bm1_i, Wm2bt_i, bm2_i, he2);

        // fused gather + Wmix + residual + energy
        k_gather_mix<<<NA, 128, 0, stream>>>(wbuf_i, hu, Ybuf, eidx, offs, perm,
                                             w2_i, w3_i, Wmix_i, h, he2,
                                             Wr0, Wr1a, Wr1b, (i == 0) ? 0 : 1,
                                             hn, nebuf + (size_t)i * NA);

        float* tmp = h; h = hn; hn = tmp;
    }

    k_reduceE<<<BG, 256, 0, stream>>>(e0buf, nebuf, gs, Eout);
}

// Round 10
// 405.505 us; speedup vs baseline: 1.8956x; 1.0414x over previous
//
#include <hip/hip_runtime.h>
#include <hip/hip_bf16.h>
#include <math.h>

// ---------------- problem constants ----------------
constexpr int NA  = 3200;     // atoms
constexpr int NE  = 51200;    // edges
constexpr int C   = 128;      // channels
constexpr int NK  = 123;      // k-points with |k| <= 0.6
constexpr int NKP = 128;      // padded stride for cosd/sind
constexpr int BG  = 8;        // graphs
constexpr int SFSPLIT = 8;    // k_sf split factor
constexpr float SKIPF = 0.57735026918962576f;  // 3^-0.5
constexpr float AVGN  = 16.0f;
constexpr size_t SFSZ = (size_t)BG * NK * C;   // one sf plane (125952)

__device__ __forceinline__ float dsilu(float x) { return x / (1.0f + expf(-x)); }

__device__ __forceinline__ unsigned short f2bf(float f) {
    unsigned int u = __float_as_uint(f);
    unsigned int r = (u + 0x7fffu + ((u >> 16) & 1u)) >> 16;
    return (unsigned short)r;
}
__device__ __forceinline__ float bf2f(unsigned short s) {
    return __uint_as_float(((unsigned int)s) << 16);
}

typedef __attribute__((ext_vector_type(8))) short short8;
typedef __attribute__((ext_vector_type(4))) float f32x4;

// ---------------- generic tiled f32 GEMM (LB: batch 2 layers over blockIdx.z) ----------------
template <int K, int ACT, int OBF16, int LB = 0>
__global__ __launch_bounds__(256, 4) void gemm_kernel(
    const float* __restrict__ X, const float* __restrict__ W,
    const float* __restrict__ bias, void* __restrict__ outv,
    int M, int N)
{
    if (LB) {
        int L = blockIdx.z;
        W += (size_t)L * K * N;
        if (bias) bias += (size_t)L * N;
        outv = OBF16 ? (void*)((unsigned short*)outv + (size_t)L * M * N)
                     : (void*)((float*)outv + (size_t)L * M * N);
    }
    constexpr int K4 = K / 4;
    constexpr int BK  = (K < 64) ? K : 64;
    constexpr int BK4 = BK / 4;
    constexpr int BK4P = BK4 + 1;
    __shared__ float As[64 * BK4P * 4];
    __shared__ float Bs[BK * 64];
    const int tid = threadIdx.x;
    const int m0 = blockIdx.x * 64;
    const int n0 = blockIdx.y * 64;

    const float4* X4 = (const float4*)X;
    const float4* W4 = (const float4*)W;
    float4* As4 = (float4*)As;
    float4* Bs4 = (float4*)Bs;
    const int N4 = N >> 2;

    const int tx = tid & 15;
    const int ty = tid >> 4;
    float acc[4][4];
#pragma unroll
    for (int i = 0; i < 4; i++)
#pragma unroll
        for (int j = 0; j < 4; j++) acc[i][j] = 0.0f;

    for (int k0 = 0; k0 < K4; k0 += BK4) {
        if (k0) __syncthreads();
        for (int idx = tid; idx < 64 * BK4; idx += 256) {
            int r = idx / BK4, k4 = idx - r * BK4;
            As4[r * BK4P + k4] = X4[(size_t)(m0 + r) * K4 + k0 + k4];
        }
        for (int idx = tid; idx < BK * 16; idx += 256) {
            int kr = idx >> 4, c4 = idx & 15;
            Bs4[idx] = W4[(size_t)(k0 * 4 + kr) * N4 + (n0 >> 2) + c4];
        }
        __syncthreads();

#pragma unroll 4
        for (int k4 = 0; k4 < BK4; k4++) {
            float a[4][4];
#pragma unroll
            for (int i = 0; i < 4; i++) {
                float4 av = As4[(ty * 4 + i) * BK4P + k4];
                a[i][0] = av.x; a[i][1] = av.y; a[i][2] = av.z; a[i][3] = av.w;
            }
#pragma unroll
            for (int kk = 0; kk < 4; kk++) {
                float4 bv = Bs4[(k4 * 4 + kk) * 16 + tx];
#pragma unroll
                for (int i = 0; i < 4; i++) {
                    acc[i][0] += a[i][kk] * bv.x;
                    acc[i][1] += a[i][kk] * bv.y;
                    acc[i][2] += a[i][kk] * bv.z;
                    acc[i][3] += a[i][kk] * bv.w;
                }
            }
        }
    }

    float4 bv = make_float4(0.f, 0.f, 0.f, 0.f);
    if (bias) bv = ((const float4*)bias)[(n0 >> 2) + tx];
#pragma unroll
    for (int i = 0; i < 4; i++) {
        int row = m0 + ty * 4 + i;
        size_t o = (size_t)row * N + n0 + tx * 4;
        float4 v;
        v.x = acc[i][0] + bv.x; v.y = acc[i][1] + bv.y;
        v.z = acc[i][2] + bv.z; v.w = acc[i][3] + bv.w;
        if (ACT) { v.x = dsilu(v.x); v.y = dsilu(v.y); v.z = dsilu(v.z); v.w = dsilu(v.w); }
        if (OBF16) {
            ushort4 pk;
            pk.x = f2bf(v.x); pk.y = f2bf(v.y); pk.z = f2bf(v.z); pk.w = f2bf(v.w);
            *(ushort4*)((unsigned short*)outv + o) = pk;
        } else {
            *(float4*)((float*)outv + o) = v;
        }
    }
}

// ---------------- fused pre-MLP + Wup (3-stage bf16 MFMA) ----------------
// t1 = silu(h@Wpre1+b1) [LDS]; hu = h@Wup; hres = t1@Wpre2 + b2 + h
__global__ __launch_bounds__(256, 2) void k_pre(
    const float* __restrict__ h,
    const unsigned short* __restrict__ W1t, const float* __restrict__ b1,
    const unsigned short* __restrict__ Wut,
    const unsigned short* __restrict__ W2t, const float* __restrict__ b2,
    float* __restrict__ hu, float* __restrict__ hres)
{
    constexpr int MT = 64, ASH = 136;
    __shared__ unsigned short Xs[MT * ASH];
    __shared__ unsigned short Ws[128 * ASH];
    __shared__ unsigned short Ts[MT * ASH];
    const int tid = threadIdx.x;
    const int m0 = blockIdx.x * MT;

    for (int idx = tid; idx < MT * 32; idx += 256) {
        int r = idx >> 5, c4 = idx & 31;
        float4 v = ((const float4*)h)[(size_t)(m0 + r) * 32 + c4];
        ushort4 pk;
        pk.x = f2bf(v.x); pk.y = f2bf(v.y); pk.z = f2bf(v.z); pk.w = f2bf(v.w);
        *(ushort4*)(Xs + r * ASH + c4 * 4) = pk;
    }
    for (int idx = tid; idx < 128 * 16; idx += 256) {
        int r = idx >> 4, s = idx & 15;
        *(short8*)(Ws + r * ASH + s * 8) = ((const short8*)W1t)[(size_t)r * 16 + s];
    }
    __syncthreads();

    const int wave = tid >> 6;
    const int lane = tid & 63;
    const int q = lane >> 4;
    const int l16 = lane & 15;
    const int mrow = wave * 16;

    f32x4 acc[8];
    // stage 1: t1 = silu(h@Wpre1 + b1)
#pragma unroll
    for (int ni = 0; ni < 8; ni++) acc[ni] = (f32x4){0.f, 0.f, 0.f, 0.f};
#pragma unroll
    for (int kc = 0; kc < 4; kc++) {
        short8 a = *(const short8*)(Xs + (mrow + l16) * ASH + kc * 32 + q * 8);
#pragma unroll
        for (int ni = 0; ni < 8; ni++) {
            short8 b = *(const short8*)(Ws + (ni * 16 + l16) * ASH + kc * 32 + q * 8);
            acc[ni] = __builtin_amdgcn_mfma_f32_16x16x32_bf16(a, b, acc[ni], 0, 0, 0);
        }
    }
#pragma unroll
    for (int ni = 0; ni < 8; ni++) {
        float bv = b1[ni * 16 + l16];
#pragma unroll
        for (int r = 0; r < 4; r++) {
            Ts[(mrow + q * 4 + r) * ASH + ni * 16 + l16] = f2bf(dsilu(acc[ni][r] + bv));
        }
    }
    __syncthreads();
    // stage 2: hu = h@Wup
    for (int idx = tid; idx < 128 * 16; idx += 256) {
        int r = idx >> 4, s = idx & 15;
        *(short8*)(Ws + r * ASH + s * 8) = ((const short8*)Wut)[(size_t)r * 16 + s];
    }
    __syncthreads();
#pragma unroll
    for (int ni = 0; ni < 8; ni++) acc[ni] = (f32x4){0.f, 0.f, 0.f, 0.f};
#pragma unroll
    for (int kc = 0; kc < 4; kc++) {
        short8 a = *(const short8*)(Xs + (mrow + l16) * ASH + kc * 32 + q * 8);
#pragma unroll
        for (int ni = 0; ni < 8; ni++) {
            short8 b = *(const short8*)(Ws + (ni * 16 + l16) * ASH + kc * 32 + q * 8);
            acc[ni] = __builtin_amdgcn_mfma_f32_16x16x32_bf16(a, b, acc[ni], 0, 0, 0);
        }
    }
#pragma unroll
    for (int ni = 0; ni < 8; ni++) {
#pragma unroll
        for (int r = 0; r < 4; r++) {
            int row = m0 + mrow + q * 4 + r;
            hu[(size_t)row * C + ni * 16 + l16] = acc[ni][r];
        }
    }
    __syncthreads();
    // stage 3: hres = t1@Wpre2 + b2 + h
    for (int idx = tid; idx < 128 * 16; idx += 256) {
        int r = idx >> 4, s = idx & 15;
        *(short8*)(Ws + r * ASH + s * 8) = ((const short8*)W2t)[(size_t)r * 16 + s];
    }
    __syncthreads();
#pragma unroll
    for (int ni = 0; ni < 8; ni++) acc[ni] = (f32x4){0.f, 0.f, 0.f, 0.f};
#pragma unroll
    for (int kc = 0; kc < 4; kc++) {
        short8 a = *(const short8*)(Ts + (mrow + l16) * ASH + kc * 32 + q * 8);
#pragma unroll
        for (int ni = 0; ni < 8; ni++) {
            short8 b = *(const short8*)(Ws + (ni * 16 + l16) * ASH + kc * 32 + q * 8);
            acc[ni] = __builtin_amdgcn_mfma_f32_16x16x32_bf16(a, b, acc[ni], 0, 0, 0);
        }
    }
#pragma unroll
    for (int ni = 0; ni < 8; ni++) {
        float bv = b2[ni * 16 + l16];
#pragma unroll
        for (int r = 0; r < 4; r++) {
            int row = m0 + mrow + q * 4 + r;
            int col = ni * 16 + l16;
            hres[(size_t)row * C + col] = acc[ni][r] + bv + h[(size_t)row * C + col];
        }
    }
}

// ---------------- MFMA MLP layer, 2-layer batched ----------------
__global__ __launch_bounds__(128, 2) void k_mlp_mfma(
    const unsigned short* __restrict__ X, const unsigned short* __restrict__ Wbase,
    const float* __restrict__ bbase, unsigned short* __restrict__ out)
{
    constexpr int MT = 128, AS = 72;
    __shared__ unsigned short Als[MT * AS];
    __shared__ unsigned short Bls[64 * AS];
    const int tid = threadIdx.x;
    const int m0 = blockIdx.x * MT;
    const int layer = (m0 >= NE) ? 1 : 0;
    const unsigned short* Wt = Wbase + (size_t)layer * 64 * 64;
    const float* bias = bbase + (size_t)layer * 64;

    for (int idx = tid; idx < MT * 8; idx += 128) {
        int r = idx >> 3, s = idx & 7;
        *(short8*)(Als + r * AS + s * 8) = ((const short8*)X)[(size_t)(m0 + r) * 8 + s];
    }
    for (int idx = tid; idx < 64 * 8; idx += 128) {
        int r = idx >> 3, s = idx & 7;
        *(short8*)(Bls + r * AS + s * 8) = ((const short8*)Wt)[(size_t)r * 8 + s];
    }
    __syncthreads();

    const int wave = tid >> 6;
    const int lane = tid & 63;
    const int q = lane >> 4;
    const int l16 = lane & 15;
    const int mw = wave * 64;

    f32x4 acc[4][4];
#pragma unroll
    for (int mi = 0; mi < 4; mi++)
#pragma unroll
        for (int ni = 0; ni < 4; ni++) acc[mi][ni] = (f32x4){0.f, 0.f, 0.f, 0.f};

#pragma unroll
    for (int kc = 0; kc < 2; kc++) {
        short8 a[4], b[4];
#pragma unroll
        for (int mi = 0; mi < 4; mi++)
            a[mi] = *(const short8*)(Als + (mw + mi * 16 + l16) * AS + kc * 32 + q * 8);
#pragma unroll
        for (int ni = 0; ni < 4; ni++)
            b[ni] = *(const short8*)(Bls + (ni * 16 + l16) * AS + kc * 32 + q * 8);
#pragma unroll
        for (int mi = 0; mi < 4; mi++)
#pragma unroll
            for (int ni = 0; ni < 4; ni++)
                acc[mi][ni] = __builtin_amdgcn_mfma_f32_16x16x32_bf16(a[mi], b[ni], acc[mi][ni], 0, 0, 0);
    }

#pragma unroll
    for (int ni = 0; ni < 4; ni++) {
        float bv = bias[ni * 16 + l16];
#pragma unroll
        for (int mi = 0; mi < 4; mi++) {
#pragma unroll
            for (int r = 0; r < 4; r++) {
                int e = m0 + mw + mi * 16 + q * 4 + r;
                int n = ni * 16 + l16;
                out[(size_t)e * 64 + n] = f2bf(dsilu(acc[mi][ni][r] + bv));
            }
        }
    }
}

// ---------------- fused he-MLP: he2 = silu(silu(t1@Wm1+b1)@Wm2+b2), bf16 MFMA ----------------
__global__ __launch_bounds__(256, 2) void k_hemlp(
    const float* __restrict__ t1,
    const unsigned short* __restrict__ Wm1t, const float* __restrict__ bm1,
    const unsigned short* __restrict__ Wm2t, const float* __restrict__ bm2,
    float* __restrict__ he2)
{
    constexpr int MT = 64, ASH = 136;
    __shared__ unsigned short Xs[MT * ASH];
    __shared__ unsigned short Ws[128 * ASH];
    __shared__ unsigned short Ts[MT * ASH];
    const int tid = threadIdx.x;
    const int m0 = blockIdx.x * MT;

    for (int idx = tid; idx < MT * 32; idx += 256) {
        int r = idx >> 5, c4 = idx & 31;
        float4 v = ((const float4*)t1)[(size_t)(m0 + r) * 32 + c4];
        ushort4 pk;
        pk.x = f2bf(v.x); pk.y = f2bf(v.y); pk.z = f2bf(v.z); pk.w = f2bf(v.w);
        *(ushort4*)(Xs + r * ASH + c4 * 4) = pk;
    }
    for (int idx = tid; idx < 128 * 16; idx += 256) {
        int r = idx >> 4, s = idx & 15;
        *(short8*)(Ws + r * ASH + s * 8) = ((const short8*)Wm1t)[(size_t)r * 16 + s];
    }
    __syncthreads();

    const int wave = tid >> 6;
    const int lane = tid & 63;
    const int q = lane >> 4;
    const int l16 = lane & 15;
    const int mrow = wave * 16;

    f32x4 acc[8];
#pragma unroll
    for (int ni = 0; ni < 8; ni++) acc[ni] = (f32x4){0.f, 0.f, 0.f, 0.f};
#pragma unroll
    for (int kc = 0; kc < 4; kc++) {
        short8 a = *(const short8*)(Xs + (mrow + l16) * ASH + kc * 32 + q * 8);
#pragma unroll
        for (int ni = 0; ni < 8; ni++) {
            short8 b = *(const short8*)(Ws + (ni * 16 + l16) * ASH + kc * 32 + q * 8);
            acc[ni] = __builtin_amdgcn_mfma_f32_16x16x32_bf16(a, b, acc[ni], 0, 0, 0);
        }
    }
#pragma unroll
    for (int ni = 0; ni < 8; ni++) {
        float bv = bm1[ni * 16 + l16];
#pragma unroll
        for (int r = 0; r < 4; r++) {
            Ts[(mrow + q * 4 + r) * ASH + ni * 16 + l16] = f2bf(dsilu(acc[ni][r] + bv));
        }
    }
    __syncthreads();
    for (int idx = tid; idx < 128 * 16; idx += 256) {
        int r = idx >> 4, s = idx & 15;
        *(short8*)(Ws + r * ASH + s * 8) = ((const short8*)Wm2t)[(size_t)r * 16 + s];
    }
    __syncthreads();

#pragma unroll
    for (int ni = 0; ni < 8; ni++) acc[ni] = (f32x4){0.f, 0.f, 0.f, 0.f};
#pragma unroll
    for (int kc = 0; kc < 4; kc++) {
        short8 a = *(const short8*)(Ts + (mrow + l16) * ASH + kc * 32 + q * 8);
#pragma unroll
        for (int ni = 0; ni < 8; ni++) {
            short8 b = *(const short8*)(Ws + (ni * 16 + l16) * ASH + kc * 32 + q * 8);
            acc[ni] = __builtin_amdgcn_mfma_f32_16x16x32_bf16(a, b, acc[ni], 0, 0, 0);
        }
    }
#pragma unroll
    for (int ni = 0; ni < 8; ni++) {
        float bv = bm2[ni * 16 + l16];
#pragma unroll
        for (int r = 0; r < 4; r++) {
            int row = m0 + mrow + q * 4 + r;
            he2[(size_t)row * C + ni * 16 + l16] = dsilu(acc[ni][r] + bv);
        }
    }
}

// ---------------- MFMA GEMM, 2-layer batched: wbuf[e][n] = X[e] @ W4t_l[n] ----------------
__global__ __launch_bounds__(256, 2) void k_wbuf_mfma(
    const unsigned short* __restrict__ X, const unsigned short* __restrict__ W4base,
    unsigned short* __restrict__ wbuf)
{
    constexpr int MT = 256, NT = 64, AS = 72;
    __shared__ unsigned short Als[MT * AS];
    __shared__ unsigned short Bls[NT * AS];
    const int tid = threadIdx.x;
    const int m0 = blockIdx.x * MT;
    const int n0 = blockIdx.y * NT;
    const int layer = (m0 >= NE) ? 1 : 0;
    const unsigned short* W4t = W4base + (size_t)layer * 512 * 64;

    for (int idx = tid; idx < MT * 8; idx += 256) {
        int r = idx >> 3, s = idx & 7;
        *(short8*)(Als + r * AS + s * 8) = ((const short8*)X)[(size_t)(m0 + r) * 8 + s];
    }
    for (int idx = tid; idx < NT * 8; idx += 256) {
        int r = idx >> 3, s = idx & 7;
        *(short8*)(Bls + r * AS + s * 8) = ((const short8*)W4t)[(size_t)(n0 + r) * 8 + s];
    }
    __syncthreads();

    const int wave = tid >> 6;
    const int lane = tid & 63;
    const int q = lane >> 4;
    const int l16 = lane & 15;
    const int mw = wave * 64;

    f32x4 acc[4][4];
#pragma unroll
    for (int mi = 0; mi < 4; mi++)
#pragma unroll
        for (int ni = 0; ni < 4; ni++) acc[mi][ni] = (f32x4){0.f, 0.f, 0.f, 0.f};

#pragma unroll
    for (int kc = 0; kc < 2; kc++) {
        short8 a[4], b[4];
#pragma unroll
        for (int mi = 0; mi < 4; mi++)
            a[mi] = *(const short8*)(Als + (mw + mi * 16 + l16) * AS + kc * 32 + q * 8);
#pragma unroll
        for (int ni = 0; ni < 4; ni++)
            b[ni] = *(const short8*)(Bls + (ni * 16 + l16) * AS + kc * 32 + q * 8);
#pragma unroll
        for (int mi = 0; mi < 4; mi++)
#pragma unroll
            for (int ni = 0; ni < 4; ni++)
                acc[mi][ni] = __builtin_amdgcn_mfma_f32_16x16x32_bf16(a[mi], b[ni], acc[mi][ni], 0, 0, 0);
    }

#pragma unroll
    for (int mi = 0; mi < 4; mi++) {
#pragma unroll
        for (int ni = 0; ni < 4; ni++) {
#pragma unroll
            for (int r = 0; r < 4; r++) {
                int e = m0 + mw + mi * 16 + q * 4 + r;
                int n = n0 + ni * 16 + l16;
                wbuf[(size_t)e * 512 + n] = f2bf(acc[mi][ni][r]);
            }
        }
    }
}

// ---------------- setup megakernel ----------------
// task ranges over blockIdx.x (block = 128 threads):
constexpr int TK0 = NA;            // [0,NA): node_init + kspace
constexpr int TK1 = TK0 + 8;       // kdown
constexpr int TK2 = TK1 + 512;     // convW4 (rW4 -> W4bt)
constexpr int TK3 = TK2 + 64;      // convW64 rW2
constexpr int TK4 = TK3 + 64;      // convW64 rW3
constexpr int TK5 = TK4 + 256;     // convT128 Wm1
constexpr int TK6 = TK5 + 256;     // convT128 Wm2
constexpr int TK7 = TK6 + 256;     // convT128 Wpre1
constexpr int TK8 = TK7 + 256;     // convT128 Wpre2
constexpr int TK9 = TK8 + 256;     // convT128 Wup
constexpr int TKEND = TK9 + 1;     // ranges (1 block)

__device__ __forceinline__ float sincn(float x) {
    float px = 3.14159265358979323846f * x;
    return (fabsf(px) < 1e-8f) ? 1.0f : (sinf(px) / px);
}

__device__ __forceinline__ void convT128_task(
    const float* __restrict__ W, unsigned short* __restrict__ Wt, int idx)
{
    int layer = idx >> 14, rem = idx & 16383;
    int n = rem >> 7, k = rem & 127;
    Wt[((size_t)layer << 14) + (n << 7) + k] = f2bf(W[((size_t)layer << 14) + (k << 7) + n]);
}

__global__ __launch_bounds__(128) void k_setup(
    const float* __restrict__ na, const float* __restrict__ Wemb,
    const float* __restrict__ aE, const int* __restrict__ batch,
    const float* __restrict__ pos, const float* __restrict__ kgrid,
    const float* __restrict__ krbf, const float* __restrict__ Wdown,
    const float* __restrict__ rW4, const float* __restrict__ rW2,
    const float* __restrict__ rW3, const float* __restrict__ Wm1,
    const float* __restrict__ Wm2, const float* __restrict__ Wpre1,
    const float* __restrict__ Wpre2, const float* __restrict__ Wup,
    float* __restrict__ h, float* __restrict__ e0buf,
    float* __restrict__ cosd, float* __restrict__ sind,
    float* __restrict__ kdwn,
    unsigned short* __restrict__ W4bt, unsigned short* __restrict__ W2bt,
    unsigned short* __restrict__ W3bt, unsigned short* __restrict__ Wm1bt,
    unsigned short* __restrict__ Wm2bt, unsigned short* __restrict__ Wpre1bt,
    unsigned short* __restrict__ Wpre2bt, unsigned short* __restrict__ Wupbt,
    int* __restrict__ gs)
{
    const int bx = blockIdx.x;
    const int t = threadIdx.x;
    __shared__ int cnt[BG];

    if (bx < TK0) {
        // node_init + kspace for atom bx
        int n = bx, c = t;
        float s = 0.f;
#pragma unroll
        for (int k = 0; k < 10; k++) s += na[n * 10 + k] * Wemb[k * C + c];
        h[(size_t)n * C + c] = s;
        if (c == 0) {
            float e = 0.f;
#pragma unroll
            for (int k = 0; k < 10; k++) e += na[n * 10 + k] * aE[k];
            e0buf[n] = e;
        }
        float p0 = pos[n * 3 + 0], p1 = pos[n * 3 + 1], p2 = pos[n * 3 + 2];
        float sd = sincn(0.1f * p0) * sincn(0.1f * p1) * sincn(0.1f * p2);
        int k = t;
        if (k < NK) {
            float d = p0 * kgrid[k * 3 + 0] + p1 * kgrid[k * 3 + 1] + p2 * kgrid[k * 3 + 2];
            float sn, cs;
            sincosf(d, &sn, &cs);
            cosd[(size_t)n * NKP + k] = sd * cs;
            sind[(size_t)n * NKP + k] = sd * sn;
        } else {
            cosd[(size_t)n * NKP + k] = 0.f;
            sind[(size_t)n * NKP + k] = 0.f;
        }
    } else if (bx < TK1) {
        int slot = (bx - TK0) * 128 + t;
        if (slot < NK * 8) {
            int k = slot >> 3, j = slot & 7;
            float s = 0.f;
            for (int r = 0; r < 128; r++) s += krbf[k * 128 + r] * Wdown[r * 8 + j];
            kdwn[slot] = s;
        }
    } else if (bx < TK2) {
        int idx = (bx - TK1) * 128 + t;      // over 2*512*64
        int layer = idx >> 15, rem = idx & 32767;
        int n = rem >> 6, k = rem & 63;
        W4bt[((size_t)layer * 512 + n) * 64 + k] = f2bf(rW4[((size_t)layer * 64 + k) * 512 + n]);
    } else if (bx < TK3) {
        int idx = (bx - TK2) * 128 + t;      // over 2*64*64
        int layer = idx >> 12, rem = idx & 4095;
        int n = rem >> 6, k = rem & 63;
        W2bt[((size_t)layer * 64 + n) * 64 + k] = f2bf(rW2[((size_t)layer * 64 + k) * 64 + n]);
    } else if (bx < TK4) {
        int idx = (bx - TK3) * 128 + t;
        int layer = idx >> 12, rem = idx & 4095;
        int n = rem >> 6, k = rem & 63;
        W3bt[((size_t)layer * 64 + n) * 64 + k] = f2bf(rW3[((size_t)layer * 64 + k) * 64 + n]);
    } else if (bx < TK5) {
        convT128_task(Wm1, Wm1bt, (bx - TK4) * 128 + t);
    } else if (bx < TK6) {
        convT128_task(Wm2, Wm2bt, (bx - TK5) * 128 + t);
    } else if (bx < TK7) {
        convT128_task(Wpre1, Wpre1bt, (bx - TK6) * 128 + t);
    } else if (bx < TK8) {
        convT128_task(Wpre2, Wpre2bt, (bx - TK7) * 128 + t);
    } else if (bx < TK9) {
        convT128_task(Wup, Wupbt, (bx - TK8) * 128 + t);
    } else {
        // ranges
        if (t < BG) cnt[t] = 0;
        __syncthreads();
        for (int n = t; n < NA; n += 128) atomicAdd(&cnt[batch[n]], 1);
        __syncthreads();
        if (t == 0) {
            int s = 0;
            for (int b = 0; b < BG; b++) { gs[b] = s; s += cnt[b]; }
            gs[BG] = s;
        }
    }
}

// ---------------- edge geometry + degree count ----------------
__global__ __launch_bounds__(256) void k_edge_geom(
    const float* __restrict__ pos, const float* __restrict__ shifts,
    const int* __restrict__ eidx, float* __restrict__ Y, float* __restrict__ ef,
    int* __restrict__ deg)
{
    int e = blockIdx.x * 256 + threadIdx.x;
    if (e >= NE) return;
    int s = eidx[e], d = eidx[NE + e];
    atomicAdd(&deg[d], 1);
    float vx = pos[d * 3 + 0] - pos[s * 3 + 0] + shifts[e * 3 + 0];
    float vy = pos[d * 3 + 1] - pos[s * 3 + 1] + shifts[e * 3 + 1];
    float vz = pos[d * 3 + 2] - pos[s * 3 + 2] + shifts[e * 3 + 2];
    float r = sqrtf(vx * vx + vy * vy + vz * vz);
    float rinv = 1.0f / fmaxf(r, 1e-9f);
    float x = vx * rinv, y = vy * rinv, z = vz * rinv;

    const float s3 = 1.7320508075688772f, s5 = 2.2360679774997896f, s15 = 3.8729833462074170f;
    const float c70 = 2.0916500663351889f;
    const float c105 = 10.246950765959598f;
    const float c42 = 1.6201851746019651f;
    const float c7 = 1.3228756555322954f;
    float o[16];
    o[0] = 1.0f;
    o[1] = s3 * x; o[2] = s3 * y; o[3] = s3 * z;
    o[4] = s15 * x * y; o[5] = s15 * y * z; o[6] = 0.5f * s5 * (3.f * z * z - 1.f);
    o[7] = s15 * x * z; o[8] = 0.5f * s15 * (x * x - y * y);
    o[9]  = c70 * y * (3.f * x * x - y * y);
    o[10] = c105 * x * y * z;
    o[11] = c42 * y * (5.f * z * z - 1.f);
    o[12] = c7 * z * (5.f * z * z - 3.f);
    o[13] = c42 * x * (5.f * z * z - 1.f);
    o[14] = 0.5f * c105 * z * (x * x - y * y);
    o[15] = c70 * x * (x * x - 3.f * y * y);
    float4* Y4 = (float4*)(Y + (size_t)e * 16);
    Y4[0] = make_float4(o[0], o[1], o[2], o[3]);
    Y4[1] = make_float4(o[4], o[5], o[6], o[7]);
    Y4[2] = make_float4(o[8], o[9], o[10], o[11]);
    Y4[3] = make_float4(o[12], o[13], o[14], o[15]);

    float uu = fminf(fmaxf(r * 0.2f, 0.f), 1.f);
    float u2 = uu * uu, u4 = u2 * u2, u5 = u4 * uu, u6 = u5 * uu, u7 = u6 * uu;
    float env = 1.f - 21.f * u5 + 35.f * u6 - 15.f * u7;
    env = (r < 5.0f) ? env : 0.0f;
    float pref = 0.63245553203367587f * rinv * env;
    const float pio5 = 0.62831853071795865f;
    float efv[8];
#pragma unroll
    for (int n1 = 1; n1 <= 8; n1++) efv[n1 - 1] = pref * sinf(n1 * pio5 * r);
    float4* E4 = (float4*)(ef + (size_t)e * 8);
    E4[0] = make_float4(efv[0], efv[1], efv[2], efv[3]);
    E4[1] = make_float4(efv[4], efv[5], efv[6], efv[7]);
}

// ---------------- CSR by dst ----------------
__global__ __launch_bounds__(1024) void k_scan(
    const int* __restrict__ deg, int* __restrict__ offs, int* __restrict__ cursor)
{
    __shared__ int sc[1024];
    int tid = threadIdx.x;
    int base = tid * 4;
    int v[4]; int s = 0;
#pragma unroll
    for (int i = 0; i < 4; i++) {
        int idx = base + i;
        int d = (idx < NA) ? deg[idx] : 0;
        v[i] = s; s += d;
    }
    sc[tid] = s;
    __syncthreads();
    for (int ofs = 1; ofs < 1024; ofs <<= 1) {
        int t = (tid >= ofs) ? sc[tid - ofs] : 0;
        __syncthreads();
        sc[tid] += t;
        __syncthreads();
    }
    int excl = (tid > 0) ? sc[tid - 1] : 0;
#pragma unroll
    for (int i = 0; i < 4; i++) {
        int idx = base + i;
        if (idx < NA) { int o = excl + v[i]; offs[idx] = o; cursor[idx] = o; }
    }
    if (tid == 1023) offs[NA] = sc[1023];
}

__global__ __launch_bounds__(256) void k_fill(
    const int* __restrict__ eidx, int* __restrict__ cursor, int* __restrict__ perm)
{
    int e = blockIdx.x * 256 + threadIdx.x;
    if (e < NE) {
        int d = eidx[NE + e];
        int p = atomicAdd(&cursor[d], 1);
        perm[p] = e;
    }
}

// ---------------- Ewald: structure-factor partials (kfilter fused inline) ----------------
__global__ __launch_bounds__(256, 4) void k_sf(
    const float* __restrict__ hres, const float* __restrict__ cosd, const float* __restrict__ sind,
    const int* __restrict__ gs, const float* __restrict__ kdwn, const float* __restrict__ WupE,
    float* __restrict__ sfp)
{
    const int b = blockIdx.x, kt = blockIdx.y, sp = blockIdx.z;
    const int n0 = gs[b], n1 = gs[b + 1];
    const int cnt = n1 - n0;
    const int per = (cnt + SFSPLIT - 1) / SFSPLIT;
    const int cs = n0 + sp * per;
    const int ce = min(cs + per, n1);

    __shared__ float Hs[32 * 128];
    __shared__ float Cs[32 * 32];
    __shared__ float Ss[32 * 32];

    const int tid = threadIdx.x;
    const int tx = tid & 31;
    const int ty = tid >> 5;

    float accR[4][4], accI[4][4];
#pragma unroll
    for (int i = 0; i < 4; i++)
#pragma unroll
        for (int j = 0; j < 4; j++) { accR[i][j] = 0.f; accI[i][j] = 0.f; }

    float4* H4 = (float4*)Hs;
    float4* C4 = (float4*)Cs;
    float4* S4 = (float4*)Ss;

    for (int nb = cs; nb < ce; nb += 32) {
        __syncthreads();
        for (int idx = tid; idx < 32 * 32; idx += 256) {
            int r = idx >> 5, c4 = idx & 31;
            int n = nb + r;
            H4[idx] = (n < ce) ? ((const float4*)hres)[(size_t)n * 32 + c4]
                               : make_float4(0.f, 0.f, 0.f, 0.f);
        }
        for (int idx = tid; idx < 32 * 8; idx += 256) {
            int r = idx >> 3, k4 = idx & 7;
            int n = nb + r;
            float4 cv = make_float4(0.f, 0.f, 0.f, 0.f), sv = cv;
            if (n < ce) {
                cv = ((const float4*)cosd)[(size_t)n * 32 + kt * 8 + k4];
                sv = ((const float4*)sind)[(size_t)n * 32 + kt * 8 + k4];
            }
            C4[idx] = cv;
            S4[idx] = sv;
        }
        __syncthreads();
        const int lim = min(32, ce - nb);
        for (int n = 0; n < lim; n++) {
            float4 hv = H4[n * 32 + tx];
            float4 cv = C4[n * 8 + ty];
            float4 sv = S4[n * 8 + ty];
            float h[4] = { hv.x, hv.y, hv.z, hv.w };
            float ck[4] = { cv.x, cv.y, cv.z, cv.w };
            float sk[4] = { sv.x, sv.y, sv.z, sv.w };
#pragma unroll
            for (int i = 0; i < 4; i++)
#pragma unroll
                for (int j = 0; j < 4; j++) {
                    accR[i][j] += ck[i] * h[j];
                    accI[i][j] += sk[i] * h[j];
                }
        }
    }

    const int kbase = kt * 32 + ty * 4;
    float* baseR = sfp + (size_t)sp * SFSZ;
    float* baseI = sfp + (size_t)(SFSPLIT + sp) * SFSZ;
#pragma unroll
    for (int i = 0; i < 4; i++) {
        int k = kbase + i;
        if (k < NK) {
            float4 kfv = make_float4(0.f, 0.f, 0.f, 0.f);
#pragma unroll
            for (int j = 0; j < 8; j++) {
                float kd = kdwn[k * 8 + j];
                float4 wv = ((const float4*)WupE)[(size_t)j * 32 + tx];
                kfv.x += kd * wv.x; kfv.y += kd * wv.y;
                kfv.z += kd * wv.z; kfv.w += kd * wv.w;
            }
            float vx = kfv.x * 0.01f, vy = kfv.y * 0.01f, vz = kfv.z * 0.01f, vw = kfv.w * 0.01f;
            size_t o = ((size_t)(b * NK + k)) * C + tx * 4;
            *(float4*)(baseR + o) = make_float4(accR[i][0] * vx, accR[i][1] * vy,
                                                accR[i][2] * vz, accR[i][3] * vw);
            *(float4*)(baseI + o) = make_float4(accI[i][0] * vx, accI[i][1] * vy,
                                                accI[i][2] * vz, accI[i][3] * vw);
        }
    }
}

__global__ __launch_bounds__(256) void k_sfred(
    const float* __restrict__ sfp, float* __restrict__ sfr, float* __restrict__ sfi)
{
    const size_t S4 = SFSZ / 4;
    size_t o4 = (size_t)blockIdx.x * 256 + threadIdx.x;
    if (o4 >= S4) return;
    const float4* p = (const float4*)sfp;
    float4 ar = make_float4(0.f, 0.f, 0.f, 0.f), ai = ar;
#pragma unroll
    for (int sp = 0; sp < SFSPLIT; sp++) {
        float4 r = p[(size_t)sp * S4 + o4];
        ar.x += r.x; ar.y += r.y; ar.z += r.z; ar.w += r.w;
        float4 q = p[(size_t)(SFSPLIT + sp) * S4 + o4];
        ai.x += q.x; ai.y += q.y; ai.z += q.z; ai.w += q.w;
    }
    ((float4*)sfr)[o4] = ar;
    ((float4*)sfi)[o4] = ai;
}

// ---------------- he back-projection, LDS-tiled (32 atoms/block) ----------------
__global__ __launch_bounds__(256) void k_he(
    const float* __restrict__ cosd, const float* __restrict__ sind,
    const float* __restrict__ sfr, const float* __restrict__ sfi,
    const int* __restrict__ gs, float* __restrict__ out)
{
    const int b = blockIdx.y;
    const int a0g = gs[b], a1g = gs[b + 1];
    const int a0 = a0g + blockIdx.x * 32;
    if (a0 >= a1g) return;
    const int nal = min(32, a1g - a0);

    __shared__ float Cc[32 * 128];  // 16 KB
    __shared__ float Sc[32 * 128];  // 16 KB
    __shared__ float Fr[16 * 128];  // 8 KB
    __shared__ float Fi[16 * 128];  // 8 KB
    const int tid = threadIdx.x;

    for (int idx = tid; idx < 32 * 32; idx += 256) {
        int r = idx >> 5, c4 = idx & 31;
        float4 cv = make_float4(0.f, 0.f, 0.f, 0.f), sv = cv;
        if (r < nal) {
            cv = ((const float4*)cosd)[(size_t)(a0 + r) * 32 + c4];
            sv = ((const float4*)sind)[(size_t)(a0 + r) * 32 + c4];
        }
        ((float4*)Cc)[idx] = cv;
        ((float4*)Sc)[idx] = sv;
    }

    const int c = tid & 127;
    const int half = tid >> 7;   // 0 or 1; atoms half, half+2, ..., half+30
    float acc[16];
#pragma unroll
    for (int a = 0; a < 16; a++) acc[a] = 0.f;

    for (int kc = 0; kc < NKP; kc += 16) {
        __syncthreads();
        for (int idx = tid; idx < 16 * 32; idx += 256) {
            int kr = idx >> 5, c4 = idx & 31;
            float4 rv = make_float4(0.f, 0.f, 0.f, 0.f), iv = rv;
            if (kc + kr < NK) {
                rv = ((const float4*)sfr)[((size_t)(b * NK + kc + kr)) * 32 + c4];
                iv = ((const float4*)sfi)[((size_t)(b * NK + kc + kr)) * 32 + c4];
            }
            ((float4*)Fr)[idx] = rv;
            ((float4*)Fi)[idx] = iv;
        }
        __syncthreads();
#pragma unroll 4
        for (int kk = 0; kk < 16; kk++) {
            float fr = Fr[kk * 128 + c];
            float fi = Fi[kk * 128 + c];
            int kcc = kc + kk;
#pragma unroll
            for (int a = 0; a < 16; a++) {
                int row = half + a * 2;
                acc[a] += Cc[row * 128 + kcc] * fr + Sc[row * 128 + kcc] * fi;
            }
        }
    }

#pragma unroll
    for (int a = 0; a < 16; a++) {
        int row = half + a * 2;
        if (row < nal) out[(size_t)(a0 + row) * C + c] = acc[a];
    }
}

// ---------------- fused gather + symm-contraction + Wmix + residual + energy ----------------
__global__ __launch_bounds__(128) void k_gather_mix(
    const unsigned short* __restrict__ wbuf, const float* __restrict__ hu,
    const float* __restrict__ Y, const int* __restrict__ srcArr,
    const int* __restrict__ offs, const int* __restrict__ perm,
    const float* __restrict__ w2, const float* __restrict__ w3,
    const float* __restrict__ Wmix, const float* __restrict__ h,
    const float* __restrict__ he2,
    const float* __restrict__ Wr0, const float* __restrict__ Wr1a,
    const float* __restrict__ Wr1b, int mode,
    float* __restrict__ hn, float* __restrict__ nebuf)
{
    int n = blockIdx.x, c = threadIdx.x;
    int j0 = offs[n], j1 = offs[n + 1];
    float A[16];
#pragma unroll
    for (int s = 0; s < 16; s++) A[s] = 0.f;
    for (int j = j0; j < j1; j++) {
        int e = perm[j];
        int s = srcArr[e];
        float huc = hu[(size_t)s * C + c];
        ushort4 wv = *(const ushort4*)(wbuf + (size_t)e * 512 + c * 4);
        const float4* Yp = (const float4*)(Y + (size_t)e * 16);
        float4 y0 = Yp[0], y1 = Yp[1], y2 = Yp[2], y3 = Yp[3];
        float m0 = bf2f(wv.x) * huc, m1 = bf2f(wv.y) * huc;
        float m2 = bf2f(wv.z) * huc, m3 = bf2f(wv.w) * huc;
        A[0] += m0 * y0.x;
        A[1] += m1 * y0.y;  A[2]  += m1 * y0.z;  A[3]  += m1 * y0.w;
        A[4] += m2 * y1.x;  A[5]  += m2 * y1.y;  A[6]  += m2 * y1.z;  A[7] += m2 * y1.w;
        A[8] += m2 * y2.x;
        A[9] += m3 * y2.y;  A[10] += m3 * y2.z;  A[11] += m3 * y2.w;
        A[12] += m3 * y3.x; A[13] += m3 * y3.y;  A[14] += m3 * y3.z;  A[15] += m3 * y3.w;
    }
    const float inv = 1.0f / AVGN;
#pragma unroll
    for (int s = 0; s < 16; s++) A[s] *= inv;
    float scal = A[0];
    float i0 = A[0] * A[0];
    float i1 = A[1] * A[1] + A[2] * A[2] + A[3] * A[3];
    float i2 = A[4] * A[4] + A[5] * A[5] + A[6] * A[6] + A[7] * A[7] + A[8] * A[8];
    float i3 = A[9] * A[9] + A[10] * A[10] + A[11] * A[11] + A[12] * A[12] +
               A[13] * A[13] + A[14] * A[14] + A[15] * A[15];
    float t2 = i0 * w2[c] + i1 * w2[C + c] + i2 * w2[2 * C + c] + i3 * w2[3 * C + c];
    float t3 = i0 * w3[c] + i1 * w3[C + c] + i2 * w3[2 * C + c] + i3 * w3[3 * C + c];
    float fe_c = scal + t2 + scal * t3;

    __shared__ float fs[128];
    __shared__ float red[16];
    fs[c] = fe_c;
    __syncthreads();

    float mix = 0.f;
#pragma unroll 8
    for (int k = 0; k < 128; k++) mix += fs[k] * Wmix[(size_t)k * C + c];

    float hnv = SKIPF * (mix + h[(size_t)n * C + c] + he2[(size_t)n * C + c]);
    hn[(size_t)n * C + c] = hnv;

    __syncthreads();
    fs[c] = hnv;
    __syncthreads();

    if (mode == 0) {
        float v = hnv * Wr0[c];
#pragma unroll
        for (int o = 32; o; o >>= 1) v += __shfl_down(v, o, 64);
        if ((c & 63) == 0) red[c >> 6] = v;
        __syncthreads();
        if (c == 0) nebuf[n] = red[0] + red[1];
    } else {
        if (c < 16) {
            float s = 0.f;
#pragma unroll 8
            for (int cc = 0; cc < 128; cc++) s += fs[cc] * Wr1a[cc * 16 + c];
            red[c] = dsilu(s) * Wr1b[c];
        }
        __syncthreads();
        if (c == 0) {
            float s = 0.f;
#pragma unroll
            for (int j = 0; j < 16; j++) s += red[j];
            nebuf[n] = s;
        }
    }
}

// ---------------- final per-graph energy reduction ----------------
__global__ __launch_bounds__(256) void k_reduceE(
    const float* __restrict__ e0buf, const float* __restrict__ nebuf,
    const int* __restrict__ gs, float* __restrict__ Eout)
{
    int b = blockIdx.x, t = threadIdx.x;
    int n0 = gs[b], n1 = gs[b + 1];
    float s = 0.f;
    for (int n = n0 + t; n < n1; n += 256)
        s += e0buf[n] + nebuf[n] + nebuf[NA + n];
#pragma unroll
    for (int o = 32; o; o >>= 1) s += __shfl_down(s, o, 64);
    __shared__ float red[4];
    if ((t & 63) == 0) red[t >> 6] = s;
    __syncthreads();
    if (t == 0) Eout[b] = red[0] + red[1] + red[2] + red[3];
}

// ---------------- workspace layout (floats) ----------------
constexpr size_t NAC   = (size_t)NA * C;
constexpr size_t F_COSD = 0;
constexpr size_t F_SIND = F_COSD + (size_t)NA * NKP;
constexpr size_t F_Y    = F_SIND + (size_t)NA * NKP;
constexpr size_t F_EF   = F_Y + (size_t)NE * 16;
constexpr size_t F_H    = F_EF + (size_t)NE * 8;
constexpr size_t F_HN   = F_H + NAC;
constexpr size_t F_HRES = F_HN + NAC;
constexpr size_t F_T1   = F_HRES + NAC;
constexpr size_t F_HE2  = F_T1 + NAC;
constexpr size_t F_HU   = F_HE2 + NAC;
constexpr size_t F_TA   = F_HU + NAC;                // bf16 tA: 2*NE*64 shorts
constexpr size_t F_TB   = F_TA + (size_t)NE * 64;    // bf16 hbuf: 2*NE*64 shorts
constexpr size_t F_WTS  = F_TB + (size_t)NE * 64;    // bf16 weight stash (<=128K floats)
constexpr size_t F_W    = F_WTS + 128 * 1024;        // bf16 wbuf: 2*NE*512 shorts
constexpr size_t F_SFR  = F_W + (size_t)NE * 512;
constexpr size_t F_SFI  = F_SFR + SFSZ;
constexpr size_t F_SFP  = F_SFI + SFSZ;              // 16 planes of SFSZ
constexpr size_t F_KD   = F_SFP + 2 * (size_t)SFSPLIT * SFSZ;
constexpr size_t F_E0   = F_KD + 1024;
constexpr size_t F_NE   = F_E0 + NA;
constexpr size_t F_END  = F_NE + 2 * (size_t)NA;
constexpr size_t I_BASE = ((F_END * 4 + 255) / 256) * 256;

extern "C" void kernel_launch(void* const* d_in, const int* in_sizes, int n_in,
                              void* d_out, int out_size, void* d_ws, size_t ws_size,
                              hipStream_t stream) {
    const float* pos    = (const float*)d_in[0];
    const float* na     = (const float*)d_in[1];
    const float* shifts = (const float*)d_in[2];
    const int*   eidx   = (const int*)d_in[3];
    const int*   batch  = (const int*)d_in[4];
    const float* kgrid  = (const float*)d_in[5];
    const float* krbf   = (const float*)d_in[6];
    const float* Wemb   = (const float*)d_in[7];
    const float* aE     = (const float*)d_in[8];
    const float* rW1    = (const float*)d_in[9];
    const float* rb1    = (const float*)d_in[10];
    const float* rW2    = (const float*)d_in[11];
    const float* rb2    = (const float*)d_in[12];
    const float* rW3    = (const float*)d_in[13];
    const float* rb3    = (const float*)d_in[14];
    const float* rW4    = (const float*)d_in[15];
    const float* Wup    = (const float*)d_in[16];
    const float* w2     = (const float*)d_in[17];
    const float* w3     = (const float*)d_in[18];
    const float* Wmix   = (const float*)d_in[19];
    const float* Wr0    = (const float*)d_in[20];
    const float* Wr1a   = (const float*)d_in[21];
    const float* Wr1b   = (const float*)d_in[22];
    const float* Wdown  = (const float*)d_in[23];
    const float* WupE   = (const float*)d_in[24];
    const float* Wpre1  = (const float*)d_in[25];
    const float* bpre1  = (const float*)d_in[26];
    const float* Wpre2  = (const float*)d_in[27];
    const float* bpre2  = (const float*)d_in[28];
    const float* Wm1    = (const float*)d_in[29];
    const float* bm1    = (const float*)d_in[30];
    const float* Wm2    = (const float*)d_in[31];
    const float* bm2    = (const float*)d_in[32];

    float* fw = (float*)d_ws;
    float* cosd = fw + F_COSD;
    float* sind = fw + F_SIND;
    float* Ybuf = fw + F_Y;
    float* efb  = fw + F_EF;
    float* h    = fw + F_H;
    float* hn   = fw + F_HN;
    float* hres = fw + F_HRES;
    float* t1   = fw + F_T1;
    float* he2  = fw + F_HE2;
    float* hu   = fw + F_HU;
    unsigned short* tA   = (unsigned short*)(fw + F_TA);
    unsigned short* hbuf = (unsigned short*)(fw + F_TB);
    unsigned short* W4bt = (unsigned short*)(fw + F_WTS);
    unsigned short* W2bt  = W4bt + (size_t)2 * 512 * 64;
    unsigned short* W3bt  = W2bt + (size_t)2 * 64 * 64;
    unsigned short* Wm1bt = W3bt + (size_t)2 * 64 * 64;
    unsigned short* Wm2bt = Wm1bt + (size_t)2 * 128 * 128;
    unsigned short* Wp1bt = Wm2bt + (size_t)2 * 128 * 128;
    unsigned short* Wp2bt = Wp1bt + (size_t)2 * 128 * 128;
    unsigned short* Wupbt = Wp2bt + (size_t)2 * 128 * 128;
    unsigned short* wbuf = (unsigned short*)(fw + F_W);
    float* sfr  = fw + F_SFR;
    float* sfi  = fw + F_SFI;
    float* sfp  = fw + F_SFP;
    float* kdwn = fw + F_KD;
    float* e0buf = fw + F_E0;
    float* nebuf = fw + F_NE;

    int* ip     = (int*)((char*)d_ws + I_BASE);
    int* deg    = ip;
    int* offs   = ip + NA;
    int* cursor = ip + 2 * NA + 1;
    int* perm   = ip + 3 * NA + 1;
    int* gs     = perm + NE;

    float* Eout = (float*)d_out;

    hipMemsetAsync(deg, 0, NA * sizeof(int), stream);

    k_setup<<<TKEND, 128, 0, stream>>>(
        na, Wemb, aE, batch, pos, kgrid, krbf, Wdown,
        rW4, rW2, rW3, Wm1, Wm2, Wpre1, Wpre2, Wup,
        h, e0buf, cosd, sind, kdwn,
        W4bt, W2bt, W3bt, Wm1bt, Wm2bt, Wp1bt, Wp2bt, Wupbt, gs);
    k_edge_geom<<<NE / 256, 256, 0, stream>>>(pos, shifts, eidx, Ybuf, efb, deg);
    k_scan<<<1, 1024, 0, stream>>>(deg, offs, cursor);
    k_fill<<<NE / 256, 256, 0, stream>>>(eidx, cursor, perm);

    // ---- edge branch, both layers batched ----
    gemm_kernel<8, 1, 1, 1><<<dim3(NE / 64, 1, 2), 256, 0, stream>>>(
        efb, rW1, rb1, hbuf, NE, 64);
    k_mlp_mfma<<<2 * NE / 128, 128, 0, stream>>>(hbuf, W2bt, rb2, tA);
    k_mlp_mfma<<<2 * NE / 128, 128, 0, stream>>>(tA, W3bt, rb3, hbuf);
    k_wbuf_mfma<<<dim3(2 * NE / 256, 512 / 64), 256, 0, stream>>>(hbuf, W4bt, wbuf);

    const dim3 gSF(BG, 4, SFSPLIT);
    const dim3 gHE(16, BG);
    const int gRED = (int)((SFSZ / 4 + 255) / 256);

    for (int i = 0; i < 2; i++) {
        const float* bpre1_i = bpre1 + (size_t)i * C;
        const float* bpre2_i = bpre2 + (size_t)i * C;
        const float* WupE_i  = WupE + (size_t)i * 8 * C;
        const float* bm1_i   = bm1 + (size_t)i * C;
        const float* bm2_i   = bm2 + (size_t)i * C;
        const float* w2_i    = w2 + (size_t)i * 4 * C;
        const float* w3_i    = w3 + (size_t)i * 4 * C;
        const float* Wmix_i  = Wmix + (size_t)i * C * C;
        const unsigned short* Wm1bt_i = Wm1bt + (size_t)i * 128 * 128;
        const unsigned short* Wm2bt_i = Wm2bt + (size_t)i * 128 * 128;
        const unsigned short* Wp1bt_i = Wp1bt + (size_t)i * 128 * 128;
        const unsigned short* Wp2bt_i = Wp2bt + (size_t)i * 128 * 128;
        const unsigned short* Wupbt_i = Wupbt + (size_t)i * 128 * 128;
        const unsigned short* wbuf_i = wbuf + (size_t)i * NE * 512;

        // fused pre-MLP + Wup
        k_pre<<<NA / 64, 256, 0, stream>>>(h, Wp1bt_i, bpre1_i, Wupbt_i,
                                           Wp2bt_i, bpre2_i, hu, hres);

        // Ewald branch
        k_sf<<<gSF, 256, 0, stream>>>(hres, cosd, sind, gs, kdwn, WupE_i, sfp);
        k_sfred<<<gRED, 256, 0, stream>>>(sfp, sfr, sfi);
        k_he<<<gHE, 256, 0, stream>>>(cosd, sind, sfr, sfi, gs, t1);
        k_hemlp<<<NA / 64, 256, 0, stream>>>(t1, Wm1bt_i, bm1_i, Wm2bt_i, bm2_i, he2);

        // fused gather + Wmix + residual + energy
        k_gather_mix<<<NA, 128, 0, stream>>>(wbuf_i, hu, Ybuf, eidx, offs, perm,
                                             w2_i, w3_i, Wmix_i, h, he2,
                                             Wr0, Wr1a, Wr1b, (i == 0) ? 0 : 1,
                                             hn, nebuf + (size_t)i * NA);

        float* tmp = h; h = hn; hn = tmp;
    }

    k_reduceE<<<BG, 256, 0, stream>>>(e0buf, nebuf, gs, Eout);
}